// Round 6
// baseline (575.703 us; speedup 1.0000x reference)
//
#include <hip/hip_runtime.h>
#include <math.h>

#define LMAXP1 33
#define EDIM   256
#define CINF   10000.0f
#define FBIG   3.0e38f

// ---------------------------------------------------------------------------
// GEMM (NT, fused bias+relu): C[Mtot x 256] = relu(A @ W^T + b)
// 128 threads, 64x128 tile, 8x8 micro-tile (2 FLOP/LDS-byte -> VALU-bound).
// ---------------------------------------------------------------------------
__global__ __launch_bounds__(128)
void k_embed_gemm(const float* __restrict__ S0, int n0,
                  const float* __restrict__ S1, int n1,
                  const float* __restrict__ S2,
                  const float* __restrict__ W, const float* __restrict__ bias,
                  float* __restrict__ C, int Mtot, int K) {
    __shared__ alignas(16) float As[16][68];    // [k][row], 64 rows
    __shared__ alignas(16) float Bs[16][132];   // [k][col], 128 cols
    const int t    = threadIdx.x;               // 0..127
    const int tx   = t & 15, ty = t >> 4;       // 16 x 8 thread grid
    const int m0   = blockIdx.x * 64, nc0 = blockIdx.y * 128;
    const int arow  = t >> 1;                   // 0..63
    const int khalf = (t & 1) << 3;             // 0 or 8

    const int gr = m0 + arow;
    const float* srow = nullptr;
    if (gr < n0)            srow = S0 + (size_t)gr * K;
    else if (gr < n0 + n1)  srow = S1 + (size_t)(gr - n0) * K;
    else if (gr < Mtot)     srow = S2;               // single virtual row
    const float* wrow = W + (size_t)(nc0 + t) * K;

    float acc[8][8] = {};
    for (int k0 = 0; k0 < K; k0 += 16) {
        float4 va0 = make_float4(0.f,0.f,0.f,0.f), va1 = va0;
        if (srow) {
            va0 = *(const float4*)(srow + k0 + khalf);
            va1 = *(const float4*)(srow + k0 + khalf + 4);
        }
        const float4 vb0 = *(const float4*)(wrow + k0 + 0);
        const float4 vb1 = *(const float4*)(wrow + k0 + 4);
        const float4 vb2 = *(const float4*)(wrow + k0 + 8);
        const float4 vb3 = *(const float4*)(wrow + k0 + 12);
        As[khalf+0][arow]=va0.x; As[khalf+1][arow]=va0.y;
        As[khalf+2][arow]=va0.z; As[khalf+3][arow]=va0.w;
        As[khalf+4][arow]=va1.x; As[khalf+5][arow]=va1.y;
        As[khalf+6][arow]=va1.z; As[khalf+7][arow]=va1.w;
        Bs[ 0][t]=vb0.x; Bs[ 1][t]=vb0.y; Bs[ 2][t]=vb0.z; Bs[ 3][t]=vb0.w;
        Bs[ 4][t]=vb1.x; Bs[ 5][t]=vb1.y; Bs[ 6][t]=vb1.z; Bs[ 7][t]=vb1.w;
        Bs[ 8][t]=vb2.x; Bs[ 9][t]=vb2.y; Bs[10][t]=vb2.z; Bs[11][t]=vb2.w;
        Bs[12][t]=vb3.x; Bs[13][t]=vb3.y; Bs[14][t]=vb3.z; Bs[15][t]=vb3.w;
        __syncthreads();
        #pragma unroll
        for (int kk = 0; kk < 16; ++kk) {
            const float4 a0 = *(const float4*)&As[kk][ty << 3];
            const float4 a1 = *(const float4*)&As[kk][(ty << 3) + 4];
            const float4 b0 = *(const float4*)&Bs[kk][tx << 3];
            const float4 b1 = *(const float4*)&Bs[kk][(tx << 3) + 4];
            const float av[8] = {a0.x,a0.y,a0.z,a0.w,a1.x,a1.y,a1.z,a1.w};
            const float bv[8] = {b0.x,b0.y,b0.z,b0.w,b1.x,b1.y,b1.z,b1.w};
            #pragma unroll
            for (int i2 = 0; i2 < 8; ++i2)
                #pragma unroll
                for (int j2 = 0; j2 < 8; ++j2)
                    acc[i2][j2] = fmaf(av[i2], bv[j2], acc[i2][j2]);
        }
        __syncthreads();
    }
    #pragma unroll
    for (int i2 = 0; i2 < 8; ++i2) {
        const int grr = m0 + (ty << 3) + i2;
        if (grr >= Mtot) continue;
        #pragma unroll
        for (int j2 = 0; j2 < 8; ++j2) {
            const int gc = nc0 + (tx << 3) + j2;
            const float vv = acc[i2][j2] + bias[gc];
            C[(size_t)grr * EDIM + gc] = fmaxf(vv, 0.0f);
        }
    }
}

// ---------------------------------------------------------------------------
// Per-pair scaled edit-cost matrix (33x33), written dense (zeros outside valid)
// Emb layout: rows [0,Ns) = source, [Ns, Ns+Nt) = target, row Ns+Nt = virtual.
// ---------------------------------------------------------------------------
__global__ __launch_bounds__(256)
void k_costs(const float* __restrict__ Emb, const int* __restrict__ len_s,
             const int* __restrict__ len_t, int Ns, int Nt,
             float* __restrict__ costs) {
    __shared__ alignas(16) float Asl[LMAXP1 * EDIM];      // ~33.8 KB
    __shared__ float dtile[LMAXP1 * LMAXP1];
    __shared__ float na[LMAXP1], nb[LMAXP1];
    __shared__ float red[256];
    __shared__ float s_scale;
    const int p = blockIdx.x, tid = threadIdx.x;
    const int n = len_s[p], m = len_t[p];
    int offs = 0, offt = 0;
    for (int j = 0; j < p; ++j) { offs += len_s[j]; offt += len_t[j]; }  // uniform
    const int veRow = Ns + Nt;
    const int tbase = Ns + offt;                 // target rows base

    for (int idx = tid; idx < (n + 1) * (EDIM / 4); idx += 256) {
        const int r = idx >> 6, c = idx & 63;
        const float* src = (r < n) ? (Emb + (size_t)(offs + r) * EDIM)
                                   : (Emb + (size_t)veRow * EDIM);
        ((float4*)Asl)[r * 64 + c] = ((const float4*)src)[c];
    }
    __syncthreads();

    if (tid <= n) {                                  // ||a_i||^2
        const float4* a4 = (const float4*)(Asl + tid * EDIM);
        float s = 0.f;
        for (int k = 0; k < 64; ++k) {
            const float4 a = a4[k];
            s = fmaf(a.x, a.x, s); s = fmaf(a.y, a.y, s);
            s = fmaf(a.z, a.z, s); s = fmaf(a.w, a.w, s);
        }
        na[tid] = s;
    } else if (tid >= 64 && tid - 64 <= m) {          // ||b_j||^2
        const int j = tid - 64;
        const float* src = (j < m) ? (Emb + (size_t)(tbase + j) * EDIM)
                                   : (Emb + (size_t)veRow * EDIM);
        const float4* b4 = (const float4*)src;
        float s = 0.f;
        for (int k = 0; k < 64; ++k) {
            const float4 b = b4[k];
            s = fmaf(b.x, b.x, s); s = fmaf(b.y, b.y, s);
            s = fmaf(b.z, b.z, s); s = fmaf(b.w, b.w, s);
        }
        nb[j] = s;
    }
    __syncthreads();

    float lsum = 0.f;
    const int m1 = m + 1;
    const int cells = (n + 1) * m1;
    for (int c = tid; c < cells; c += 256) {
        const int i = c / m1, j = c - i * m1;
        const float* brow = (j < m) ? (Emb + (size_t)(tbase + j) * EDIM)
                                    : (Emb + (size_t)veRow * EDIM);
        const float4* a4 = (const float4*)(Asl + i * EDIM);
        const float4* b4 = (const float4*)brow;
        float dot = 0.f;
        #pragma unroll 8
        for (int k = 0; k < 64; ++k) {
            const float4 a = a4[k], b = b4[k];
            dot = fmaf(a.x, b.x, dot); dot = fmaf(a.y, b.y, dot);
            dot = fmaf(a.z, b.z, dot); dot = fmaf(a.w, b.w, dot);
        }
        const float sq = fmaxf(na[i] + nb[j] - 2.0f * dot, 0.0f);
        const float d  = (sq > 0.0f) ? sqrtf(sq) : 0.0f;
        dtile[i * LMAXP1 + j] = d;
        lsum += d;
    }
    red[tid] = lsum;
    __syncthreads();
    for (int s = 128; s > 0; s >>= 1) {
        if (tid < s) red[tid] += red[tid + s];
        __syncthreads();
    }
    if (tid == 0) s_scale = (float)(n * m) / red[0];
    __syncthreads();
    const float scale = s_scale;
    for (int idx = tid; idx < LMAXP1 * LMAXP1; idx += 256) {
        const int i = idx / LMAXP1, j = idx - i * LMAXP1;
        const float v = (i <= n && j <= m) ? dtile[i * LMAXP1 + j] * scale : 0.0f;
        costs[(size_t)p * (LMAXP1 * LMAXP1) + idx] = v;
    }
}

// ---------------------------------------------------------------------------
// LAP (Jonker-Volgenant) — R4 flow (all rows Dijkstra'd sequentially, literal
// reference semantics) with shortened serial chain:
//  * packed u32 argmin: reduced costs >= 0 so IEEE bits order as uint;
//    key = (bits & ~63) | lane; one DPP umin chain gives min AND first-index
//    argmin (ties are bit-identical -> lowest lane = np.argmin). Exact delta
//    re-read from winning lane.
//  * (i0, u_i0) carried across the loop: one readlane of p per step, LDS row
//    read issued immediately after argmin.
// ---------------------------------------------------------------------------
__device__ inline int rdlane_i(int v, int l) { return __builtin_amdgcn_readlane(v, l); }
__device__ inline float rdlane_f(float v, int l) {
    return __int_as_float(__builtin_amdgcn_readlane(__float_as_int(v), l));
}
__device__ inline unsigned wave_umin64(unsigned x) {
#define DPPMINU(ctrl) { unsigned t_ = (unsigned)__builtin_amdgcn_update_dpp(  \
        (int)x, (int)x, (ctrl), 0xf, 0xf, false);                             \
        x = (t_ < x) ? t_ : x; }
    DPPMINU(0xB1)   // quad_perm xor1
    DPPMINU(0x4E)   // quad_perm xor2
    DPPMINU(0x141)  // row_half_mirror xor4
    DPPMINU(0x140)  // row_mirror xor8
    DPPMINU(0x142)  // row_bcast15
    DPPMINU(0x143)  // row_bcast31
#undef DPPMINU
    return (unsigned)__builtin_amdgcn_readlane((int)x, 63);
}

__global__ __launch_bounds__(64)
void k_lap(const float* __restrict__ costs, const int* __restrict__ len_s,
           const int* __restrict__ len_t, float* __restrict__ aligns,
           float* __restrict__ geds) {
    __shared__ float ec[LMAXP1 * LMAXP1];
    __shared__ float Cs[62 * 64];           // rows 1..N at [r*64 + col]
    const int p = blockIdx.x, lane = threadIdx.x;
    const int n = len_s[p], m = len_t[p], N = n + m;
    const float* cp = costs + (size_t)p * (LMAXP1 * LMAXP1);
    for (int idx = lane; idx < LMAXP1 * LMAXP1; idx += 64) ec[idx] = cp[idx];
    __syncthreads();

    // Build expanded (N x N) LSAPE matrix exactly like _lsape_align (fp32).
    const bool vec = (lane >= 1 && lane <= N);
    for (int r = 1; r <= N; ++r) {
        float cv = CINF;
        const int i0b = r - 1, j0b = lane - 1;
        if (vec) {
            if (i0b < n) cv = (j0b < m) ? ec[i0b * LMAXP1 + j0b]
                                        : ((j0b == m + i0b) ? ec[i0b * LMAXP1 + m] : CINF);
            else         cv = (j0b < m) ? ((i0b - n == j0b) ? ec[n * LMAXP1 + j0b] : CINF)
                                        : 0.0f;
        }
        Cs[(r << 6) + lane] = cv;
    }
    __syncthreads();

    // Per-lane state, index = lane (0..N). Lane 0 = dummy slot 0.
    float v_l = 0.0f, minv_l = FBIG, ucol = 0.0f;   // ucol = u[p[lane]]
    int p_l = 0, way_l = 0;

    for (int i = 1; i <= N; ++i) {
        if (lane == 0) { p_l = i; ucol = 0.0f; }    // p[0]=i, u[i]=0
        minv_l = FBIG;
        int used_l = 0;
        int j0 = 0, i0 = i;                          // i0 = p[j0]
        float u_i0 = 0.0f;                           // u[p[j0]]
        while (true) {
            if (lane == j0) used_l = 1;              // used[j0] = True
            const float cur = Cs[(i0 << 6) + lane] - u_i0 - v_l;
            const bool unused = vec && !used_l;
            if (unused && cur < minv_l) { minv_l = cur; way_l = j0; }
            // packed min+argmin (values >= 0; clamp guards fp rounding)
            const float mval = unused ? fmaxf(minv_l, 0.0f) : FBIG;
            const unsigned key = (__float_as_uint(mval) & ~63u) | (unsigned)lane;
            const unsigned kmin = wave_umin64(key);
            const int j1 = (int)(kmin & 63u);
            const float delta = rdlane_f(minv_l, j1);   // exact min value
            if (used_l) { ucol += delta; v_l -= delta; }
            if (unused) minv_l -= delta;
            j0 = j1;
            i0 = rdlane_i(p_l, j1);
            u_i0 = rdlane_f(ucol, j1);
            if (i0 == 0) break;                      // p[j0] == 0 -> augment
        }
        // augment: while j0: j1=way[j0]; p[j0]=p[j1]; j0=j1  (u follows p)
        int jj = j0;
        while (jj != 0) {
            const int   j1a = rdlane_i(way_l, jj);
            const int   pn  = rdlane_i(p_l, j1a);    // lane0 holds p[0]=i
            const float un  = rdlane_f(ucol, j1a);
            if (lane == jj) { p_l = pn; ucol = un; }
            jj = j1a;
        }
    }

    // ---- outputs: aligns (0/1 as float), geds ----
    float* ap = aligns + (size_t)p * (LMAXP1 * LMAXP1);
    for (int idx = lane; idx < LMAXP1 * LMAXP1; idx += 64) ap[idx] = 0.0f;
    __syncthreads();
    float gedv = 0.0f;
    if (vec) {
        const int r0 = p_l - 1;                  // row assigned to column (lane)
        const int c0 = lane - 1;
        const int rr = (r0 < n) ? r0 : n;
        const int cc = (c0 < m) ? c0 : m;
        if (!(r0 >= n && c0 >= m)) {             // dummy-dummy -> align[n][m], stays 0
            ap[rr * LMAXP1 + cc] = 1.0f;
            gedv = ec[rr * LMAXP1 + cc];
        }
    }
    #pragma unroll
    for (int off = 32; off > 0; off >>= 1) gedv += __shfl_xor(gedv, off);
    if (lane == 0) geds[p] = gedv / (float)(n + m);
}

// ---------------------------------------------------------------------------
extern "C" void kernel_launch(void* const* d_in, const int* in_sizes, int n_in,
                              void* d_out, int out_size, void* d_ws, size_t ws_size,
                              hipStream_t stream) {
    const float* x_s = (const float*)d_in[0];
    const float* x_t = (const float*)d_in[1];
    const float* W1  = (const float*)d_in[2];
    const float* b1  = (const float*)d_in[3];
    const float* W2  = (const float*)d_in[4];
    const float* b2  = (const float*)d_in[5];
    const float* ve  = (const float*)d_in[6];
    const int* len_s = (const int*)d_in[7];
    const int* len_t = (const int*)d_in[8];
    const int P    = in_sizes[7];
    const int Ns   = in_sizes[0] / 2048;
    const int Nt   = in_sizes[1] / 2048;
    const int Mtot = Ns + Nt + 1;

    float* H   = (float*)d_ws;
    float* Emb = H + (size_t)Mtot * EDIM;

    float* out_aligns = (float*)d_out;
    float* out_costs  = out_aligns + (size_t)P * LMAXP1 * LMAXP1;
    float* out_geds   = out_costs  + (size_t)P * LMAXP1 * LMAXP1;

    const dim3 b128(128);
    const dim3 g1((Mtot + 63) / 64, EDIM / 128);
    k_embed_gemm<<<g1, b128, 0, stream>>>(x_s, Ns, x_t, Nt, ve, W1, b1, H, Mtot, 2048);
    k_embed_gemm<<<g1, b128, 0, stream>>>(H, Mtot, nullptr, 0, nullptr, W2, b2, Emb, Mtot, 256);
    k_costs<<<dim3(P), dim3(256), 0, stream>>>(Emb, len_s, len_t, Ns, Nt, out_costs);
    k_lap<<<dim3(P), dim3(64), 0, stream>>>(out_costs, len_s, len_t, out_aligns, out_geds);
}

// Round 7
// 466.514 us; speedup vs baseline: 1.2341x; 1.2341x over previous
//
#include <hip/hip_runtime.h>
#include <math.h>

#define LMAXP1 33
#define EDIM   256
#define CINF   10000.0f
#define FBIG   3.0e38f

// ---------------------------------------------------------------------------
// GEMM (NT, fused bias+relu): C[Mtot x 256] = relu(A @ W^T + b)
// R4 shape: 256 threads, 64x64 tile, BK=16, 4x4 micro-tile.
// grid (ceil(M/64), 4) = 640 blocks -> ~2.5 blocks/CU, coalesced loads.
// ---------------------------------------------------------------------------
__global__ __launch_bounds__(256)
void k_embed_gemm(const float* __restrict__ S0, int n0,
                  const float* __restrict__ S1, int n1,
                  const float* __restrict__ S2,
                  const float* __restrict__ W, const float* __restrict__ bias,
                  float* __restrict__ C, int Mtot, int K) {
    __shared__ alignas(16) float As[16][68];   // transposed: As[k][row]
    __shared__ alignas(16) float Bs[16][68];
    const int tid  = threadIdx.x;
    const int tx   = tid & 15, ty = tid >> 4;
    const int m0   = blockIdx.x * 64, nc0 = blockIdx.y * 64;
    const int lrow = tid >> 2;            // 0..63
    const int lk4  = (tid & 3) << 2;      // 0,4,8,12

    const int gr = m0 + lrow;
    const float* srow = nullptr;
    if (gr < n0)            srow = S0 + (size_t)gr * K;
    else if (gr < n0 + n1)  srow = S1 + (size_t)(gr - n0) * K;
    else if (gr < Mtot)     srow = S2;               // single virtual row
    const float* wrow = W + (size_t)(nc0 + lrow) * K;

    float acc[4][4] = {};
    for (int k0 = 0; k0 < K; k0 += 16) {
        float4 va = make_float4(0.f, 0.f, 0.f, 0.f);
        if (srow) va = *(const float4*)(srow + k0 + lk4);
        const float4 vb = *(const float4*)(wrow + k0 + lk4);
        As[lk4+0][lrow] = va.x; As[lk4+1][lrow] = va.y;
        As[lk4+2][lrow] = va.z; As[lk4+3][lrow] = va.w;
        Bs[lk4+0][lrow] = vb.x; Bs[lk4+1][lrow] = vb.y;
        Bs[lk4+2][lrow] = vb.z; Bs[lk4+3][lrow] = vb.w;
        __syncthreads();
        #pragma unroll
        for (int kk = 0; kk < 16; ++kk) {
            const float4 a4 = *(const float4*)&As[kk][ty << 2];
            const float4 b4 = *(const float4*)&Bs[kk][tx << 2];
            const float av[4] = {a4.x, a4.y, a4.z, a4.w};
            const float bv[4] = {b4.x, b4.y, b4.z, b4.w};
            #pragma unroll
            for (int i2 = 0; i2 < 4; ++i2)
                #pragma unroll
                for (int j2 = 0; j2 < 4; ++j2)
                    acc[i2][j2] = fmaf(av[i2], bv[j2], acc[i2][j2]);
        }
        __syncthreads();
    }
    #pragma unroll
    for (int i2 = 0; i2 < 4; ++i2) {
        const int grr = m0 + (ty << 2) + i2;
        if (grr >= Mtot) continue;
        #pragma unroll
        for (int j2 = 0; j2 < 4; ++j2) {
            const int gc = nc0 + (tx << 2) + j2;
            const float vv = acc[i2][j2] + bias[gc];
            C[(size_t)grr * EDIM + gc] = fmaxf(vv, 0.0f);
        }
    }
}

// ---------------------------------------------------------------------------
// Per-pair scaled edit-cost matrix (33x33), written dense (zeros outside valid)
// Emb layout: rows [0,Ns) = source, [Ns, Ns+Nt) = target, row Ns+Nt = virtual.
// ---------------------------------------------------------------------------
__global__ __launch_bounds__(256)
void k_costs(const float* __restrict__ Emb, const int* __restrict__ len_s,
             const int* __restrict__ len_t, int Ns, int Nt,
             float* __restrict__ costs) {
    __shared__ alignas(16) float Asl[LMAXP1 * EDIM];      // ~33.8 KB
    __shared__ float dtile[LMAXP1 * LMAXP1];
    __shared__ float na[LMAXP1], nb[LMAXP1];
    __shared__ float red[256];
    __shared__ float s_scale;
    const int p = blockIdx.x, tid = threadIdx.x;
    const int n = len_s[p], m = len_t[p];
    int offs = 0, offt = 0;
    for (int j = 0; j < p; ++j) { offs += len_s[j]; offt += len_t[j]; }  // uniform
    const int veRow = Ns + Nt;
    const int tbase = Ns + offt;                 // target rows base

    for (int idx = tid; idx < (n + 1) * (EDIM / 4); idx += 256) {
        const int r = idx >> 6, c = idx & 63;
        const float* src = (r < n) ? (Emb + (size_t)(offs + r) * EDIM)
                                   : (Emb + (size_t)veRow * EDIM);
        ((float4*)Asl)[r * 64 + c] = ((const float4*)src)[c];
    }
    __syncthreads();

    if (tid <= n) {                                  // ||a_i||^2
        const float4* a4 = (const float4*)(Asl + tid * EDIM);
        float s = 0.f;
        for (int k = 0; k < 64; ++k) {
            const float4 a = a4[k];
            s = fmaf(a.x, a.x, s); s = fmaf(a.y, a.y, s);
            s = fmaf(a.z, a.z, s); s = fmaf(a.w, a.w, s);
        }
        na[tid] = s;
    } else if (tid >= 64 && tid - 64 <= m) {          // ||b_j||^2
        const int j = tid - 64;
        const float* src = (j < m) ? (Emb + (size_t)(tbase + j) * EDIM)
                                   : (Emb + (size_t)veRow * EDIM);
        const float4* b4 = (const float4*)src;
        float s = 0.f;
        for (int k = 0; k < 64; ++k) {
            const float4 b = b4[k];
            s = fmaf(b.x, b.x, s); s = fmaf(b.y, b.y, s);
            s = fmaf(b.z, b.z, s); s = fmaf(b.w, b.w, s);
        }
        nb[j] = s;
    }
    __syncthreads();

    float lsum = 0.f;
    const int m1 = m + 1;
    const int cells = (n + 1) * m1;
    for (int c = tid; c < cells; c += 256) {
        const int i = c / m1, j = c - i * m1;
        const float* brow = (j < m) ? (Emb + (size_t)(tbase + j) * EDIM)
                                    : (Emb + (size_t)veRow * EDIM);
        const float4* a4 = (const float4*)(Asl + i * EDIM);
        const float4* b4 = (const float4*)brow;
        float dot = 0.f;
        #pragma unroll 8
        for (int k = 0; k < 64; ++k) {
            const float4 a = a4[k], b = b4[k];
            dot = fmaf(a.x, b.x, dot); dot = fmaf(a.y, b.y, dot);
            dot = fmaf(a.z, b.z, dot); dot = fmaf(a.w, b.w, dot);
        }
        const float sq = fmaxf(na[i] + nb[j] - 2.0f * dot, 0.0f);
        const float d  = (sq > 0.0f) ? sqrtf(sq) : 0.0f;
        dtile[i * LMAXP1 + j] = d;
        lsum += d;
    }
    red[tid] = lsum;
    __syncthreads();
    for (int s = 128; s > 0; s >>= 1) {
        if (tid < s) red[tid] += red[tid + s];
        __syncthreads();
    }
    if (tid == 0) s_scale = (float)(n * m) / red[0];
    __syncthreads();
    const float scale = s_scale;
    for (int idx = tid; idx < LMAXP1 * LMAXP1; idx += 256) {
        const int i = idx / LMAXP1, j = idx - i * LMAXP1;
        const float v = (i <= n && j <= m) ? dtile[i * LMAXP1 + j] * scale : 0.0f;
        costs[(size_t)p * (LMAXP1 * LMAXP1) + idx] = v;
    }
}

// ---------------------------------------------------------------------------
// LAP (Jonker-Volgenant) — literal reference semantics, shortened chain:
//  * packed u32 argmin via DPP (reduced costs >= 0 -> IEEE bits order as uint;
//    key=(bits&~63)|lane; ties bit-identical -> lowest lane = np.argmin).
//  * (i0, u_i0) carried across loop iterations; one readlane of p per step.
// ---------------------------------------------------------------------------
__device__ inline int rdlane_i(int v, int l) { return __builtin_amdgcn_readlane(v, l); }
__device__ inline float rdlane_f(float v, int l) {
    return __int_as_float(__builtin_amdgcn_readlane(__float_as_int(v), l));
}
__device__ inline unsigned wave_umin64(unsigned x) {
#define DPPMINU(ctrl) { unsigned t_ = (unsigned)__builtin_amdgcn_update_dpp(  \
        (int)x, (int)x, (ctrl), 0xf, 0xf, false);                             \
        x = (t_ < x) ? t_ : x; }
    DPPMINU(0xB1)   // quad_perm xor1
    DPPMINU(0x4E)   // quad_perm xor2
    DPPMINU(0x141)  // row_half_mirror xor4
    DPPMINU(0x140)  // row_mirror xor8
    DPPMINU(0x142)  // row_bcast15
    DPPMINU(0x143)  // row_bcast31
#undef DPPMINU
    return (unsigned)__builtin_amdgcn_readlane((int)x, 63);
}

__global__ __launch_bounds__(64)
void k_lap(const float* __restrict__ costs, const int* __restrict__ len_s,
           const int* __restrict__ len_t, float* __restrict__ aligns,
           float* __restrict__ geds) {
    __shared__ float ec[LMAXP1 * LMAXP1];
    __shared__ float Cs[62 * 64];           // rows 1..N at [r*64 + col]
    const int p = blockIdx.x, lane = threadIdx.x;
    const int n = len_s[p], m = len_t[p], N = n + m;
    const float* cp = costs + (size_t)p * (LMAXP1 * LMAXP1);
    for (int idx = lane; idx < LMAXP1 * LMAXP1; idx += 64) ec[idx] = cp[idx];
    __syncthreads();

    // Build expanded (N x N) LSAPE matrix exactly like _lsape_align (fp32).
    const bool vec = (lane >= 1 && lane <= N);
    for (int r = 1; r <= N; ++r) {
        float cv = CINF;
        const int i0b = r - 1, j0b = lane - 1;
        if (vec) {
            if (i0b < n) cv = (j0b < m) ? ec[i0b * LMAXP1 + j0b]
                                        : ((j0b == m + i0b) ? ec[i0b * LMAXP1 + m] : CINF);
            else         cv = (j0b < m) ? ((i0b - n == j0b) ? ec[n * LMAXP1 + j0b] : CINF)
                                        : 0.0f;
        }
        Cs[(r << 6) + lane] = cv;
    }
    __syncthreads();

    // Per-lane state, index = lane (0..N). Lane 0 = dummy slot 0.
    float v_l = 0.0f, minv_l = FBIG, ucol = 0.0f;   // ucol = u[p[lane]]
    int p_l = 0, way_l = 0;

    for (int i = 1; i <= N; ++i) {
        if (lane == 0) { p_l = i; ucol = 0.0f; }    // p[0]=i, u[i]=0
        minv_l = FBIG;
        int used_l = 0;
        int j0 = 0, i0 = i;                          // i0 = p[j0]
        float u_i0 = 0.0f;                           // u[p[j0]]
        while (true) {
            if (lane == j0) used_l = 1;              // used[j0] = True
            const float cur = Cs[(i0 << 6) + lane] - u_i0 - v_l;
            const bool unused = vec && !used_l;
            if (unused && cur < minv_l) { minv_l = cur; way_l = j0; }
            // packed min+argmin (values >= 0; clamp guards fp rounding)
            const float mval = unused ? fmaxf(minv_l, 0.0f) : FBIG;
            const unsigned key = (__float_as_uint(mval) & ~63u) | (unsigned)lane;
            const unsigned kmin = wave_umin64(key);
            const int j1 = (int)(kmin & 63u);
            const float delta = rdlane_f(minv_l, j1);   // exact min value
            if (used_l) { ucol += delta; v_l -= delta; }
            if (unused) minv_l -= delta;
            j0 = j1;
            i0 = rdlane_i(p_l, j1);
            u_i0 = rdlane_f(ucol, j1);
            if (i0 == 0) break;                      // p[j0] == 0 -> augment
        }
        // augment: while j0: j1=way[j0]; p[j0]=p[j1]; j0=j1  (u follows p)
        int jj = j0;
        while (jj != 0) {
            const int   j1a = rdlane_i(way_l, jj);
            const int   pn  = rdlane_i(p_l, j1a);    // lane0 holds p[0]=i
            const float un  = rdlane_f(ucol, j1a);
            if (lane == jj) { p_l = pn; ucol = un; }
            jj = j1a;
        }
    }

    // ---- outputs: aligns (0/1 as float), geds ----
    float* ap = aligns + (size_t)p * (LMAXP1 * LMAXP1);
    for (int idx = lane; idx < LMAXP1 * LMAXP1; idx += 64) ap[idx] = 0.0f;
    __syncthreads();
    float gedv = 0.0f;
    if (vec) {
        const int r0 = p_l - 1;                  // row assigned to column (lane)
        const int c0 = lane - 1;
        const int rr = (r0 < n) ? r0 : n;
        const int cc = (c0 < m) ? c0 : m;
        if (!(r0 >= n && c0 >= m)) {             // dummy-dummy -> align[n][m], stays 0
            ap[rr * LMAXP1 + cc] = 1.0f;
            gedv = ec[rr * LMAXP1 + cc];
        }
    }
    #pragma unroll
    for (int off = 32; off > 0; off >>= 1) gedv += __shfl_xor(gedv, off);
    if (lane == 0) geds[p] = gedv / (float)(n + m);
}

// ---------------------------------------------------------------------------
extern "C" void kernel_launch(void* const* d_in, const int* in_sizes, int n_in,
                              void* d_out, int out_size, void* d_ws, size_t ws_size,
                              hipStream_t stream) {
    const float* x_s = (const float*)d_in[0];
    const float* x_t = (const float*)d_in[1];
    const float* W1  = (const float*)d_in[2];
    const float* b1  = (const float*)d_in[3];
    const float* W2  = (const float*)d_in[4];
    const float* b2  = (const float*)d_in[5];
    const float* ve  = (const float*)d_in[6];
    const int* len_s = (const int*)d_in[7];
    const int* len_t = (const int*)d_in[8];
    const int P    = in_sizes[7];
    const int Ns   = in_sizes[0] / 2048;
    const int Nt   = in_sizes[1] / 2048;
    const int Mtot = Ns + Nt + 1;

    float* H   = (float*)d_ws;
    float* Emb = H + (size_t)Mtot * EDIM;

    float* out_aligns = (float*)d_out;
    float* out_costs  = out_aligns + (size_t)P * LMAXP1 * LMAXP1;
    float* out_geds   = out_costs  + (size_t)P * LMAXP1 * LMAXP1;

    const dim3 b256(256);
    const dim3 g1((Mtot + 63) / 64, EDIM / 64);
    k_embed_gemm<<<g1, b256, 0, stream>>>(x_s, Ns, x_t, Nt, ve, W1, b1, H, Mtot, 2048);
    k_embed_gemm<<<g1, b256, 0, stream>>>(H, Mtot, nullptr, 0, nullptr, W2, b2, Emb, Mtot, 256);
    k_costs<<<dim3(P), dim3(256), 0, stream>>>(Emb, len_s, len_t, Ns, Nt, out_costs);
    k_lap<<<dim3(P), dim3(64), 0, stream>>>(out_costs, len_s, len_t, out_aligns, out_geds);
}

// Round 8
// 334.134 us; speedup vs baseline: 1.7230x; 1.3962x over previous
//
#include <hip/hip_runtime.h>
#include <math.h>

#define LMAXP1 33
#define EDIM   256
#define FBIG   3.0e38f

// ---------------------------------------------------------------------------
// GEMM (NT, fused bias+relu): C[Mtot x 256] = relu(A @ W^T + b)
// 256 threads, 64x64 tile, BK=16, 4x4 micro-tile (R4/R7 proven shape).
// ---------------------------------------------------------------------------
__global__ __launch_bounds__(256)
void k_embed_gemm(const float* __restrict__ S0, int n0,
                  const float* __restrict__ S1, int n1,
                  const float* __restrict__ S2,
                  const float* __restrict__ W, const float* __restrict__ bias,
                  float* __restrict__ C, int Mtot, int K) {
    __shared__ alignas(16) float As[16][68];   // transposed: As[k][row]
    __shared__ alignas(16) float Bs[16][68];
    const int tid  = threadIdx.x;
    const int tx   = tid & 15, ty = tid >> 4;
    const int m0   = blockIdx.x * 64, nc0 = blockIdx.y * 64;
    const int lrow = tid >> 2;            // 0..63
    const int lk4  = (tid & 3) << 2;      // 0,4,8,12

    const int gr = m0 + lrow;
    const float* srow = nullptr;
    if (gr < n0)            srow = S0 + (size_t)gr * K;
    else if (gr < n0 + n1)  srow = S1 + (size_t)(gr - n0) * K;
    else if (gr < Mtot)     srow = S2;               // single virtual row
    const float* wrow = W + (size_t)(nc0 + lrow) * K;

    float acc[4][4] = {};
    for (int k0 = 0; k0 < K; k0 += 16) {
        float4 va = make_float4(0.f, 0.f, 0.f, 0.f);
        if (srow) va = *(const float4*)(srow + k0 + lk4);
        const float4 vb = *(const float4*)(wrow + k0 + lk4);
        As[lk4+0][lrow] = va.x; As[lk4+1][lrow] = va.y;
        As[lk4+2][lrow] = va.z; As[lk4+3][lrow] = va.w;
        Bs[lk4+0][lrow] = vb.x; Bs[lk4+1][lrow] = vb.y;
        Bs[lk4+2][lrow] = vb.z; Bs[lk4+3][lrow] = vb.w;
        __syncthreads();
        #pragma unroll
        for (int kk = 0; kk < 16; ++kk) {
            const float4 a4 = *(const float4*)&As[kk][ty << 2];
            const float4 b4 = *(const float4*)&Bs[kk][tx << 2];
            const float av[4] = {a4.x, a4.y, a4.z, a4.w};
            const float bv[4] = {b4.x, b4.y, b4.z, b4.w};
            #pragma unroll
            for (int i2 = 0; i2 < 4; ++i2)
                #pragma unroll
                for (int j2 = 0; j2 < 4; ++j2)
                    acc[i2][j2] = fmaf(av[i2], bv[j2], acc[i2][j2]);
        }
        __syncthreads();
    }
    #pragma unroll
    for (int i2 = 0; i2 < 4; ++i2) {
        const int grr = m0 + (ty << 2) + i2;
        if (grr >= Mtot) continue;
        #pragma unroll
        for (int j2 = 0; j2 < 4; ++j2) {
            const int gc = nc0 + (tx << 2) + j2;
            const float vv = acc[i2][j2] + bias[gc];
            C[(size_t)grr * EDIM + gc] = fmaxf(vv, 0.0f);
        }
    }
}

// ---------------------------------------------------------------------------
// Per-pair scaled edit-cost matrix (33x33), written dense (zeros outside valid)
// Emb layout: rows [0,Ns) = source, [Ns, Ns+Nt) = target, row Ns+Nt = virtual.
// ---------------------------------------------------------------------------
__global__ __launch_bounds__(256)
void k_costs(const float* __restrict__ Emb, const int* __restrict__ len_s,
             const int* __restrict__ len_t, int Ns, int Nt,
             float* __restrict__ costs) {
    __shared__ alignas(16) float Asl[LMAXP1 * EDIM];      // ~33.8 KB
    __shared__ float dtile[LMAXP1 * LMAXP1];
    __shared__ float na[LMAXP1], nb[LMAXP1];
    __shared__ float red[256];
    __shared__ float s_scale;
    const int p = blockIdx.x, tid = threadIdx.x;
    const int n = len_s[p], m = len_t[p];
    int offs = 0, offt = 0;
    for (int j = 0; j < p; ++j) { offs += len_s[j]; offt += len_t[j]; }  // uniform
    const int veRow = Ns + Nt;
    const int tbase = Ns + offt;                 // target rows base

    for (int idx = tid; idx < (n + 1) * (EDIM / 4); idx += 256) {
        const int r = idx >> 6, c = idx & 63;
        const float* src = (r < n) ? (Emb + (size_t)(offs + r) * EDIM)
                                   : (Emb + (size_t)veRow * EDIM);
        ((float4*)Asl)[r * 64 + c] = ((const float4*)src)[c];
    }
    __syncthreads();

    if (tid <= n) {                                  // ||a_i||^2
        const float4* a4 = (const float4*)(Asl + tid * EDIM);
        float s = 0.f;
        for (int k = 0; k < 64; ++k) {
            const float4 a = a4[k];
            s = fmaf(a.x, a.x, s); s = fmaf(a.y, a.y, s);
            s = fmaf(a.z, a.z, s); s = fmaf(a.w, a.w, s);
        }
        na[tid] = s;
    } else if (tid >= 64 && tid - 64 <= m) {          // ||b_j||^2
        const int j = tid - 64;
        const float* src = (j < m) ? (Emb + (size_t)(tbase + j) * EDIM)
                                   : (Emb + (size_t)veRow * EDIM);
        const float4* b4 = (const float4*)src;
        float s = 0.f;
        for (int k = 0; k < 64; ++k) {
            const float4 b = b4[k];
            s = fmaf(b.x, b.x, s); s = fmaf(b.y, b.y, s);
            s = fmaf(b.z, b.z, s); s = fmaf(b.w, b.w, s);
        }
        nb[j] = s;
    }
    __syncthreads();

    float lsum = 0.f;
    const int m1 = m + 1;
    const int cells = (n + 1) * m1;
    for (int c = tid; c < cells; c += 256) {
        const int i = c / m1, j = c - i * m1;
        const float* brow = (j < m) ? (Emb + (size_t)(tbase + j) * EDIM)
                                    : (Emb + (size_t)veRow * EDIM);
        const float4* a4 = (const float4*)(Asl + i * EDIM);
        const float4* b4 = (const float4*)brow;
        float dot = 0.f;
        #pragma unroll 8
        for (int k = 0; k < 64; ++k) {
            const float4 a = a4[k], b = b4[k];
            dot = fmaf(a.x, b.x, dot); dot = fmaf(a.y, b.y, dot);
            dot = fmaf(a.z, b.z, dot); dot = fmaf(a.w, b.w, dot);
        }
        const float sq = fmaxf(na[i] + nb[j] - 2.0f * dot, 0.0f);
        const float d  = (sq > 0.0f) ? sqrtf(sq) : 0.0f;
        dtile[i * LMAXP1 + j] = d;
        lsum += d;
    }
    red[tid] = lsum;
    __syncthreads();
    for (int s = 128; s > 0; s >>= 1) {
        if (tid < s) red[tid] += red[tid + s];
        __syncthreads();
    }
    if (tid == 0) s_scale = (float)(n * m) / red[0];
    __syncthreads();
    const float scale = s_scale;
    for (int idx = tid; idx < LMAXP1 * LMAXP1; idx += 256) {
        const int i = idx / LMAXP1, j = idx - i * LMAXP1;
        const float v = (i <= n && j <= m) ? dtile[i * LMAXP1 + j] * scale : 0.0f;
        costs[(size_t)p * (LMAXP1 * LMAXP1) + idx] = v;
    }
}

// ---------------------------------------------------------------------------
// LAP via EXACT LSAPE reduction to a max(n,m)^2 square LAP:
//   n<=m: rows 1..n real, rows n+1..m padding.
//     M[i][j] = min(sub_ij, del_i + ins_j)  (real),  M[pad][j] = ins_j
//   n>m : transposed roles (rows=targets, cols=sources; del<->ins swapped).
// Equal optimum to the reference's (n+m)^2 LAP (pair deleted rows with
// inserted cols; counts match since |I|-|D| = m-n). Unique optimum (continuous
// random costs; empirically confirmed in R5) => decoded aligns == reference.
// Dijkstra core identical to the R7-verified one (packed u32 DPP argmin,
// carried (i0,u_i0), register dual state). R <= 32 so ~3.5x fewer steps.
// ---------------------------------------------------------------------------
__device__ inline int rdlane_i(int v, int l) { return __builtin_amdgcn_readlane(v, l); }
__device__ inline float rdlane_f(float v, int l) {
    return __int_as_float(__builtin_amdgcn_readlane(__float_as_int(v), l));
}
__device__ inline unsigned wave_umin64(unsigned x) {
#define DPPMINU(ctrl) { unsigned t_ = (unsigned)__builtin_amdgcn_update_dpp(  \
        (int)x, (int)x, (ctrl), 0xf, 0xf, false);                             \
        x = (t_ < x) ? t_ : x; }
    DPPMINU(0xB1)   // quad_perm xor1
    DPPMINU(0x4E)   // quad_perm xor2
    DPPMINU(0x141)  // row_half_mirror xor4
    DPPMINU(0x140)  // row_mirror xor8
    DPPMINU(0x142)  // row_bcast15
    DPPMINU(0x143)  // row_bcast31
#undef DPPMINU
    return (unsigned)__builtin_amdgcn_readlane((int)x, 63);
}

__global__ __launch_bounds__(64)
void k_lap(const float* __restrict__ costs, const int* __restrict__ len_s,
           const int* __restrict__ len_t, float* __restrict__ aligns,
           float* __restrict__ geds) {
    __shared__ float ec[LMAXP1 * LMAXP1];
    __shared__ float Ms[33 * 64];           // rows 1..R (R<=32) at [r*64 + col]
    const int p = blockIdx.x, lane = threadIdx.x;
    const int n = len_s[p], m = len_t[p];
    const float* cp = costs + (size_t)p * (LMAXP1 * LMAXP1);
    for (int idx = lane; idx < LMAXP1 * LMAXP1; idx += 64) ec[idx] = cp[idx];
    __syncthreads();

    const bool swp = (n > m);
    const int R  = swp ? n : m;             // square size (cols & rows)
    const int S_ = swp ? m : n;             // # real rows
    const bool vec = (lane >= 1 && lane <= R);

    // Build reduced R x R matrix (all finite, all >= 0).
    for (int r = 1; r <= R; ++r) {
        float cv = FBIG;
        const int i0b = r - 1, j0b = lane - 1;
        if (vec) {
            if (!swp) {
                const float ins = ec[n * LMAXP1 + j0b];          // insert target j0b
                cv = (i0b < S_)
                   ? fminf(ec[i0b * LMAXP1 + j0b], ec[i0b * LMAXP1 + m] + ins)
                   : ins;
            } else {
                const float ins = ec[j0b * LMAXP1 + m];          // delete source j0b
                cv = (i0b < S_)
                   ? fminf(ec[j0b * LMAXP1 + i0b], ec[n * LMAXP1 + i0b] + ins)
                   : ins;
            }
        }
        Ms[(r << 6) + lane] = cv;
    }
    __syncthreads();

    // Per-lane state, index = lane (0..R). Lane 0 = dummy slot 0.
    float v_l = 0.0f, minv_l = FBIG, ucol = 0.0f;   // ucol = u[p[lane]]
    int p_l = 0, way_l = 0;

    for (int i = 1; i <= R; ++i) {
        if (lane == 0) { p_l = i; ucol = 0.0f; }    // p[0]=i, u[i]=0
        minv_l = FBIG;
        int used_l = 0;
        int j0 = 0, i0 = i;                          // i0 = p[j0]
        float u_i0 = 0.0f;                           // u[p[j0]]
        while (true) {
            if (lane == j0) used_l = 1;              // used[j0] = True
            const float cur = Ms[(i0 << 6) + lane] - u_i0 - v_l;
            const bool unused = vec && !used_l;
            if (unused && cur < minv_l) { minv_l = cur; way_l = j0; }
            // packed min+argmin (values >= 0; clamp guards fp rounding)
            const float mval = unused ? fmaxf(minv_l, 0.0f) : FBIG;
            const unsigned key = (__float_as_uint(mval) & ~63u) | (unsigned)lane;
            const unsigned kmin = wave_umin64(key);
            const int j1 = (int)(kmin & 63u);
            const float delta = rdlane_f(minv_l, j1);   // exact min value
            if (used_l) { ucol += delta; v_l -= delta; }
            if (unused) minv_l -= delta;
            j0 = j1;
            i0 = rdlane_i(p_l, j1);
            u_i0 = rdlane_f(ucol, j1);
            if (i0 == 0) break;                      // p[j0] == 0 -> augment
        }
        // augment: while j0: j1=way[j0]; p[j0]=p[j1]; j0=j1  (u follows p)
        int jj = j0;
        while (jj != 0) {
            const int   j1a = rdlane_i(way_l, jj);
            const int   pn  = rdlane_i(p_l, j1a);    // lane0 holds p[0]=i
            const float un  = rdlane_f(ucol, j1a);
            if (lane == jj) { p_l = pn; ucol = un; }
            jj = j1a;
        }
    }

    // ---- decode to aligns (0/1 as float) + geds ----
    float* ap = aligns + (size_t)p * (LMAXP1 * LMAXP1);
    for (int idx = lane; idx < LMAXP1 * LMAXP1; idx += 64) ap[idx] = 0.0f;
    __syncthreads();
    float gedv = 0.0f;
    if (vec) {
        const int i0b = p_l - 1;                 // matched row (0-based)
        const int j0b = lane - 1;                // this column (0-based)
        if (!swp) {
            // rows = sources, cols = targets
            if (i0b < S_) {
                const float sub = ec[i0b * LMAXP1 + j0b];
                const float alt = ec[i0b * LMAXP1 + m] + ec[n * LMAXP1 + j0b];
                if (sub <= alt) { ap[i0b * LMAXP1 + j0b] = 1.0f; gedv = sub; }
                else { ap[i0b * LMAXP1 + m] = 1.0f;              // delete src i0b
                       ap[n * LMAXP1 + j0b] = 1.0f;              // insert tgt j0b
                       gedv = alt; }
            } else {                                             // padding row
                ap[n * LMAXP1 + j0b] = 1.0f;                     // insert tgt j0b
                gedv = ec[n * LMAXP1 + j0b];
            }
        } else {
            // rows = targets, cols = sources (transposed)
            if (i0b < S_) {
                const float sub = ec[j0b * LMAXP1 + i0b];
                const float alt = ec[n * LMAXP1 + i0b] + ec[j0b * LMAXP1 + m];
                if (sub <= alt) { ap[j0b * LMAXP1 + i0b] = 1.0f; gedv = sub; }
                else { ap[n * LMAXP1 + i0b] = 1.0f;              // insert tgt i0b
                       ap[j0b * LMAXP1 + m] = 1.0f;              // delete src j0b
                       gedv = alt; }
            } else {                                             // padding row
                ap[j0b * LMAXP1 + m] = 1.0f;                     // delete src j0b
                gedv = ec[j0b * LMAXP1 + m];
            }
        }
    }
    #pragma unroll
    for (int off = 32; off > 0; off >>= 1) gedv += __shfl_xor(gedv, off);
    if (lane == 0) geds[p] = gedv / (float)(n + m);
}

// ---------------------------------------------------------------------------
extern "C" void kernel_launch(void* const* d_in, const int* in_sizes, int n_in,
                              void* d_out, int out_size, void* d_ws, size_t ws_size,
                              hipStream_t stream) {
    const float* x_s = (const float*)d_in[0];
    const float* x_t = (const float*)d_in[1];
    const float* W1  = (const float*)d_in[2];
    const float* b1  = (const float*)d_in[3];
    const float* W2  = (const float*)d_in[4];
    const float* b2  = (const float*)d_in[5];
    const float* ve  = (const float*)d_in[6];
    const int* len_s = (const int*)d_in[7];
    const int* len_t = (const int*)d_in[8];
    const int P    = in_sizes[7];
    const int Ns   = in_sizes[0] / 2048;
    const int Nt   = in_sizes[1] / 2048;
    const int Mtot = Ns + Nt + 1;

    float* H   = (float*)d_ws;
    float* Emb = H + (size_t)Mtot * EDIM;

    float* out_aligns = (float*)d_out;
    float* out_costs  = out_aligns + (size_t)P * LMAXP1 * LMAXP1;
    float* out_geds   = out_costs  + (size_t)P * LMAXP1 * LMAXP1;

    const dim3 b256(256);
    const dim3 g1((Mtot + 63) / 64, EDIM / 64);
    k_embed_gemm<<<g1, b256, 0, stream>>>(x_s, Ns, x_t, Nt, ve, W1, b1, H, Mtot, 2048);
    k_embed_gemm<<<g1, b256, 0, stream>>>(H, Mtot, nullptr, 0, nullptr, W2, b2, Emb, Mtot, 256);
    k_costs<<<dim3(P), dim3(256), 0, stream>>>(Emb, len_s, len_t, Ns, Nt, out_costs);
    k_lap<<<dim3(P), dim3(64), 0, stream>>>(out_costs, len_s, len_t, out_aligns, out_geds);
}

// Round 9
// 310.449 us; speedup vs baseline: 1.8544x; 1.0763x over previous
//
#include <hip/hip_runtime.h>
#include <math.h>

#define LMAXP1 33
#define EDIM   256
#define FBIG   3.0e38f

// ---------------------------------------------------------------------------
// Split-K GEMM (NT): Part[ks] += A @ W^T over K-chunk ks. No bias/relu here.
// 256 threads, 64x64 tile, BK=16, 4x4 micro-tile (proven R4/R7 inner loop).
// ---------------------------------------------------------------------------
__global__ __launch_bounds__(256)
void k_gemm_splitk(const float* __restrict__ S0, int n0,
                   const float* __restrict__ S1, int n1,
                   const float* __restrict__ S2,
                   const float* __restrict__ W,
                   float* __restrict__ Part, int Mtot, int K, int kchunk) {
    __shared__ alignas(16) float As[16][68];   // transposed: As[k][row]
    __shared__ alignas(16) float Bs[16][68];
    const int tid  = threadIdx.x;
    const int tx   = tid & 15, ty = tid >> 4;
    const int m0   = blockIdx.x * 64, nc0 = blockIdx.y * 64;
    const int ks   = blockIdx.z;
    const int kb   = ks * kchunk;
    const int ke   = (kb + kchunk < K) ? kb + kchunk : K;
    const int lrow = tid >> 2;            // 0..63
    const int lk4  = (tid & 3) << 2;      // 0,4,8,12

    const int gr = m0 + lrow;
    const float* srow = nullptr;
    if (gr < n0)            srow = S0 + (size_t)gr * K;
    else if (gr < n0 + n1)  srow = S1 + (size_t)(gr - n0) * K;
    else if (gr < Mtot)     srow = S2;               // single virtual row
    const float* wrow = W + (size_t)(nc0 + lrow) * K;

    float acc[4][4] = {};
    for (int k0 = kb; k0 < ke; k0 += 16) {
        float4 va = make_float4(0.f, 0.f, 0.f, 0.f);
        if (srow) va = *(const float4*)(srow + k0 + lk4);
        const float4 vb = *(const float4*)(wrow + k0 + lk4);
        As[lk4+0][lrow] = va.x; As[lk4+1][lrow] = va.y;
        As[lk4+2][lrow] = va.z; As[lk4+3][lrow] = va.w;
        Bs[lk4+0][lrow] = vb.x; Bs[lk4+1][lrow] = vb.y;
        Bs[lk4+2][lrow] = vb.z; Bs[lk4+3][lrow] = vb.w;
        __syncthreads();
        #pragma unroll
        for (int kk = 0; kk < 16; ++kk) {
            const float4 a4 = *(const float4*)&As[kk][ty << 2];
            const float4 b4 = *(const float4*)&Bs[kk][tx << 2];
            const float av[4] = {a4.x, a4.y, a4.z, a4.w};
            const float bv[4] = {b4.x, b4.y, b4.z, b4.w};
            #pragma unroll
            for (int i2 = 0; i2 < 4; ++i2)
                #pragma unroll
                for (int j2 = 0; j2 < 4; ++j2)
                    acc[i2][j2] = fmaf(av[i2], bv[j2], acc[i2][j2]);
        }
        __syncthreads();
    }
    float* pout = Part + (size_t)ks * ((size_t)Mtot * EDIM);
    #pragma unroll
    for (int i2 = 0; i2 < 4; ++i2) {
        const int grr = m0 + (ty << 2) + i2;
        if (grr >= Mtot) continue;
        #pragma unroll
        for (int j2 = 0; j2 < 4; ++j2) {
            const int gc = nc0 + (tx << 2) + j2;
            pout[(size_t)grr * EDIM + gc] = acc[i2][j2];
        }
    }
}

// Reduce split-K partials + bias + relu. Deterministic fixed-order sum.
__global__ __launch_bounds__(256)
void k_reduce_bias_relu(const float* __restrict__ Part,
                        const float* __restrict__ bias,
                        float* __restrict__ C, int S, size_t MN4) {
    const size_t i = (size_t)blockIdx.x * blockDim.x + threadIdx.x;
    const size_t stride = (size_t)gridDim.x * blockDim.x;
    const size_t MN = MN4 * 4;
    for (size_t i4 = i; i4 < MN4; i4 += stride) {
        float4 s = ((const float4*)Part)[i4];
        for (int z = 1; z < S; ++z)
            { const float4 q = ((const float4*)(Part + (size_t)z * MN))[i4];
              s.x += q.x; s.y += q.y; s.z += q.z; s.w += q.w; }
        const float4 b = ((const float4*)bias)[i4 & 63];   // EDIM/4 = 64
        s.x = fmaxf(s.x + b.x, 0.f); s.y = fmaxf(s.y + b.y, 0.f);
        s.z = fmaxf(s.z + b.z, 0.f); s.w = fmaxf(s.w + b.w, 0.f);
        ((float4*)C)[i4] = s;
    }
}

// ---------------------------------------------------------------------------
// Direct GEMM (NT, fused bias+relu) — fallback / layer 2 (K=256).
// ---------------------------------------------------------------------------
__global__ __launch_bounds__(256)
void k_embed_gemm(const float* __restrict__ S0, int n0,
                  const float* __restrict__ S1, int n1,
                  const float* __restrict__ S2,
                  const float* __restrict__ W, const float* __restrict__ bias,
                  float* __restrict__ C, int Mtot, int K) {
    __shared__ alignas(16) float As[16][68];
    __shared__ alignas(16) float Bs[16][68];
    const int tid  = threadIdx.x;
    const int tx   = tid & 15, ty = tid >> 4;
    const int m0   = blockIdx.x * 64, nc0 = blockIdx.y * 64;
    const int lrow = tid >> 2;
    const int lk4  = (tid & 3) << 2;

    const int gr = m0 + lrow;
    const float* srow = nullptr;
    if (gr < n0)            srow = S0 + (size_t)gr * K;
    else if (gr < n0 + n1)  srow = S1 + (size_t)(gr - n0) * K;
    else if (gr < Mtot)     srow = S2;
    const float* wrow = W + (size_t)(nc0 + lrow) * K;

    float acc[4][4] = {};
    for (int k0 = 0; k0 < K; k0 += 16) {
        float4 va = make_float4(0.f, 0.f, 0.f, 0.f);
        if (srow) va = *(const float4*)(srow + k0 + lk4);
        const float4 vb = *(const float4*)(wrow + k0 + lk4);
        As[lk4+0][lrow] = va.x; As[lk4+1][lrow] = va.y;
        As[lk4+2][lrow] = va.z; As[lk4+3][lrow] = va.w;
        Bs[lk4+0][lrow] = vb.x; Bs[lk4+1][lrow] = vb.y;
        Bs[lk4+2][lrow] = vb.z; Bs[lk4+3][lrow] = vb.w;
        __syncthreads();
        #pragma unroll
        for (int kk = 0; kk < 16; ++kk) {
            const float4 a4 = *(const float4*)&As[kk][ty << 2];
            const float4 b4 = *(const float4*)&Bs[kk][tx << 2];
            const float av[4] = {a4.x, a4.y, a4.z, a4.w};
            const float bv[4] = {b4.x, b4.y, b4.z, b4.w};
            #pragma unroll
            for (int i2 = 0; i2 < 4; ++i2)
                #pragma unroll
                for (int j2 = 0; j2 < 4; ++j2)
                    acc[i2][j2] = fmaf(av[i2], bv[j2], acc[i2][j2]);
        }
        __syncthreads();
    }
    #pragma unroll
    for (int i2 = 0; i2 < 4; ++i2) {
        const int grr = m0 + (ty << 2) + i2;
        if (grr >= Mtot) continue;
        #pragma unroll
        for (int j2 = 0; j2 < 4; ++j2) {
            const int gc = nc0 + (tx << 2) + j2;
            const float vv = acc[i2][j2] + bias[gc];
            C[(size_t)grr * EDIM + gc] = fmaxf(vv, 0.0f);
        }
    }
}

// ---------------------------------------------------------------------------
// Per-pair scaled edit-cost matrix (33x33), written dense (zeros outside valid)
// ---------------------------------------------------------------------------
__global__ __launch_bounds__(256)
void k_costs(const float* __restrict__ Emb, const int* __restrict__ len_s,
             const int* __restrict__ len_t, int Ns, int Nt,
             float* __restrict__ costs) {
    __shared__ alignas(16) float Asl[LMAXP1 * EDIM];
    __shared__ float dtile[LMAXP1 * LMAXP1];
    __shared__ float na[LMAXP1], nb[LMAXP1];
    __shared__ float red[256];
    __shared__ float s_scale;
    const int p = blockIdx.x, tid = threadIdx.x;
    const int n = len_s[p], m = len_t[p];
    int offs = 0, offt = 0;
    for (int j = 0; j < p; ++j) { offs += len_s[j]; offt += len_t[j]; }
    const int veRow = Ns + Nt;
    const int tbase = Ns + offt;

    for (int idx = tid; idx < (n + 1) * (EDIM / 4); idx += 256) {
        const int r = idx >> 6, c = idx & 63;
        const float* src = (r < n) ? (Emb + (size_t)(offs + r) * EDIM)
                                   : (Emb + (size_t)veRow * EDIM);
        ((float4*)Asl)[r * 64 + c] = ((const float4*)src)[c];
    }
    __syncthreads();

    if (tid <= n) {
        const float4* a4 = (const float4*)(Asl + tid * EDIM);
        float s = 0.f;
        for (int k = 0; k < 64; ++k) {
            const float4 a = a4[k];
            s = fmaf(a.x, a.x, s); s = fmaf(a.y, a.y, s);
            s = fmaf(a.z, a.z, s); s = fmaf(a.w, a.w, s);
        }
        na[tid] = s;
    } else if (tid >= 64 && tid - 64 <= m) {
        const int j = tid - 64;
        const float* src = (j < m) ? (Emb + (size_t)(tbase + j) * EDIM)
                                   : (Emb + (size_t)veRow * EDIM);
        const float4* b4 = (const float4*)src;
        float s = 0.f;
        for (int k = 0; k < 64; ++k) {
            const float4 b = b4[k];
            s = fmaf(b.x, b.x, s); s = fmaf(b.y, b.y, s);
            s = fmaf(b.z, b.z, s); s = fmaf(b.w, b.w, s);
        }
        nb[j] = s;
    }
    __syncthreads();

    float lsum = 0.f;
    const int m1 = m + 1;
    const int cells = (n + 1) * m1;
    for (int c = tid; c < cells; c += 256) {
        const int i = c / m1, j = c - i * m1;
        const float* brow = (j < m) ? (Emb + (size_t)(tbase + j) * EDIM)
                                    : (Emb + (size_t)veRow * EDIM);
        const float4* a4 = (const float4*)(Asl + i * EDIM);
        const float4* b4 = (const float4*)brow;
        float dot = 0.f;
        #pragma unroll 8
        for (int k = 0; k < 64; ++k) {
            const float4 a = a4[k], b = b4[k];
            dot = fmaf(a.x, b.x, dot); dot = fmaf(a.y, b.y, dot);
            dot = fmaf(a.z, b.z, dot); dot = fmaf(a.w, b.w, dot);
        }
        const float sq = fmaxf(na[i] + nb[j] - 2.0f * dot, 0.0f);
        const float d  = (sq > 0.0f) ? sqrtf(sq) : 0.0f;
        dtile[i * LMAXP1 + j] = d;
        lsum += d;
    }
    red[tid] = lsum;
    __syncthreads();
    for (int s = 128; s > 0; s >>= 1) {
        if (tid < s) red[tid] += red[tid + s];
        __syncthreads();
    }
    if (tid == 0) s_scale = (float)(n * m) / red[0];
    __syncthreads();
    const float scale = s_scale;
    for (int idx = tid; idx < LMAXP1 * LMAXP1; idx += 256) {
        const int i = idx / LMAXP1, j = idx - i * LMAXP1;
        const float v = (i <= n && j <= m) ? dtile[i * LMAXP1 + j] * scale : 0.0f;
        costs[(size_t)p * (LMAXP1 * LMAXP1) + idx] = v;
    }
}

// ---------------------------------------------------------------------------
// LAP via exact LSAPE reduction to max(n,m)^2 square LAP (R8-verified),
// JV Dijkstra core with packed u32 DPP argmin.
// ---------------------------------------------------------------------------
__device__ inline int rdlane_i(int v, int l) { return __builtin_amdgcn_readlane(v, l); }
__device__ inline float rdlane_f(float v, int l) {
    return __int_as_float(__builtin_amdgcn_readlane(__float_as_int(v), l));
}
__device__ inline unsigned wave_umin64(unsigned x) {
#define DPPMINU(ctrl) { unsigned t_ = (unsigned)__builtin_amdgcn_update_dpp(  \
        (int)x, (int)x, (ctrl), 0xf, 0xf, false);                             \
        x = (t_ < x) ? t_ : x; }
    DPPMINU(0xB1)
    DPPMINU(0x4E)
    DPPMINU(0x141)
    DPPMINU(0x140)
    DPPMINU(0x142)
    DPPMINU(0x143)
#undef DPPMINU
    return (unsigned)__builtin_amdgcn_readlane((int)x, 63);
}

__global__ __launch_bounds__(64)
void k_lap(const float* __restrict__ costs, const int* __restrict__ len_s,
           const int* __restrict__ len_t, float* __restrict__ aligns,
           float* __restrict__ geds) {
    __shared__ float ec[LMAXP1 * LMAXP1];
    __shared__ float Ms[33 * 64];
    const int p = blockIdx.x, lane = threadIdx.x;
    const int n = len_s[p], m = len_t[p];
    const float* cp = costs + (size_t)p * (LMAXP1 * LMAXP1);
    for (int idx = lane; idx < LMAXP1 * LMAXP1; idx += 64) ec[idx] = cp[idx];
    __syncthreads();

    const bool swp = (n > m);
    const int R  = swp ? n : m;
    const int S_ = swp ? m : n;
    const bool vec = (lane >= 1 && lane <= R);

    for (int r = 1; r <= R; ++r) {
        float cv = FBIG;
        const int i0b = r - 1, j0b = lane - 1;
        if (vec) {
            if (!swp) {
                const float ins = ec[n * LMAXP1 + j0b];
                cv = (i0b < S_)
                   ? fminf(ec[i0b * LMAXP1 + j0b], ec[i0b * LMAXP1 + m] + ins)
                   : ins;
            } else {
                const float ins = ec[j0b * LMAXP1 + m];
                cv = (i0b < S_)
                   ? fminf(ec[j0b * LMAXP1 + i0b], ec[n * LMAXP1 + i0b] + ins)
                   : ins;
            }
        }
        Ms[(r << 6) + lane] = cv;
    }
    __syncthreads();

    float v_l = 0.0f, minv_l = FBIG, ucol = 0.0f;
    int p_l = 0, way_l = 0;

    for (int i = 1; i <= R; ++i) {
        if (lane == 0) { p_l = i; ucol = 0.0f; }
        minv_l = FBIG;
        int used_l = 0;
        int j0 = 0, i0 = i;
        float u_i0 = 0.0f;
        while (true) {
            if (lane == j0) used_l = 1;
            const float cur = Ms[(i0 << 6) + lane] - u_i0 - v_l;
            const bool unused = vec && !used_l;
            if (unused && cur < minv_l) { minv_l = cur; way_l = j0; }
            const float mval = unused ? fmaxf(minv_l, 0.0f) : FBIG;
            const unsigned key = (__float_as_uint(mval) & ~63u) | (unsigned)lane;
            const unsigned kmin = wave_umin64(key);
            const int j1 = (int)(kmin & 63u);
            const float delta = rdlane_f(minv_l, j1);
            if (used_l) { ucol += delta; v_l -= delta; }
            if (unused) minv_l -= delta;
            j0 = j1;
            i0 = rdlane_i(p_l, j1);
            u_i0 = rdlane_f(ucol, j1);
            if (i0 == 0) break;
        }
        int jj = j0;
        while (jj != 0) {
            const int   j1a = rdlane_i(way_l, jj);
            const int   pn  = rdlane_i(p_l, j1a);
            const float un  = rdlane_f(ucol, j1a);
            if (lane == jj) { p_l = pn; ucol = un; }
            jj = j1a;
        }
    }

    float* ap = aligns + (size_t)p * (LMAXP1 * LMAXP1);
    for (int idx = lane; idx < LMAXP1 * LMAXP1; idx += 64) ap[idx] = 0.0f;
    __syncthreads();
    float gedv = 0.0f;
    if (vec) {
        const int i0b = p_l - 1;
        const int j0b = lane - 1;
        if (!swp) {
            if (i0b < S_) {
                const float sub = ec[i0b * LMAXP1 + j0b];
                const float alt = ec[i0b * LMAXP1 + m] + ec[n * LMAXP1 + j0b];
                if (sub <= alt) { ap[i0b * LMAXP1 + j0b] = 1.0f; gedv = sub; }
                else { ap[i0b * LMAXP1 + m] = 1.0f;
                       ap[n * LMAXP1 + j0b] = 1.0f;
                       gedv = alt; }
            } else {
                ap[n * LMAXP1 + j0b] = 1.0f;
                gedv = ec[n * LMAXP1 + j0b];
            }
        } else {
            if (i0b < S_) {
                const float sub = ec[j0b * LMAXP1 + i0b];
                const float alt = ec[n * LMAXP1 + i0b] + ec[j0b * LMAXP1 + m];
                if (sub <= alt) { ap[j0b * LMAXP1 + i0b] = 1.0f; gedv = sub; }
                else { ap[n * LMAXP1 + i0b] = 1.0f;
                       ap[j0b * LMAXP1 + m] = 1.0f;
                       gedv = alt; }
            } else {
                ap[j0b * LMAXP1 + m] = 1.0f;
                gedv = ec[j0b * LMAXP1 + m];
            }
        }
    }
    #pragma unroll
    for (int off = 32; off > 0; off >>= 1) gedv += __shfl_xor(gedv, off);
    if (lane == 0) geds[p] = gedv / (float)(n + m);
}

// ---------------------------------------------------------------------------
extern "C" void kernel_launch(void* const* d_in, const int* in_sizes, int n_in,
                              void* d_out, int out_size, void* d_ws, size_t ws_size,
                              hipStream_t stream) {
    const float* x_s = (const float*)d_in[0];
    const float* x_t = (const float*)d_in[1];
    const float* W1  = (const float*)d_in[2];
    const float* b1  = (const float*)d_in[3];
    const float* W2  = (const float*)d_in[4];
    const float* b2  = (const float*)d_in[5];
    const float* ve  = (const float*)d_in[6];
    const int* len_s = (const int*)d_in[7];
    const int* len_t = (const int*)d_in[8];
    const int P    = in_sizes[7];
    const int Ns   = in_sizes[0] / 2048;
    const int Nt   = in_sizes[1] / 2048;
    const int Mtot = Ns + Nt + 1;
    const size_t MN  = (size_t)Mtot * EDIM;

    float* H    = (float*)d_ws;
    float* Emb  = H + MN;
    float* Part = Emb + MN;

    // pick largest split that fits ws: need (2 + S)*MN floats
    int S = 1;
    if (ws_size >= (2 + 4) * MN * sizeof(float)) S = 4;
    else if (ws_size >= (2 + 2) * MN * sizeof(float)) S = 2;

    float* out_aligns = (float*)d_out;
    float* out_costs  = out_aligns + (size_t)P * LMAXP1 * LMAXP1;
    float* out_geds   = out_costs  + (size_t)P * LMAXP1 * LMAXP1;

    const dim3 b256(256);
    const int gx = (Mtot + 63) / 64;

    if (S > 1) {
        k_gemm_splitk<<<dim3(gx, 4, S), b256, 0, stream>>>(
            x_s, Ns, x_t, Nt, ve, W1, Part, Mtot, 2048, 2048 / S);
        const size_t MN4 = MN / 4;
        const int rblocks = (int)((MN4 + 255) / 256) < 2048
                          ? (int)((MN4 + 255) / 256) : 2048;
        k_reduce_bias_relu<<<dim3(rblocks), b256, 0, stream>>>(Part, b1, H, S, MN4);
    } else {
        k_embed_gemm<<<dim3(gx, 4), b256, 0, stream>>>(
            x_s, Ns, x_t, Nt, ve, W1, b1, H, Mtot, 2048);
    }
    k_embed_gemm<<<dim3(gx, 4), b256, 0, stream>>>(
        H, Mtot, nullptr, 0, nullptr, W2, b2, Emb, Mtot, 256);
    k_costs<<<dim3(P), b256, 0, stream>>>(Emb, len_s, len_t, Ns, Nt, out_costs);
    k_lap<<<dim3(P), dim3(64), 0, stream>>>(out_costs, len_s, len_t, out_aligns, out_geds);
}

// Round 10
// 297.694 us; speedup vs baseline: 1.9339x; 1.0428x over previous
//
#include <hip/hip_runtime.h>
#include <math.h>

#define LMAXP1 33
#define EDIM   256
#define FBIG   3.0e38f

// ---------------------------------------------------------------------------
// Split-K GEMM v2 (NT): Part[ks] = A @ W^T over K-chunk ks. No bias/relu.
// 256 threads, 128x64 tile, BK=16, 8x4 micro-tile, register-prefetch dbuf.
// ---------------------------------------------------------------------------
__global__ __launch_bounds__(256)
void k_gemm_splitk(const float* __restrict__ S0, int n0,
                   const float* __restrict__ S1, int n1,
                   const float* __restrict__ S2,
                   const float* __restrict__ W,
                   float* __restrict__ Part, int Mtot, int K, int kchunk) {
    __shared__ alignas(16) float As[16][132];  // [k][row], 128 rows (+pad)
    __shared__ alignas(16) float Bs[16][68];   // [k][col], 64 cols (+pad)
    const int tid  = threadIdx.x;
    const int tx   = tid & 15, ty = tid >> 4;   // 16 x 16 thread grid
    const int m0   = blockIdx.x * 128, nc0 = blockIdx.y * 64;
    const int ks   = blockIdx.z;
    const int kb   = ks * kchunk;
    const int ke   = (kb + kchunk < K) ? kb + kchunk : K;
    const int arow = tid >> 1;            // 0..127 (A staging row)
    const int ak8  = (tid & 1) << 3;      // 0 or 8
    const int brow = tid >> 2;            // 0..63  (B staging row)
    const int bk4  = (tid & 3) << 2;      // 0,4,8,12

    const int gr = m0 + arow;
    const float* srow = nullptr;
    if (gr < n0)            srow = S0 + (size_t)gr * K;
    else if (gr < n0 + n1)  srow = S1 + (size_t)(gr - n0) * K;
    else if (gr < Mtot)     srow = S2;               // single virtual row
    const float* wrow = W + (size_t)(nc0 + brow) * K;

    float acc[8][4] = {};
    // prologue: prefetch first tile into regs
    float4 va0 = make_float4(0.f,0.f,0.f,0.f), va1 = va0;
    if (srow) { va0 = *(const float4*)(srow + kb + ak8);
                va1 = *(const float4*)(srow + kb + ak8 + 4); }
    float4 vb = *(const float4*)(wrow + kb + bk4);

    for (int k0 = kb; k0 < ke; k0 += 16) {
        // write staged regs to LDS
        As[ak8+0][arow] = va0.x; As[ak8+1][arow] = va0.y;
        As[ak8+2][arow] = va0.z; As[ak8+3][arow] = va0.w;
        As[ak8+4][arow] = va1.x; As[ak8+5][arow] = va1.y;
        As[ak8+6][arow] = va1.z; As[ak8+7][arow] = va1.w;
        Bs[bk4+0][brow] = vb.x;  Bs[bk4+1][brow] = vb.y;
        Bs[bk4+2][brow] = vb.z;  Bs[bk4+3][brow] = vb.w;
        __syncthreads();
        // prefetch next tile (overlaps compute below)
        const int kn = k0 + 16;
        if (kn < ke) {
            if (srow) { va0 = *(const float4*)(srow + kn + ak8);
                        va1 = *(const float4*)(srow + kn + ak8 + 4); }
            vb = *(const float4*)(wrow + kn + bk4);
        }
        #pragma unroll
        for (int kk = 0; kk < 16; ++kk) {
            const float4 a0 = *(const float4*)&As[kk][ty << 3];
            const float4 a1 = *(const float4*)&As[kk][(ty << 3) + 4];
            const float4 b4 = *(const float4*)&Bs[kk][tx << 2];
            const float av[8] = {a0.x,a0.y,a0.z,a0.w,a1.x,a1.y,a1.z,a1.w};
            const float bv[4] = {b4.x,b4.y,b4.z,b4.w};
            #pragma unroll
            for (int i2 = 0; i2 < 8; ++i2)
                #pragma unroll
                for (int j2 = 0; j2 < 4; ++j2)
                    acc[i2][j2] = fmaf(av[i2], bv[j2], acc[i2][j2]);
        }
        __syncthreads();
    }
    float* pout = Part + (size_t)ks * ((size_t)Mtot * EDIM);
    #pragma unroll
    for (int i2 = 0; i2 < 8; ++i2) {
        const int grr = m0 + (ty << 3) + i2;
        if (grr >= Mtot) continue;
        float4 o; o.x = acc[i2][0]; o.y = acc[i2][1];
                  o.z = acc[i2][2]; o.w = acc[i2][3];
        *(float4*)(pout + (size_t)grr * EDIM + nc0 + (tx << 2)) = o;
    }
}

// Reduce split-K partials + bias + relu. Deterministic fixed-order sum.
__global__ __launch_bounds__(256)
void k_reduce_bias_relu(const float* __restrict__ Part,
                        const float* __restrict__ bias,
                        float* __restrict__ C, int S, size_t MN4) {
    const size_t i = (size_t)blockIdx.x * blockDim.x + threadIdx.x;
    const size_t stride = (size_t)gridDim.x * blockDim.x;
    const size_t MN = MN4 * 4;
    for (size_t i4 = i; i4 < MN4; i4 += stride) {
        float4 s = ((const float4*)Part)[i4];
        for (int z = 1; z < S; ++z)
            { const float4 q = ((const float4*)(Part + (size_t)z * MN))[i4];
              s.x += q.x; s.y += q.y; s.z += q.z; s.w += q.w; }
        const float4 b = ((const float4*)bias)[i4 & 63];   // EDIM/4 = 64
        s.x = fmaxf(s.x + b.x, 0.f); s.y = fmaxf(s.y + b.y, 0.f);
        s.z = fmaxf(s.z + b.z, 0.f); s.w = fmaxf(s.w + b.w, 0.f);
        ((float4*)C)[i4] = s;
    }
}

// ---------------------------------------------------------------------------
// Direct GEMM (NT, fused bias+relu) — layer 2 (K=256) / fallback.
// ---------------------------------------------------------------------------
__global__ __launch_bounds__(256)
void k_embed_gemm(const float* __restrict__ S0, int n0,
                  const float* __restrict__ S1, int n1,
                  const float* __restrict__ S2,
                  const float* __restrict__ W, const float* __restrict__ bias,
                  float* __restrict__ C, int Mtot, int K) {
    __shared__ alignas(16) float As[16][68];
    __shared__ alignas(16) float Bs[16][68];
    const int tid  = threadIdx.x;
    const int tx   = tid & 15, ty = tid >> 4;
    const int m0   = blockIdx.x * 64, nc0 = blockIdx.y * 64;
    const int lrow = tid >> 2;
    const int lk4  = (tid & 3) << 2;

    const int gr = m0 + lrow;
    const float* srow = nullptr;
    if (gr < n0)            srow = S0 + (size_t)gr * K;
    else if (gr < n0 + n1)  srow = S1 + (size_t)(gr - n0) * K;
    else if (gr < Mtot)     srow = S2;
    const float* wrow = W + (size_t)(nc0 + lrow) * K;

    float acc[4][4] = {};
    for (int k0 = 0; k0 < K; k0 += 16) {
        float4 va = make_float4(0.f, 0.f, 0.f, 0.f);
        if (srow) va = *(const float4*)(srow + k0 + lk4);
        const float4 vb = *(const float4*)(wrow + k0 + lk4);
        As[lk4+0][lrow] = va.x; As[lk4+1][lrow] = va.y;
        As[lk4+2][lrow] = va.z; As[lk4+3][lrow] = va.w;
        Bs[lk4+0][lrow] = vb.x; Bs[lk4+1][lrow] = vb.y;
        Bs[lk4+2][lrow] = vb.z; Bs[lk4+3][lrow] = vb.w;
        __syncthreads();
        #pragma unroll
        for (int kk = 0; kk < 16; ++kk) {
            const float4 a4 = *(const float4*)&As[kk][ty << 2];
            const float4 b4 = *(const float4*)&Bs[kk][tx << 2];
            const float av[4] = {a4.x, a4.y, a4.z, a4.w};
            const float bv[4] = {b4.x, b4.y, b4.z, b4.w};
            #pragma unroll
            for (int i2 = 0; i2 < 4; ++i2)
                #pragma unroll
                for (int j2 = 0; j2 < 4; ++j2)
                    acc[i2][j2] = fmaf(av[i2], bv[j2], acc[i2][j2]);
        }
        __syncthreads();
    }
    #pragma unroll
    for (int i2 = 0; i2 < 4; ++i2) {
        const int grr = m0 + (ty << 2) + i2;
        if (grr >= Mtot) continue;
        #pragma unroll
        for (int j2 = 0; j2 < 4; ++j2) {
            const int gc = nc0 + (tx << 2) + j2;
            const float vv = acc[i2][j2] + bias[gc];
            C[(size_t)grr * EDIM + gc] = fmaxf(vv, 0.0f);
        }
    }
}

// ---------------------------------------------------------------------------
// Per-pair scaled edit-cost matrix (33x33), written dense (zeros outside valid)
// ---------------------------------------------------------------------------
__global__ __launch_bounds__(256)
void k_costs(const float* __restrict__ Emb, const int* __restrict__ len_s,
             const int* __restrict__ len_t, int Ns, int Nt,
             float* __restrict__ costs) {
    __shared__ alignas(16) float Asl[LMAXP1 * EDIM];
    __shared__ float dtile[LMAXP1 * LMAXP1];
    __shared__ float na[LMAXP1], nb[LMAXP1];
    __shared__ float red[256];
    __shared__ float s_scale;
    const int p = blockIdx.x, tid = threadIdx.x;
    const int n = len_s[p], m = len_t[p];
    int offs = 0, offt = 0;
    for (int j = 0; j < p; ++j) { offs += len_s[j]; offt += len_t[j]; }
    const int veRow = Ns + Nt;
    const int tbase = Ns + offt;

    for (int idx = tid; idx < (n + 1) * (EDIM / 4); idx += 256) {
        const int r = idx >> 6, c = idx & 63;
        const float* src = (r < n) ? (Emb + (size_t)(offs + r) * EDIM)
                                   : (Emb + (size_t)veRow * EDIM);
        ((float4*)Asl)[r * 64 + c] = ((const float4*)src)[c];
    }
    __syncthreads();

    if (tid <= n) {
        const float4* a4 = (const float4*)(Asl + tid * EDIM);
        float s = 0.f;
        for (int k = 0; k < 64; ++k) {
            const float4 a = a4[k];
            s = fmaf(a.x, a.x, s); s = fmaf(a.y, a.y, s);
            s = fmaf(a.z, a.z, s); s = fmaf(a.w, a.w, s);
        }
        na[tid] = s;
    } else if (tid >= 64 && tid - 64 <= m) {
        const int j = tid - 64;
        const float* src = (j < m) ? (Emb + (size_t)(tbase + j) * EDIM)
                                   : (Emb + (size_t)veRow * EDIM);
        const float4* b4 = (const float4*)src;
        float s = 0.f;
        for (int k = 0; k < 64; ++k) {
            const float4 b = b4[k];
            s = fmaf(b.x, b.x, s); s = fmaf(b.y, b.y, s);
            s = fmaf(b.z, b.z, s); s = fmaf(b.w, b.w, s);
        }
        nb[j] = s;
    }
    __syncthreads();

    float lsum = 0.f;
    const int m1 = m + 1;
    const int cells = (n + 1) * m1;
    for (int c = tid; c < cells; c += 256) {
        const int i = c / m1, j = c - i * m1;
        const float* brow = (j < m) ? (Emb + (size_t)(tbase + j) * EDIM)
                                    : (Emb + (size_t)veRow * EDIM);
        const float4* a4 = (const float4*)(Asl + i * EDIM);
        const float4* b4 = (const float4*)brow;
        float dot = 0.f;
        #pragma unroll 8
        for (int k = 0; k < 64; ++k) {
            const float4 a = a4[k], b = b4[k];
            dot = fmaf(a.x, b.x, dot); dot = fmaf(a.y, b.y, dot);
            dot = fmaf(a.z, b.z, dot); dot = fmaf(a.w, b.w, dot);
        }
        const float sq = fmaxf(na[i] + nb[j] - 2.0f * dot, 0.0f);
        const float d  = (sq > 0.0f) ? sqrtf(sq) : 0.0f;
        dtile[i * LMAXP1 + j] = d;
        lsum += d;
    }
    red[tid] = lsum;
    __syncthreads();
    for (int s = 128; s > 0; s >>= 1) {
        if (tid < s) red[tid] += red[tid + s];
        __syncthreads();
    }
    if (tid == 0) s_scale = (float)(n * m) / red[0];
    __syncthreads();
    const float scale = s_scale;
    for (int idx = tid; idx < LMAXP1 * LMAXP1; idx += 256) {
        const int i = idx / LMAXP1, j = idx - i * LMAXP1;
        const float v = (i <= n && j <= m) ? dtile[i * LMAXP1 + j] * scale : 0.0f;
        costs[(size_t)p * (LMAXP1 * LMAXP1) + idx] = v;
    }
}

// ---------------------------------------------------------------------------
// LAP via exact LSAPE reduction to max(n,m)^2 square LAP (R8-verified),
// JV Dijkstra core with packed u32 DPP argmin.
// ---------------------------------------------------------------------------
__device__ inline int rdlane_i(int v, int l) { return __builtin_amdgcn_readlane(v, l); }
__device__ inline float rdlane_f(float v, int l) {
    return __int_as_float(__builtin_amdgcn_readlane(__float_as_int(v), l));
}
__device__ inline unsigned wave_umin64(unsigned x) {
#define DPPMINU(ctrl) { unsigned t_ = (unsigned)__builtin_amdgcn_update_dpp(  \
        (int)x, (int)x, (ctrl), 0xf, 0xf, false);                             \
        x = (t_ < x) ? t_ : x; }
    DPPMINU(0xB1)
    DPPMINU(0x4E)
    DPPMINU(0x141)
    DPPMINU(0x140)
    DPPMINU(0x142)
    DPPMINU(0x143)
#undef DPPMINU
    return (unsigned)__builtin_amdgcn_readlane((int)x, 63);
}

__global__ __launch_bounds__(64)
void k_lap(const float* __restrict__ costs, const int* __restrict__ len_s,
           const int* __restrict__ len_t, float* __restrict__ aligns,
           float* __restrict__ geds) {
    __shared__ float ec[LMAXP1 * LMAXP1];
    __shared__ float Ms[33 * 64];
    const int p = blockIdx.x, lane = threadIdx.x;
    const int n = len_s[p], m = len_t[p];
    const float* cp = costs + (size_t)p * (LMAXP1 * LMAXP1);
    for (int idx = lane; idx < LMAXP1 * LMAXP1; idx += 64) ec[idx] = cp[idx];
    __syncthreads();

    const bool swp = (n > m);
    const int R  = swp ? n : m;
    const int S_ = swp ? m : n;
    const bool vec = (lane >= 1 && lane <= R);

    for (int r = 1; r <= R; ++r) {
        float cv = FBIG;
        const int i0b = r - 1, j0b = lane - 1;
        if (vec) {
            if (!swp) {
                const float ins = ec[n * LMAXP1 + j0b];
                cv = (i0b < S_)
                   ? fminf(ec[i0b * LMAXP1 + j0b], ec[i0b * LMAXP1 + m] + ins)
                   : ins;
            } else {
                const float ins = ec[j0b * LMAXP1 + m];
                cv = (i0b < S_)
                   ? fminf(ec[j0b * LMAXP1 + i0b], ec[n * LMAXP1 + i0b] + ins)
                   : ins;
            }
        }
        Ms[(r << 6) + lane] = cv;
    }
    __syncthreads();

    float v_l = 0.0f, minv_l = FBIG, ucol = 0.0f;
    int p_l = 0, way_l = 0;

    for (int i = 1; i <= R; ++i) {
        if (lane == 0) { p_l = i; ucol = 0.0f; }
        minv_l = FBIG;
        int used_l = 0;
        int j0 = 0, i0 = i;
        float u_i0 = 0.0f;
        while (true) {
            if (lane == j0) used_l = 1;
            const float cur = Ms[(i0 << 6) + lane] - u_i0 - v_l;
            const bool unused = vec && !used_l;
            if (unused && cur < minv_l) { minv_l = cur; way_l = j0; }
            const float mval = unused ? fmaxf(minv_l, 0.0f) : FBIG;
            const unsigned key = (__float_as_uint(mval) & ~63u) | (unsigned)lane;
            const unsigned kmin = wave_umin64(key);
            const int j1 = (int)(kmin & 63u);
            const float delta = rdlane_f(minv_l, j1);
            if (used_l) { ucol += delta; v_l -= delta; }
            if (unused) minv_l -= delta;
            j0 = j1;
            i0 = rdlane_i(p_l, j1);
            u_i0 = rdlane_f(ucol, j1);
            if (i0 == 0) break;
        }
        int jj = j0;
        while (jj != 0) {
            const int   j1a = rdlane_i(way_l, jj);
            const int   pn  = rdlane_i(p_l, j1a);
            const float un  = rdlane_f(ucol, j1a);
            if (lane == jj) { p_l = pn; ucol = un; }
            jj = j1a;
        }
    }

    float* ap = aligns + (size_t)p * (LMAXP1 * LMAXP1);
    for (int idx = lane; idx < LMAXP1 * LMAXP1; idx += 64) ap[idx] = 0.0f;
    __syncthreads();
    float gedv = 0.0f;
    if (vec) {
        const int i0b = p_l - 1;
        const int j0b = lane - 1;
        if (!swp) {
            if (i0b < S_) {
                const float sub = ec[i0b * LMAXP1 + j0b];
                const float alt = ec[i0b * LMAXP1 + m] + ec[n * LMAXP1 + j0b];
                if (sub <= alt) { ap[i0b * LMAXP1 + j0b] = 1.0f; gedv = sub; }
                else { ap[i0b * LMAXP1 + m] = 1.0f;
                       ap[n * LMAXP1 + j0b] = 1.0f;
                       gedv = alt; }
            } else {
                ap[n * LMAXP1 + j0b] = 1.0f;
                gedv = ec[n * LMAXP1 + j0b];
            }
        } else {
            if (i0b < S_) {
                const float sub = ec[j0b * LMAXP1 + i0b];
                const float alt = ec[n * LMAXP1 + i0b] + ec[j0b * LMAXP1 + m];
                if (sub <= alt) { ap[j0b * LMAXP1 + i0b] = 1.0f; gedv = sub; }
                else { ap[n * LMAXP1 + i0b] = 1.0f;
                       ap[j0b * LMAXP1 + m] = 1.0f;
                       gedv = alt; }
            } else {
                ap[j0b * LMAXP1 + m] = 1.0f;
                gedv = ec[j0b * LMAXP1 + m];
            }
        }
    }
    #pragma unroll
    for (int off = 32; off > 0; off >>= 1) gedv += __shfl_xor(gedv, off);
    if (lane == 0) geds[p] = gedv / (float)(n + m);
}

// ---------------------------------------------------------------------------
extern "C" void kernel_launch(void* const* d_in, const int* in_sizes, int n_in,
                              void* d_out, int out_size, void* d_ws, size_t ws_size,
                              hipStream_t stream) {
    const float* x_s = (const float*)d_in[0];
    const float* x_t = (const float*)d_in[1];
    const float* W1  = (const float*)d_in[2];
    const float* b1  = (const float*)d_in[3];
    const float* W2  = (const float*)d_in[4];
    const float* b2  = (const float*)d_in[5];
    const float* ve  = (const float*)d_in[6];
    const int* len_s = (const int*)d_in[7];
    const int* len_t = (const int*)d_in[8];
    const int P    = in_sizes[7];
    const int Ns   = in_sizes[0] / 2048;
    const int Nt   = in_sizes[1] / 2048;
    const int Mtot = Ns + Nt + 1;
    const size_t MN  = (size_t)Mtot * EDIM;

    float* H    = (float*)d_ws;
    float* Emb  = H + MN;
    float* Part = Emb + MN;

    // pick largest split that fits ws: need (2 + S)*MN floats
    int S = 1;
    if (ws_size >= (2 + 4) * MN * sizeof(float)) S = 4;
    else if (ws_size >= (2 + 2) * MN * sizeof(float)) S = 2;

    float* out_aligns = (float*)d_out;
    float* out_costs  = out_aligns + (size_t)P * LMAXP1 * LMAXP1;
    float* out_geds   = out_costs  + (size_t)P * LMAXP1 * LMAXP1;

    const dim3 b256(256);

    if (S > 1) {
        const int gx128 = (Mtot + 127) / 128;
        k_gemm_splitk<<<dim3(gx128, 4, S), b256, 0, stream>>>(
            x_s, Ns, x_t, Nt, ve, W1, Part, Mtot, 2048, 2048 / S);
        const size_t MN4 = MN / 4;
        const int rblocks = (int)((MN4 + 255) / 256) < 2048
                          ? (int)((MN4 + 255) / 256) : 2048;
        k_reduce_bias_relu<<<dim3(rblocks), b256, 0, stream>>>(Part, b1, H, S, MN4);
    } else {
        const int gx64 = (Mtot + 63) / 64;
        k_embed_gemm<<<dim3(gx64, 4), b256, 0, stream>>>(
            x_s, Ns, x_t, Nt, ve, W1, b1, H, Mtot, 2048);
    }
    const int gx64 = (Mtot + 63) / 64;
    k_embed_gemm<<<dim3(gx64, 4), b256, 0, stream>>>(
        H, Mtot, nullptr, 0, nullptr, W2, b2, Emb, Mtot, 256);
    k_costs<<<dim3(P), b256, 0, stream>>>(Emb, len_s, len_t, Ns, Nt, out_costs);
    k_lap<<<dim3(P), dim3(64), 0, stream>>>(out_costs, len_s, len_t, out_aligns, out_geds);
}

// Round 11
// 208.790 us; speedup vs baseline: 2.7573x; 1.4258x over previous
//
#include <hip/hip_runtime.h>
#include <math.h>

#define LMAXP1 33
#define EDIM   256
#define FBIG   3.0e38f

typedef _Float16 half8 __attribute__((ext_vector_type(8)));
typedef float    f32x4 __attribute__((ext_vector_type(4)));

__device__ inline unsigned pk2h(_Float16 a, _Float16 b) {
    union { _Float16 h[2]; unsigned u; } q; q.h[0] = a; q.h[1] = b; return q.u;
}

// ---------------------------------------------------------------------------
// Split-K GEMM v3 (NT) via fp16-split MFMA: Part[ks] = (A @ W^T) over chunk.
// A,W fp32 -> hi/lo fp16 (W pre-scaled by 2^10; acc scaled back by 2^-10).
// D += Ah*Bh + Ah*Bl + Al*Bh  (error ~2^-22 rel, below fp32 accum noise).
// 256 thr = 4 waves; BM=128, BN=64, BK=32; wave = 64x32 out (4x2 16x16 tiles).
// Frag maps (m89-verified): A/B row|col = lane&15, k = (lane>>4)*8 + i;
// C/D col = lane&15, row = (lane>>4)*4 + reg.
// ---------------------------------------------------------------------------
#define ASTR 20   // uints per LDS row (40 halfs = 80B), pad vs bank conflicts
__global__ __launch_bounds__(256)
void k_gemm_splitk(const float* __restrict__ S0, int n0,
                   const float* __restrict__ S1, int n1,
                   const float* __restrict__ S2,
                   const float* __restrict__ W,
                   float* __restrict__ Part, int Mtot, int K, int kchunk) {
    __shared__ alignas(16) unsigned AsH[128 * ASTR];
    __shared__ alignas(16) unsigned AsL[128 * ASTR];
    __shared__ alignas(16) unsigned BsH[64 * ASTR];
    __shared__ alignas(16) unsigned BsL[64 * ASTR];
    const int tid  = threadIdx.x;
    const int m0   = blockIdx.x * 128, nc0 = blockIdx.y * 64;
    const int ks   = blockIdx.z;
    const int kb   = ks * kchunk;
    const int ke   = (kb + kchunk < K) ? kb + kchunk : K;

    // staging coords
    const int sar = tid >> 1;              // A row 0..127
    const int sak = (tid & 1) << 4;        // A k-offset 0/16
    const int sbr = tid >> 2;              // B row 0..63
    const int sbk = (tid & 3) << 3;        // B k-offset 0,8,16,24

    const int gr = m0 + sar;
    const float* srow = nullptr;
    if (gr < n0)            srow = S0 + (size_t)gr * K;
    else if (gr < n0 + n1)  srow = S1 + (size_t)(gr - n0) * K;
    else if (gr < Mtot)     srow = S2;               // single virtual row
    const float* wrow = W + (size_t)(nc0 + sbr) * K;

    // compute coords
    const int lane = tid & 63, wv = tid >> 6;
    const int wr = (wv & 1) << 6;          // wave row base 0/64
    const int wc = (wv >> 1) << 5;         // wave col base 0/32
    const int lr = lane & 15, lq = lane >> 4;

    f32x4 acc[4][2] = {};

    for (int k0 = kb; k0 < ke; k0 += 32) {
        // ---- stage A (128x32 fp32 -> hi/lo fp16) ----
        {
            float x[16];
            if (srow) {
                const float4 f0 = *(const float4*)(srow + k0 + sak + 0);
                const float4 f1 = *(const float4*)(srow + k0 + sak + 4);
                const float4 f2 = *(const float4*)(srow + k0 + sak + 8);
                const float4 f3 = *(const float4*)(srow + k0 + sak + 12);
                x[0]=f0.x; x[1]=f0.y; x[2]=f0.z; x[3]=f0.w;
                x[4]=f1.x; x[5]=f1.y; x[6]=f1.z; x[7]=f1.w;
                x[8]=f2.x; x[9]=f2.y; x[10]=f2.z; x[11]=f2.w;
                x[12]=f3.x; x[13]=f3.y; x[14]=f3.z; x[15]=f3.w;
            } else {
                #pragma unroll
                for (int j = 0; j < 16; ++j) x[j] = 0.f;
            }
            unsigned uh[8], ul[8];
            #pragma unroll
            for (int j = 0; j < 8; ++j) {
                const _Float16 h0 = (_Float16)x[2*j],   h1 = (_Float16)x[2*j+1];
                const _Float16 l0 = (_Float16)(x[2*j]   - (float)h0);
                const _Float16 l1 = (_Float16)(x[2*j+1] - (float)h1);
                uh[j] = pk2h(h0, h1); ul[j] = pk2h(l0, l1);
            }
            unsigned* ph = AsH + sar * ASTR + (sak >> 1);
            unsigned* pl = AsL + sar * ASTR + (sak >> 1);
            ((uint4*)ph)[0] = make_uint4(uh[0],uh[1],uh[2],uh[3]);
            ((uint4*)ph)[1] = make_uint4(uh[4],uh[5],uh[6],uh[7]);
            ((uint4*)pl)[0] = make_uint4(ul[0],ul[1],ul[2],ul[3]);
            ((uint4*)pl)[1] = make_uint4(ul[4],ul[5],ul[6],ul[7]);
        }
        // ---- stage B = W rows, pre-scaled by 2^10 ----
        {
            const float4 f0 = *(const float4*)(wrow + k0 + sbk + 0);
            const float4 f1 = *(const float4*)(wrow + k0 + sbk + 4);
            float y[8] = {f0.x,f0.y,f0.z,f0.w,f1.x,f1.y,f1.z,f1.w};
            unsigned uh[4], ul[4];
            #pragma unroll
            for (int j = 0; j < 4; ++j) {
                const float a0 = y[2*j] * 1024.0f, a1 = y[2*j+1] * 1024.0f;
                const _Float16 h0 = (_Float16)a0, h1 = (_Float16)a1;
                const _Float16 l0 = (_Float16)(a0 - (float)h0);
                const _Float16 l1 = (_Float16)(a1 - (float)h1);
                uh[j] = pk2h(h0, h1); ul[j] = pk2h(l0, l1);
            }
            *(uint4*)(BsH + sbr * ASTR + (sbk >> 1)) = make_uint4(uh[0],uh[1],uh[2],uh[3]);
            *(uint4*)(BsL + sbr * ASTR + (sbk >> 1)) = make_uint4(ul[0],ul[1],ul[2],ul[3]);
        }
        __syncthreads();

        // ---- MFMA: wave computes 4x2 tiles of 16x16, K=32 ----
        half8 bh[2], bl[2];
        #pragma unroll
        for (int ct = 0; ct < 2; ++ct) {
            const int br = wc + ct * 16 + lr;
            bh[ct] = *(const half8*)((const char*)BsH + br * 80 + lq * 16);
            bl[ct] = *(const half8*)((const char*)BsL + br * 80 + lq * 16);
        }
        #pragma unroll
        for (int rt = 0; rt < 4; ++rt) {
            const int ar = wr + rt * 16 + lr;
            const half8 ah = *(const half8*)((const char*)AsH + ar * 80 + lq * 16);
            const half8 al = *(const half8*)((const char*)AsL + ar * 80 + lq * 16);
            #pragma unroll
            for (int ct = 0; ct < 2; ++ct) {
                acc[rt][ct] = __builtin_amdgcn_mfma_f32_16x16x32_f16(ah, bh[ct], acc[rt][ct], 0, 0, 0);
                acc[rt][ct] = __builtin_amdgcn_mfma_f32_16x16x32_f16(ah, bl[ct], acc[rt][ct], 0, 0, 0);
                acc[rt][ct] = __builtin_amdgcn_mfma_f32_16x16x32_f16(al, bh[ct], acc[rt][ct], 0, 0, 0);
            }
        }
        __syncthreads();
    }

    // ---- store (undo 2^10 W scaling exactly) ----
    float* pout = Part + (size_t)ks * ((size_t)Mtot * EDIM);
    const float sc = 1.0f / 1024.0f;
    #pragma unroll
    for (int rt = 0; rt < 4; ++rt) {
        #pragma unroll
        for (int r = 0; r < 4; ++r) {
            const int grr = m0 + wr + rt * 16 + lq * 4 + r;
            if (grr >= Mtot) continue;
            #pragma unroll
            for (int ct = 0; ct < 2; ++ct)
                pout[(size_t)grr * EDIM + nc0 + wc + ct * 16 + lr] = acc[rt][ct][r] * sc;
        }
    }
}

// Reduce split-K partials + bias + relu. Deterministic fixed-order sum.
__global__ __launch_bounds__(256)
void k_reduce_bias_relu(const float* __restrict__ Part,
                        const float* __restrict__ bias,
                        float* __restrict__ C, int S, size_t MN4) {
    const size_t i = (size_t)blockIdx.x * blockDim.x + threadIdx.x;
    const size_t stride = (size_t)gridDim.x * blockDim.x;
    const size_t MN = MN4 * 4;
    for (size_t i4 = i; i4 < MN4; i4 += stride) {
        float4 s = ((const float4*)Part)[i4];
        for (int z = 1; z < S; ++z)
            { const float4 q = ((const float4*)(Part + (size_t)z * MN))[i4];
              s.x += q.x; s.y += q.y; s.z += q.z; s.w += q.w; }
        const float4 b = ((const float4*)bias)[i4 & 63];   // EDIM/4 = 64
        s.x = fmaxf(s.x + b.x, 0.f); s.y = fmaxf(s.y + b.y, 0.f);
        s.z = fmaxf(s.z + b.z, 0.f); s.w = fmaxf(s.w + b.w, 0.f);
        ((float4*)C)[i4] = s;
    }
}

// ---------------------------------------------------------------------------
// Direct fp32 GEMM (NT, fused bias+relu) — layer 2 (K=256) / fallback.
// ---------------------------------------------------------------------------
__global__ __launch_bounds__(256)
void k_embed_gemm(const float* __restrict__ S0, int n0,
                  const float* __restrict__ S1, int n1,
                  const float* __restrict__ S2,
                  const float* __restrict__ W, const float* __restrict__ bias,
                  float* __restrict__ C, int Mtot, int K) {
    __shared__ alignas(16) float As[16][68];
    __shared__ alignas(16) float Bs[16][68];
    const int tid  = threadIdx.x;
    const int tx   = tid & 15, ty = tid >> 4;
    const int m0   = blockIdx.x * 64, nc0 = blockIdx.y * 64;
    const int lrow = tid >> 2;
    const int lk4  = (tid & 3) << 2;

    const int gr = m0 + lrow;
    const float* srow = nullptr;
    if (gr < n0)            srow = S0 + (size_t)gr * K;
    else if (gr < n0 + n1)  srow = S1 + (size_t)(gr - n0) * K;
    else if (gr < Mtot)     srow = S2;
    const float* wrow = W + (size_t)(nc0 + lrow) * K;

    float acc[4][4] = {};
    for (int k0 = 0; k0 < K; k0 += 16) {
        float4 va = make_float4(0.f, 0.f, 0.f, 0.f);
        if (srow) va = *(const float4*)(srow + k0 + lk4);
        const float4 vb = *(const float4*)(wrow + k0 + lk4);
        As[lk4+0][lrow] = va.x; As[lk4+1][lrow] = va.y;
        As[lk4+2][lrow] = va.z; As[lk4+3][lrow] = va.w;
        Bs[lk4+0][lrow] = vb.x; Bs[lk4+1][lrow] = vb.y;
        Bs[lk4+2][lrow] = vb.z; Bs[lk4+3][lrow] = vb.w;
        __syncthreads();
        #pragma unroll
        for (int kk = 0; kk < 16; ++kk) {
            const float4 a4 = *(const float4*)&As[kk][ty << 2];
            const float4 b4 = *(const float4*)&Bs[kk][tx << 2];
            const float av[4] = {a4.x, a4.y, a4.z, a4.w};
            const float bv[4] = {b4.x, b4.y, b4.z, b4.w};
            #pragma unroll
            for (int i2 = 0; i2 < 4; ++i2)
                #pragma unroll
                for (int j2 = 0; j2 < 4; ++j2)
                    acc[i2][j2] = fmaf(av[i2], bv[j2], acc[i2][j2]);
        }
        __syncthreads();
    }
    #pragma unroll
    for (int i2 = 0; i2 < 4; ++i2) {
        const int grr = m0 + (ty << 2) + i2;
        if (grr >= Mtot) continue;
        #pragma unroll
        for (int j2 = 0; j2 < 4; ++j2) {
            const int gc = nc0 + (tx << 2) + j2;
            const float vv = acc[i2][j2] + bias[gc];
            C[(size_t)grr * EDIM + gc] = fmaxf(vv, 0.0f);
        }
    }
}

// ---------------------------------------------------------------------------
// Per-pair scaled edit-cost matrix (33x33), written dense (zeros outside valid)
// ---------------------------------------------------------------------------
__global__ __launch_bounds__(256)
void k_costs(const float* __restrict__ Emb, const int* __restrict__ len_s,
             const int* __restrict__ len_t, int Ns, int Nt,
             float* __restrict__ costs) {
    __shared__ alignas(16) float Asl[LMAXP1 * EDIM];
    __shared__ float dtile[LMAXP1 * LMAXP1];
    __shared__ float na[LMAXP1], nb[LMAXP1];
    __shared__ float red[256];
    __shared__ float s_scale;
    const int p = blockIdx.x, tid = threadIdx.x;
    const int n = len_s[p], m = len_t[p];
    int offs = 0, offt = 0;
    for (int j = 0; j < p; ++j) { offs += len_s[j]; offt += len_t[j]; }
    const int veRow = Ns + Nt;
    const int tbase = Ns + offt;

    for (int idx = tid; idx < (n + 1) * (EDIM / 4); idx += 256) {
        const int r = idx >> 6, c = idx & 63;
        const float* src = (r < n) ? (Emb + (size_t)(offs + r) * EDIM)
                                   : (Emb + (size_t)veRow * EDIM);
        ((float4*)Asl)[r * 64 + c] = ((const float4*)src)[c];
    }
    __syncthreads();

    if (tid <= n) {
        const float4* a4 = (const float4*)(Asl + tid * EDIM);
        float s = 0.f;
        for (int k = 0; k < 64; ++k) {
            const float4 a = a4[k];
            s = fmaf(a.x, a.x, s); s = fmaf(a.y, a.y, s);
            s = fmaf(a.z, a.z, s); s = fmaf(a.w, a.w, s);
        }
        na[tid] = s;
    } else if (tid >= 64 && tid - 64 <= m) {
        const int j = tid - 64;
        const float* src = (j < m) ? (Emb + (size_t)(tbase + j) * EDIM)
                                   : (Emb + (size_t)veRow * EDIM);
        const float4* b4 = (const float4*)src;
        float s = 0.f;
        for (int k = 0; k < 64; ++k) {
            const float4 b = b4[k];
            s = fmaf(b.x, b.x, s); s = fmaf(b.y, b.y, s);
            s = fmaf(b.z, b.z, s); s = fmaf(b.w, b.w, s);
        }
        nb[j] = s;
    }
    __syncthreads();

    float lsum = 0.f;
    const int m1 = m + 1;
    const int cells = (n + 1) * m1;
    for (int c = tid; c < cells; c += 256) {
        const int i = c / m1, j = c - i * m1;
        const float* brow = (j < m) ? (Emb + (size_t)(tbase + j) * EDIM)
                                    : (Emb + (size_t)veRow * EDIM);
        const float4* a4 = (const float4*)(Asl + i * EDIM);
        const float4* b4 = (const float4*)brow;
        float dot = 0.f;
        #pragma unroll 8
        for (int k = 0; k < 64; ++k) {
            const float4 a = a4[k], b = b4[k];
            dot = fmaf(a.x, b.x, dot); dot = fmaf(a.y, b.y, dot);
            dot = fmaf(a.z, b.z, dot); dot = fmaf(a.w, b.w, dot);
        }
        const float sq = fmaxf(na[i] + nb[j] - 2.0f * dot, 0.0f);
        const float d  = (sq > 0.0f) ? sqrtf(sq) : 0.0f;
        dtile[i * LMAXP1 + j] = d;
        lsum += d;
    }
    red[tid] = lsum;
    __syncthreads();
    for (int s = 128; s > 0; s >>= 1) {
        if (tid < s) red[tid] += red[tid + s];
        __syncthreads();
    }
    if (tid == 0) s_scale = (float)(n * m) / red[0];
    __syncthreads();
    const float scale = s_scale;
    for (int idx = tid; idx < LMAXP1 * LMAXP1; idx += 256) {
        const int i = idx / LMAXP1, j = idx - i * LMAXP1;
        const float v = (i <= n && j <= m) ? dtile[i * LMAXP1 + j] * scale : 0.0f;
        costs[(size_t)p * (LMAXP1 * LMAXP1) + idx] = v;
    }
}

// ---------------------------------------------------------------------------
// LAP via exact LSAPE reduction to max(n,m)^2 square LAP (R8-verified),
// JV Dijkstra core with packed u32 DPP argmin.
// ---------------------------------------------------------------------------
__device__ inline int rdlane_i(int v, int l) { return __builtin_amdgcn_readlane(v, l); }
__device__ inline float rdlane_f(float v, int l) {
    return __int_as_float(__builtin_amdgcn_readlane(__float_as_int(v), l));
}
__device__ inline unsigned wave_umin64(unsigned x) {
#define DPPMINU(ctrl) { unsigned t_ = (unsigned)__builtin_amdgcn_update_dpp(  \
        (int)x, (int)x, (ctrl), 0xf, 0xf, false);                             \
        x = (t_ < x) ? t_ : x; }
    DPPMINU(0xB1)
    DPPMINU(0x4E)
    DPPMINU(0x141)
    DPPMINU(0x140)
    DPPMINU(0x142)
    DPPMINU(0x143)
#undef DPPMINU
    return (unsigned)__builtin_amdgcn_readlane((int)x, 63);
}

__global__ __launch_bounds__(64)
void k_lap(const float* __restrict__ costs, const int* __restrict__ len_s,
           const int* __restrict__ len_t, float* __restrict__ aligns,
           float* __restrict__ geds) {
    __shared__ float ec[LMAXP1 * LMAXP1];
    __shared__ float Ms[33 * 64];
    const int p = blockIdx.x, lane = threadIdx.x;
    const int n = len_s[p], m = len_t[p];
    const float* cp = costs + (size_t)p * (LMAXP1 * LMAXP1);
    for (int idx = lane; idx < LMAXP1 * LMAXP1; idx += 64) ec[idx] = cp[idx];
    __syncthreads();

    const bool swp = (n > m);
    const int R  = swp ? n : m;
    const int S_ = swp ? m : n;
    const bool vec = (lane >= 1 && lane <= R);

    for (int r = 1; r <= R; ++r) {
        float cv = FBIG;
        const int i0b = r - 1, j0b = lane - 1;
        if (vec) {
            if (!swp) {
                const float ins = ec[n * LMAXP1 + j0b];
                cv = (i0b < S_)
                   ? fminf(ec[i0b * LMAXP1 + j0b], ec[i0b * LMAXP1 + m] + ins)
                   : ins;
            } else {
                const float ins = ec[j0b * LMAXP1 + m];
                cv = (i0b < S_)
                   ? fminf(ec[j0b * LMAXP1 + i0b], ec[n * LMAXP1 + i0b] + ins)
                   : ins;
            }
        }
        Ms[(r << 6) + lane] = cv;
    }
    __syncthreads();

    float v_l = 0.0f, minv_l = FBIG, ucol = 0.0f;
    int p_l = 0, way_l = 0;

    for (int i = 1; i <= R; ++i) {
        if (lane == 0) { p_l = i; ucol = 0.0f; }
        minv_l = FBIG;
        int used_l = 0;
        int j0 = 0, i0 = i;
        float u_i0 = 0.0f;
        while (true) {
            if (lane == j0) used_l = 1;
            const float cur = Ms[(i0 << 6) + lane] - u_i0 - v_l;
            const bool unused = vec && !used_l;
            if (unused && cur < minv_l) { minv_l = cur; way_l = j0; }
            const float mval = unused ? fmaxf(minv_l, 0.0f) : FBIG;
            const unsigned key = (__float_as_uint(mval) & ~63u) | (unsigned)lane;
            const unsigned kmin = wave_umin64(key);
            const int j1 = (int)(kmin & 63u);
            const float delta = rdlane_f(minv_l, j1);
            if (used_l) { ucol += delta; v_l -= delta; }
            if (unused) minv_l -= delta;
            j0 = j1;
            i0 = rdlane_i(p_l, j1);
            u_i0 = rdlane_f(ucol, j1);
            if (i0 == 0) break;
        }
        int jj = j0;
        while (jj != 0) {
            const int   j1a = rdlane_i(way_l, jj);
            const int   pn  = rdlane_i(p_l, j1a);
            const float un  = rdlane_f(ucol, j1a);
            if (lane == jj) { p_l = pn; ucol = un; }
            jj = j1a;
        }
    }

    float* ap = aligns + (size_t)p * (LMAXP1 * LMAXP1);
    for (int idx = lane; idx < LMAXP1 * LMAXP1; idx += 64) ap[idx] = 0.0f;
    __syncthreads();
    float gedv = 0.0f;
    if (vec) {
        const int i0b = p_l - 1;
        const int j0b = lane - 1;
        if (!swp) {
            if (i0b < S_) {
                const float sub = ec[i0b * LMAXP1 + j0b];
                const float alt = ec[i0b * LMAXP1 + m] + ec[n * LMAXP1 + j0b];
                if (sub <= alt) { ap[i0b * LMAXP1 + j0b] = 1.0f; gedv = sub; }
                else { ap[i0b * LMAXP1 + m] = 1.0f;
                       ap[n * LMAXP1 + j0b] = 1.0f;
                       gedv = alt; }
            } else {
                ap[n * LMAXP1 + j0b] = 1.0f;
                gedv = ec[n * LMAXP1 + j0b];
            }
        } else {
            if (i0b < S_) {
                const float sub = ec[j0b * LMAXP1 + i0b];
                const float alt = ec[n * LMAXP1 + i0b] + ec[j0b * LMAXP1 + m];
                if (sub <= alt) { ap[j0b * LMAXP1 + i0b] = 1.0f; gedv = sub; }
                else { ap[n * LMAXP1 + i0b] = 1.0f;
                       ap[j0b * LMAXP1 + m] = 1.0f;
                       gedv = alt; }
            } else {
                ap[j0b * LMAXP1 + m] = 1.0f;
                gedv = ec[j0b * LMAXP1 + m];
            }
        }
    }
    #pragma unroll
    for (int off = 32; off > 0; off >>= 1) gedv += __shfl_xor(gedv, off);
    if (lane == 0) geds[p] = gedv / (float)(n + m);
}

// ---------------------------------------------------------------------------
extern "C" void kernel_launch(void* const* d_in, const int* in_sizes, int n_in,
                              void* d_out, int out_size, void* d_ws, size_t ws_size,
                              hipStream_t stream) {
    const float* x_s = (const float*)d_in[0];
    const float* x_t = (const float*)d_in[1];
    const float* W1  = (const float*)d_in[2];
    const float* b1  = (const float*)d_in[3];
    const float* W2  = (const float*)d_in[4];
    const float* b2  = (const float*)d_in[5];
    const float* ve  = (const float*)d_in[6];
    const int* len_s = (const int*)d_in[7];
    const int* len_t = (const int*)d_in[8];
    const int P    = in_sizes[7];
    const int Ns   = in_sizes[0] / 2048;
    const int Nt   = in_sizes[1] / 2048;
    const int Mtot = Ns + Nt + 1;
    const size_t MN  = (size_t)Mtot * EDIM;

    float* H    = (float*)d_ws;
    float* Emb  = H + MN;
    float* Part = Emb + MN;

    // pick largest split that fits ws: need (2 + S)*MN floats
    int S = 1;
    if (ws_size >= (2 + 4) * MN * sizeof(float)) S = 4;
    else if (ws_size >= (2 + 2) * MN * sizeof(float)) S = 2;

    float* out_aligns = (float*)d_out;
    float* out_costs  = out_aligns + (size_t)P * LMAXP1 * LMAXP1;
    float* out_geds   = out_costs  + (size_t)P * LMAXP1 * LMAXP1;

    const dim3 b256(256);

    if (S > 1) {
        const int gx128 = (Mtot + 127) / 128;
        k_gemm_splitk<<<dim3(gx128, 4, S), b256, 0, stream>>>(
            x_s, Ns, x_t, Nt, ve, W1, Part, Mtot, 2048, 2048 / S);
        const size_t MN4 = MN / 4;
        const int rblocks = (int)((MN4 + 255) / 256) < 2048
                          ? (int)((MN4 + 255) / 256) : 2048;
        k_reduce_bias_relu<<<dim3(rblocks), b256, 0, stream>>>(Part, b1, H, S, MN4);
    } else {
        const int gx64 = (Mtot + 63) / 64;
        k_embed_gemm<<<dim3(gx64, 4), b256, 0, stream>>>(
            x_s, Ns, x_t, Nt, ve, W1, b1, H, Mtot, 2048);
    }
    const int gx64 = (Mtot + 63) / 64;
    k_embed_gemm<<<dim3(gx64, 4), b256, 0, stream>>>(
        H, Mtot, nullptr, 0, nullptr, W2, b2, Emb, Mtot, 256);
    k_costs<<<dim3(P), b256, 0, stream>>>(Emb, len_s, len_t, Ns, Nt, out_costs);
    k_lap<<<dim3(P), dim3(64), 0, stream>>>(out_costs, len_s, len_t, out_aligns, out_geds);
}

// Round 12
// 189.514 us; speedup vs baseline: 3.0378x; 1.1017x over previous
//
#include <hip/hip_runtime.h>
#include <math.h>

#define LMAXP1 33
#define EDIM   256
#define FBIG   3.0e38f

typedef _Float16 half8 __attribute__((ext_vector_type(8)));
typedef float    f32x4 __attribute__((ext_vector_type(4)));

__device__ inline unsigned pk2h(_Float16 a, _Float16 b) {
    union { _Float16 h[2]; unsigned u; } q; q.h[0] = a; q.h[1] = b; return q.u;
}

// ---------------------------------------------------------------------------
// Split-K GEMM (NT) via fp16-split MFMA. If bias != nullptr (requires S==1
// usage), fuses bias+relu at store (direct output); else writes raw partials.
// A,W fp32 -> hi/lo fp16 (W pre-scaled by 2^10; store scales back by 2^-10).
// D += Ah*Bh + Ah*Bl + Al*Bh. 256 thr = 4 waves; BM=128, BN=64, BK=32.
// ---------------------------------------------------------------------------
#define ASTR 20   // uints per LDS row (40 halfs = 80B)
__global__ __launch_bounds__(256)
void k_gemm_splitk(const float* __restrict__ S0, int n0,
                   const float* __restrict__ S1, int n1,
                   const float* __restrict__ S2,
                   const float* __restrict__ W,
                   float* __restrict__ Part, int Mtot, int K, int kchunk,
                   const float* __restrict__ bias) {
    __shared__ alignas(16) unsigned AsH[128 * ASTR];
    __shared__ alignas(16) unsigned AsL[128 * ASTR];
    __shared__ alignas(16) unsigned BsH[64 * ASTR];
    __shared__ alignas(16) unsigned BsL[64 * ASTR];
    const int tid  = threadIdx.x;
    const int m0   = blockIdx.x * 128, nc0 = blockIdx.y * 64;
    const int ks   = blockIdx.z;
    const int kb   = ks * kchunk;
    const int ke   = (kb + kchunk < K) ? kb + kchunk : K;

    const int sar = tid >> 1;              // A row 0..127
    const int sak = (tid & 1) << 4;        // A k-offset 0/16
    const int sbr = tid >> 2;              // B row 0..63
    const int sbk = (tid & 3) << 3;        // B k-offset 0,8,16,24

    const int gr = m0 + sar;
    const float* srow = nullptr;
    if (gr < n0)            srow = S0 + (size_t)gr * K;
    else if (gr < n0 + n1)  srow = S1 + (size_t)(gr - n0) * K;
    else if (gr < Mtot)     srow = S2;               // single virtual row
    const float* wrow = W + (size_t)(nc0 + sbr) * K;

    const int lane = tid & 63, wv = tid >> 6;
    const int wr = (wv & 1) << 6;
    const int wc = (wv >> 1) << 5;
    const int lr = lane & 15, lq = lane >> 4;

    f32x4 acc[4][2] = {};

    for (int k0 = kb; k0 < ke; k0 += 32) {
        {   // ---- stage A (128x32 fp32 -> hi/lo fp16) ----
            float x[16];
            if (srow) {
                const float4 f0 = *(const float4*)(srow + k0 + sak + 0);
                const float4 f1 = *(const float4*)(srow + k0 + sak + 4);
                const float4 f2 = *(const float4*)(srow + k0 + sak + 8);
                const float4 f3 = *(const float4*)(srow + k0 + sak + 12);
                x[0]=f0.x; x[1]=f0.y; x[2]=f0.z; x[3]=f0.w;
                x[4]=f1.x; x[5]=f1.y; x[6]=f1.z; x[7]=f1.w;
                x[8]=f2.x; x[9]=f2.y; x[10]=f2.z; x[11]=f2.w;
                x[12]=f3.x; x[13]=f3.y; x[14]=f3.z; x[15]=f3.w;
            } else {
                #pragma unroll
                for (int j = 0; j < 16; ++j) x[j] = 0.f;
            }
            unsigned uh[8], ul[8];
            #pragma unroll
            for (int j = 0; j < 8; ++j) {
                const _Float16 h0 = (_Float16)x[2*j],   h1 = (_Float16)x[2*j+1];
                const _Float16 l0 = (_Float16)(x[2*j]   - (float)h0);
                const _Float16 l1 = (_Float16)(x[2*j+1] - (float)h1);
                uh[j] = pk2h(h0, h1); ul[j] = pk2h(l0, l1);
            }
            unsigned* ph = AsH + sar * ASTR + (sak >> 1);
            unsigned* pl = AsL + sar * ASTR + (sak >> 1);
            ((uint4*)ph)[0] = make_uint4(uh[0],uh[1],uh[2],uh[3]);
            ((uint4*)ph)[1] = make_uint4(uh[4],uh[5],uh[6],uh[7]);
            ((uint4*)pl)[0] = make_uint4(ul[0],ul[1],ul[2],ul[3]);
            ((uint4*)pl)[1] = make_uint4(ul[4],ul[5],ul[6],ul[7]);
        }
        {   // ---- stage B = W rows, pre-scaled by 2^10 ----
            const float4 f0 = *(const float4*)(wrow + k0 + sbk + 0);
            const float4 f1 = *(const float4*)(wrow + k0 + sbk + 4);
            float y[8] = {f0.x,f0.y,f0.z,f0.w,f1.x,f1.y,f1.z,f1.w};
            unsigned uh[4], ul[4];
            #pragma unroll
            for (int j = 0; j < 4; ++j) {
                const float a0 = y[2*j] * 1024.0f, a1 = y[2*j+1] * 1024.0f;
                const _Float16 h0 = (_Float16)a0, h1 = (_Float16)a1;
                const _Float16 l0 = (_Float16)(a0 - (float)h0);
                const _Float16 l1 = (_Float16)(a1 - (float)h1);
                uh[j] = pk2h(h0, h1); ul[j] = pk2h(l0, l1);
            }
            *(uint4*)(BsH + sbr * ASTR + (sbk >> 1)) = make_uint4(uh[0],uh[1],uh[2],uh[3]);
            *(uint4*)(BsL + sbr * ASTR + (sbk >> 1)) = make_uint4(ul[0],ul[1],ul[2],ul[3]);
        }
        __syncthreads();

        half8 bh[2], bl[2];
        #pragma unroll
        for (int ct = 0; ct < 2; ++ct) {
            const int br = wc + ct * 16 + lr;
            bh[ct] = *(const half8*)((const char*)BsH + br * 80 + lq * 16);
            bl[ct] = *(const half8*)((const char*)BsL + br * 80 + lq * 16);
        }
        #pragma unroll
        for (int rt = 0; rt < 4; ++rt) {
            const int ar = wr + rt * 16 + lr;
            const half8 ah = *(const half8*)((const char*)AsH + ar * 80 + lq * 16);
            const half8 al = *(const half8*)((const char*)AsL + ar * 80 + lq * 16);
            #pragma unroll
            for (int ct = 0; ct < 2; ++ct) {
                acc[rt][ct] = __builtin_amdgcn_mfma_f32_16x16x32_f16(ah, bh[ct], acc[rt][ct], 0, 0, 0);
                acc[rt][ct] = __builtin_amdgcn_mfma_f32_16x16x32_f16(ah, bl[ct], acc[rt][ct], 0, 0, 0);
                acc[rt][ct] = __builtin_amdgcn_mfma_f32_16x16x32_f16(al, bh[ct], acc[rt][ct], 0, 0, 0);
            }
        }
        __syncthreads();
    }

    float* pout = Part + (size_t)ks * ((size_t)Mtot * EDIM);
    const float sc = 1.0f / 1024.0f;
    #pragma unroll
    for (int rt = 0; rt < 4; ++rt) {
        #pragma unroll
        for (int r = 0; r < 4; ++r) {
            const int grr = m0 + wr + rt * 16 + lq * 4 + r;
            if (grr >= Mtot) continue;
            #pragma unroll
            for (int ct = 0; ct < 2; ++ct) {
                const int gc = nc0 + wc + ct * 16 + lr;
                float vv = acc[rt][ct][r] * sc;
                if (bias) vv = fmaxf(vv + bias[gc], 0.0f);
                pout[(size_t)grr * EDIM + gc] = vv;
            }
        }
    }
}

// Reduce split-K partials + bias + relu. Deterministic fixed-order sum.
__global__ __launch_bounds__(256)
void k_reduce_bias_relu(const float* __restrict__ Part,
                        const float* __restrict__ bias,
                        float* __restrict__ C, int S, size_t MN4) {
    const size_t i = (size_t)blockIdx.x * blockDim.x + threadIdx.x;
    const size_t stride = (size_t)gridDim.x * blockDim.x;
    const size_t MN = MN4 * 4;
    for (size_t i4 = i; i4 < MN4; i4 += stride) {
        float4 s = ((const float4*)Part)[i4];
        for (int z = 1; z < S; ++z)
            { const float4 q = ((const float4*)(Part + (size_t)z * MN))[i4];
              s.x += q.x; s.y += q.y; s.z += q.z; s.w += q.w; }
        const float4 b = ((const float4*)bias)[i4 & 63];   // EDIM/4 = 64
        s.x = fmaxf(s.x + b.x, 0.f); s.y = fmaxf(s.y + b.y, 0.f);
        s.z = fmaxf(s.z + b.z, 0.f); s.w = fmaxf(s.w + b.w, 0.f);
        ((float4*)C)[i4] = s;
    }
}

// ---------------------------------------------------------------------------
// Direct fp32 GEMM (NT, fused bias+relu) — fallback only (ws too small).
// ---------------------------------------------------------------------------
__global__ __launch_bounds__(256)
void k_embed_gemm(const float* __restrict__ S0, int n0,
                  const float* __restrict__ S1, int n1,
                  const float* __restrict__ S2,
                  const float* __restrict__ W, const float* __restrict__ bias,
                  float* __restrict__ C, int Mtot, int K) {
    __shared__ alignas(16) float As[16][68];
    __shared__ alignas(16) float Bs[16][68];
    const int tid  = threadIdx.x;
    const int tx   = tid & 15, ty = tid >> 4;
    const int m0   = blockIdx.x * 64, nc0 = blockIdx.y * 64;
    const int lrow = tid >> 2;
    const int lk4  = (tid & 3) << 2;

    const int gr = m0 + lrow;
    const float* srow = nullptr;
    if (gr < n0)            srow = S0 + (size_t)gr * K;
    else if (gr < n0 + n1)  srow = S1 + (size_t)(gr - n0) * K;
    else if (gr < Mtot)     srow = S2;
    const float* wrow = W + (size_t)(nc0 + lrow) * K;

    float acc[4][4] = {};
    for (int k0 = 0; k0 < K; k0 += 16) {
        float4 va = make_float4(0.f, 0.f, 0.f, 0.f);
        if (srow) va = *(const float4*)(srow + k0 + lk4);
        const float4 vb = *(const float4*)(wrow + k0 + lk4);
        As[lk4+0][lrow] = va.x; As[lk4+1][lrow] = va.y;
        As[lk4+2][lrow] = va.z; As[lk4+3][lrow] = va.w;
        Bs[lk4+0][lrow] = vb.x; Bs[lk4+1][lrow] = vb.y;
        Bs[lk4+2][lrow] = vb.z; Bs[lk4+3][lrow] = vb.w;
        __syncthreads();
        #pragma unroll
        for (int kk = 0; kk < 16; ++kk) {
            const float4 a4 = *(const float4*)&As[kk][ty << 2];
            const float4 b4 = *(const float4*)&Bs[kk][tx << 2];
            const float av[4] = {a4.x, a4.y, a4.z, a4.w};
            const float bv[4] = {b4.x, b4.y, b4.z, b4.w};
            #pragma unroll
            for (int i2 = 0; i2 < 4; ++i2)
                #pragma unroll
                for (int j2 = 0; j2 < 4; ++j2)
                    acc[i2][j2] = fmaf(av[i2], bv[j2], acc[i2][j2]);
        }
        __syncthreads();
    }
    #pragma unroll
    for (int i2 = 0; i2 < 4; ++i2) {
        const int grr = m0 + (ty << 2) + i2;
        if (grr >= Mtot) continue;
        #pragma unroll
        for (int j2 = 0; j2 < 4; ++j2) {
            const int gc = nc0 + (tx << 2) + j2;
            const float vv = acc[i2][j2] + bias[gc];
            C[(size_t)grr * EDIM + gc] = fmaxf(vv, 0.0f);
        }
    }
}

// ---------------------------------------------------------------------------
// Per-pair scaled edit-cost matrix (33x33), written dense (zeros outside valid)
// ---------------------------------------------------------------------------
__global__ __launch_bounds__(256)
void k_costs(const float* __restrict__ Emb, const int* __restrict__ len_s,
             const int* __restrict__ len_t, int Ns, int Nt,
             float* __restrict__ costs) {
    __shared__ alignas(16) float Asl[LMAXP1 * EDIM];
    __shared__ float dtile[LMAXP1 * LMAXP1];
    __shared__ float na[LMAXP1], nb[LMAXP1];
    __shared__ float red[256];
    __shared__ float s_scale;
    const int p = blockIdx.x, tid = threadIdx.x;
    const int n = len_s[p], m = len_t[p];
    int offs = 0, offt = 0;
    for (int j = 0; j < p; ++j) { offs += len_s[j]; offt += len_t[j]; }
    const int veRow = Ns + Nt;
    const int tbase = Ns + offt;

    for (int idx = tid; idx < (n + 1) * (EDIM / 4); idx += 256) {
        const int r = idx >> 6, c = idx & 63;
        const float* src = (r < n) ? (Emb + (size_t)(offs + r) * EDIM)
                                   : (Emb + (size_t)veRow * EDIM);
        ((float4*)Asl)[r * 64 + c] = ((const float4*)src)[c];
    }
    __syncthreads();

    if (tid <= n) {
        const float4* a4 = (const float4*)(Asl + tid * EDIM);
        float s = 0.f;
        for (int k = 0; k < 64; ++k) {
            const float4 a = a4[k];
            s = fmaf(a.x, a.x, s); s = fmaf(a.y, a.y, s);
            s = fmaf(a.z, a.z, s); s = fmaf(a.w, a.w, s);
        }
        na[tid] = s;
    } else if (tid >= 64 && tid - 64 <= m) {
        const int j = tid - 64;
        const float* src = (j < m) ? (Emb + (size_t)(tbase + j) * EDIM)
                                   : (Emb + (size_t)veRow * EDIM);
        const float4* b4 = (const float4*)src;
        float s = 0.f;
        for (int k = 0; k < 64; ++k) {
            const float4 b = b4[k];
            s = fmaf(b.x, b.x, s); s = fmaf(b.y, b.y, s);
            s = fmaf(b.z, b.z, s); s = fmaf(b.w, b.w, s);
        }
        nb[j] = s;
    }
    __syncthreads();

    float lsum = 0.f;
    const int m1 = m + 1;
    const int cells = (n + 1) * m1;
    for (int c = tid; c < cells; c += 256) {
        const int i = c / m1, j = c - i * m1;
        const float* brow = (j < m) ? (Emb + (size_t)(tbase + j) * EDIM)
                                    : (Emb + (size_t)veRow * EDIM);
        const float4* a4 = (const float4*)(Asl + i * EDIM);
        const float4* b4 = (const float4*)brow;
        float dot = 0.f;
        #pragma unroll 8
        for (int k = 0; k < 64; ++k) {
            const float4 a = a4[k], b = b4[k];
            dot = fmaf(a.x, b.x, dot); dot = fmaf(a.y, b.y, dot);
            dot = fmaf(a.z, b.z, dot); dot = fmaf(a.w, b.w, dot);
        }
        const float sq = fmaxf(na[i] + nb[j] - 2.0f * dot, 0.0f);
        const float d  = (sq > 0.0f) ? sqrtf(sq) : 0.0f;
        dtile[i * LMAXP1 + j] = d;
        lsum += d;
    }
    red[tid] = lsum;
    __syncthreads();
    for (int s = 128; s > 0; s >>= 1) {
        if (tid < s) red[tid] += red[tid + s];
        __syncthreads();
    }
    if (tid == 0) s_scale = (float)(n * m) / red[0];
    __syncthreads();
    const float scale = s_scale;
    for (int idx = tid; idx < LMAXP1 * LMAXP1; idx += 256) {
        const int i = idx / LMAXP1, j = idx - i * LMAXP1;
        const float v = (i <= n && j <= m) ? dtile[i * LMAXP1 + j] * scale : 0.0f;
        costs[(size_t)p * (LMAXP1 * LMAXP1) + idx] = v;
    }
}

// ---------------------------------------------------------------------------
// LAP via exact LSAPE reduction to max(n,m)^2 square LAP (R8-verified) with
// column-reduction + greedy init (R5-verified-correct code; on the dense
// reduced matrix there is no zero plateau, so post-greedy Dijkstra paths are
// short). JV Dijkstra core with packed u32 DPP argmin (R7-verified).
// ---------------------------------------------------------------------------
__device__ inline int rdlane_i(int v, int l) { return __builtin_amdgcn_readlane(v, l); }
__device__ inline float rdlane_f(float v, int l) {
    return __int_as_float(__builtin_amdgcn_readlane(__float_as_int(v), l));
}
__device__ inline unsigned wave_umin64(unsigned x) {
#define DPPMINU(ctrl) { unsigned t_ = (unsigned)__builtin_amdgcn_update_dpp(  \
        (int)x, (int)x, (ctrl), 0xf, 0xf, false);                             \
        x = (t_ < x) ? t_ : x; }
    DPPMINU(0xB1)
    DPPMINU(0x4E)
    DPPMINU(0x141)
    DPPMINU(0x140)
    DPPMINU(0x142)
    DPPMINU(0x143)
#undef DPPMINU
    return (unsigned)__builtin_amdgcn_readlane((int)x, 63);
}

__global__ __launch_bounds__(64)
void k_lap(const float* __restrict__ costs, const int* __restrict__ len_s,
           const int* __restrict__ len_t, float* __restrict__ aligns,
           float* __restrict__ geds) {
    __shared__ float ec[LMAXP1 * LMAXP1];
    __shared__ float Ms[33 * 64];
    const int p = blockIdx.x, lane = threadIdx.x;
    const int n = len_s[p], m = len_t[p];
    const float* cp = costs + (size_t)p * (LMAXP1 * LMAXP1);
    for (int idx = lane; idx < LMAXP1 * LMAXP1; idx += 64) ec[idx] = cp[idx];
    __syncthreads();

    const bool swp = (n > m);
    const int R  = swp ? n : m;
    const int S_ = swp ? m : n;
    const bool vec = (lane >= 1 && lane <= R);

    for (int r = 1; r <= R; ++r) {
        float cv = FBIG;
        const int i0b = r - 1, j0b = lane - 1;
        if (vec) {
            if (!swp) {
                const float ins = ec[n * LMAXP1 + j0b];
                cv = (i0b < S_)
                   ? fminf(ec[i0b * LMAXP1 + j0b], ec[i0b * LMAXP1 + m] + ins)
                   : ins;
            } else {
                const float ins = ec[j0b * LMAXP1 + m];
                cv = (i0b < S_)
                   ? fminf(ec[j0b * LMAXP1 + i0b], ec[n * LMAXP1 + i0b] + ins)
                   : ins;
            }
        }
        Ms[(r << 6) + lane] = cv;
    }
    __syncthreads();

    // ---- column reduction: v_j = min_r M[r][j], first argmin row ----
    float v_l = 0.0f;
    int amin_l = 0;
    if (vec) {
        float best = FBIG;
        for (int r = 1; r <= R; ++r) {
            const float c = Ms[(r << 6) + lane];
            if (c < best) { best = c; amin_l = r; }
        }
        v_l = best;
    }
    // ---- greedy: column j -> its argmin row if that row is still free ----
    int p_l = 0;                                     // p[col]=row (0 = free)
    unsigned long long rowfree = ((1ull << R) - 1ull) << 1;   // bits 1..R
    for (int j = 1; j <= R; ++j) {
        const int ai = rdlane_i(amin_l, j);
        if ((rowfree >> ai) & 1ull) {
            if (lane == j) p_l = ai;
            rowfree &= ~(1ull << ai);
        }
    }

    // ---- JV Dijkstra for remaining free rows ----
    float ucol = 0.0f, minv_l = FBIG;                // ucol = u[p[lane]] (=0)
    int way_l = 0;

    for (int i = 1; i <= R; ++i) {
        if (!((rowfree >> i) & 1ull)) continue;      // uniform branch
        if (lane == 0) { p_l = i; ucol = 0.0f; }
        minv_l = FBIG;
        int used_l = 0;
        int j0 = 0, i0 = i;
        float u_i0 = 0.0f;
        while (true) {
            if (lane == j0) used_l = 1;
            const float cur = Ms[(i0 << 6) + lane] - u_i0 - v_l;
            const bool unused = vec && !used_l;
            if (unused && cur < minv_l) { minv_l = cur; way_l = j0; }
            const float mval = unused ? fmaxf(minv_l, 0.0f) : FBIG;
            const unsigned key = (__float_as_uint(mval) & ~63u) | (unsigned)lane;
            const unsigned kmin = wave_umin64(key);
            const int j1 = (int)(kmin & 63u);
            const float delta = rdlane_f(minv_l, j1);
            if (used_l) { ucol += delta; v_l -= delta; }
            if (unused) minv_l -= delta;
            j0 = j1;
            i0 = rdlane_i(p_l, j1);
            u_i0 = rdlane_f(ucol, j1);
            if (i0 == 0) break;
        }
        int jj = j0;
        while (jj != 0) {
            const int   j1a = rdlane_i(way_l, jj);
            const int   pn  = rdlane_i(p_l, j1a);
            const float un  = rdlane_f(ucol, j1a);
            if (lane == jj) { p_l = pn; ucol = un; }
            jj = j1a;
        }
    }

    // ---- decode to aligns (0/1 as float) + geds ----
    float* ap = aligns + (size_t)p * (LMAXP1 * LMAXP1);
    for (int idx = lane; idx < LMAXP1 * LMAXP1; idx += 64) ap[idx] = 0.0f;
    __syncthreads();
    float gedv = 0.0f;
    if (vec) {
        const int i0b = p_l - 1;
        const int j0b = lane - 1;
        if (!swp) {
            if (i0b < S_) {
                const float sub = ec[i0b * LMAXP1 + j0b];
                const float alt = ec[i0b * LMAXP1 + m] + ec[n * LMAXP1 + j0b];
                if (sub <= alt) { ap[i0b * LMAXP1 + j0b] = 1.0f; gedv = sub; }
                else { ap[i0b * LMAXP1 + m] = 1.0f;
                       ap[n * LMAXP1 + j0b] = 1.0f;
                       gedv = alt; }
            } else {
                ap[n * LMAXP1 + j0b] = 1.0f;
                gedv = ec[n * LMAXP1 + j0b];
            }
        } else {
            if (i0b < S_) {
                const float sub = ec[j0b * LMAXP1 + i0b];
                const float alt = ec[n * LMAXP1 + i0b] + ec[j0b * LMAXP1 + m];
                if (sub <= alt) { ap[j0b * LMAXP1 + i0b] = 1.0f; gedv = sub; }
                else { ap[n * LMAXP1 + i0b] = 1.0f;
                       ap[j0b * LMAXP1 + m] = 1.0f;
                       gedv = alt; }
            } else {
                ap[j0b * LMAXP1 + m] = 1.0f;
                gedv = ec[j0b * LMAXP1 + m];
            }
        }
    }
    #pragma unroll
    for (int off = 32; off > 0; off >>= 1) gedv += __shfl_xor(gedv, off);
    if (lane == 0) geds[p] = gedv / (float)(n + m);
}

// ---------------------------------------------------------------------------
extern "C" void kernel_launch(void* const* d_in, const int* in_sizes, int n_in,
                              void* d_out, int out_size, void* d_ws, size_t ws_size,
                              hipStream_t stream) {
    const float* x_s = (const float*)d_in[0];
    const float* x_t = (const float*)d_in[1];
    const float* W1  = (const float*)d_in[2];
    const float* b1  = (const float*)d_in[3];
    const float* W2  = (const float*)d_in[4];
    const float* b2  = (const float*)d_in[5];
    const float* ve  = (const float*)d_in[6];
    const int* len_s = (const int*)d_in[7];
    const int* len_t = (const int*)d_in[8];
    const int P    = in_sizes[7];
    const int Ns   = in_sizes[0] / 2048;
    const int Nt   = in_sizes[1] / 2048;
    const int Mtot = Ns + Nt + 1;
    const size_t MN  = (size_t)Mtot * EDIM;

    float* H    = (float*)d_ws;
    float* Emb  = H + MN;
    float* Part = Emb + MN;

    int S = 1;
    if (ws_size >= (2 + 4) * MN * sizeof(float)) S = 4;
    else if (ws_size >= (2 + 2) * MN * sizeof(float)) S = 2;

    float* out_aligns = (float*)d_out;
    float* out_costs  = out_aligns + (size_t)P * LMAXP1 * LMAXP1;
    float* out_geds   = out_costs  + (size_t)P * LMAXP1 * LMAXP1;

    const dim3 b256(256);
    const int gx128 = (Mtot + 127) / 128;

    if (S > 1) {
        k_gemm_splitk<<<dim3(gx128, 4, S), b256, 0, stream>>>(
            x_s, Ns, x_t, Nt, ve, W1, Part, Mtot, 2048, 2048 / S, nullptr);
        const size_t MN4 = MN / 4;
        const int rblocks = (int)((MN4 + 255) / 256) < 2048
                          ? (int)((MN4 + 255) / 256) : 2048;
        k_reduce_bias_relu<<<dim3(rblocks), b256, 0, stream>>>(Part, b1, H, S, MN4);
        // layer 2 via MFMA, fused bias+relu (S=1 path writes Emb directly)
        k_gemm_splitk<<<dim3(gx128, 4, 1), b256, 0, stream>>>(
            H, Mtot, nullptr, 0, nullptr, W2, Emb, Mtot, 256, 256, b2);
    } else {
        const int gx64 = (Mtot + 63) / 64;
        k_embed_gemm<<<dim3(gx64, 4), b256, 0, stream>>>(
            x_s, Ns, x_t, Nt, ve, W1, b1, H, Mtot, 2048);
        k_embed_gemm<<<dim3(gx64, 4), b256, 0, stream>>>(
            H, Mtot, nullptr, 0, nullptr, W2, b2, Emb, Mtot, 256);
    }
    k_costs<<<dim3(P), b256, 0, stream>>>(Emb, len_s, len_t, Ns, Nt, out_costs);
    k_lap<<<dim3(P), dim3(64), 0, stream>>>(out_costs, len_s, len_t, out_aligns, out_geds);
}

// Round 13
// 180.113 us; speedup vs baseline: 3.1963x; 1.0522x over previous
//
#include <hip/hip_runtime.h>
#include <math.h>

#define LMAXP1 33
#define EDIM   256
#define FBIG   3.0e38f

typedef _Float16 half8 __attribute__((ext_vector_type(8)));
typedef float    f32x4 __attribute__((ext_vector_type(4)));

__device__ inline unsigned pk2h(_Float16 a, _Float16 b) {
    union { _Float16 h[2]; unsigned u; } q; q.h[0] = a; q.h[1] = b; return q.u;
}

// ---------------------------------------------------------------------------
// GEMM (NT) via fp16-split MFMA, BM=64 x BN=256 (full N per block -> A is
// converted exactly once across the grid). Split-K over blockIdx.z writes
// partials; bias!=nullptr (S=1) fuses bias+relu. W pre-scaled 2^10.
// D += Ah*Bh + Ah*Bl + Al*Bh. 256 thr = 4 waves; wave = 64 rows x 64 cols.
// ---------------------------------------------------------------------------
#define ASTR 20   // uints per LDS k-row (80B): bank phase period 8 -> 2-way (free)
__global__ __launch_bounds__(256)
void k_gemm_splitk(const float* __restrict__ S0, int n0,
                   const float* __restrict__ S1, int n1,
                   const float* __restrict__ S2,
                   const float* __restrict__ W,
                   float* __restrict__ Part, int Mtot, int K, int kchunk,
                   const float* __restrict__ bias) {
    __shared__ alignas(16) unsigned AsH[64 * ASTR],  AsL[64 * ASTR];
    __shared__ alignas(16) unsigned BsH[256 * ASTR], BsL[256 * ASTR];
    const int tid = threadIdx.x;
    const int m0  = blockIdx.x * 64;
    const int ks  = blockIdx.z;
    const int kb  = ks * kchunk;
    const int ke  = (kb + kchunk < K) ? kb + kchunk : K;

    const int sar = tid >> 2, sak = (tid & 3) << 3;   // A: row 0..63, k 0/8/16/24
    const int gr  = m0 + sar;
    const float* srow = nullptr;
    if (gr < n0)            srow = S0 + (size_t)gr * K;
    else if (gr < n0 + n1)  srow = S1 + (size_t)(gr - n0) * K;
    else if (gr < Mtot)     srow = S2;                // single virtual row

    const int lane = tid & 63, wv = tid >> 6;
    const int wc = wv << 6;                           // wave col base
    const int lr = lane & 15, lq = lane >> 4;

    f32x4 acc[4][4] = {};

    for (int k0 = kb; k0 < ke; k0 += 32) {
        {   // ---- stage A (64x32), 8 elements/thread ----
            float x[8];
            if (srow) {
                const float4 f0 = *(const float4*)(srow + k0 + sak + 0);
                const float4 f1 = *(const float4*)(srow + k0 + sak + 4);
                x[0]=f0.x; x[1]=f0.y; x[2]=f0.z; x[3]=f0.w;
                x[4]=f1.x; x[5]=f1.y; x[6]=f1.z; x[7]=f1.w;
            } else {
                #pragma unroll
                for (int j = 0; j < 8; ++j) x[j] = 0.f;
            }
            unsigned uh[4], ul[4];
            #pragma unroll
            for (int j = 0; j < 4; ++j) {
                const _Float16 h0 = (_Float16)x[2*j],   h1 = (_Float16)x[2*j+1];
                const _Float16 l0 = (_Float16)(x[2*j]   - (float)h0);
                const _Float16 l1 = (_Float16)(x[2*j+1] - (float)h1);
                uh[j] = pk2h(h0, h1); ul[j] = pk2h(l0, l1);
            }
            *(uint4*)(AsH + sar * ASTR + (sak >> 1)) = make_uint4(uh[0],uh[1],uh[2],uh[3]);
            *(uint4*)(AsL + sar * ASTR + (sak >> 1)) = make_uint4(ul[0],ul[1],ul[2],ul[3]);
        }
        // ---- stage B = all 256 W rows, pre-scaled 2^10; 4 iters x 8 elems ----
        #pragma unroll
        for (int it = 0; it < 4; ++it) {
            const int idx = tid + it * 256;            // 0..1023
            const int br = idx >> 2, bk = (idx & 3) << 3;
            const float* wr_ = W + (size_t)br * K + k0 + bk;
            const float4 f0 = *(const float4*)(wr_ + 0);
            const float4 f1 = *(const float4*)(wr_ + 4);
            const float y[8] = {f0.x,f0.y,f0.z,f0.w,f1.x,f1.y,f1.z,f1.w};
            unsigned uh[4], ul[4];
            #pragma unroll
            for (int j = 0; j < 4; ++j) {
                const float a0 = y[2*j] * 1024.0f, a1 = y[2*j+1] * 1024.0f;
                const _Float16 h0 = (_Float16)a0, h1 = (_Float16)a1;
                const _Float16 l0 = (_Float16)(a0 - (float)h0);
                const _Float16 l1 = (_Float16)(a1 - (float)h1);
                uh[j] = pk2h(h0, h1); ul[j] = pk2h(l0, l1);
            }
            *(uint4*)(BsH + br * ASTR + (bk >> 1)) = make_uint4(uh[0],uh[1],uh[2],uh[3]);
            *(uint4*)(BsL + br * ASTR + (bk >> 1)) = make_uint4(ul[0],ul[1],ul[2],ul[3]);
        }
        __syncthreads();

        half8 bhv[4], blv[4];
        #pragma unroll
        for (int ct = 0; ct < 4; ++ct) {
            const int br = wc + ct * 16 + lr;
            bhv[ct] = *(const half8*)((const char*)BsH + br * 80 + lq * 16);
            blv[ct] = *(const half8*)((const char*)BsL + br * 80 + lq * 16);
        }
        #pragma unroll
        for (int rt = 0; rt < 4; ++rt) {
            const int ar = rt * 16 + lr;
            const half8 ah = *(const half8*)((const char*)AsH + ar * 80 + lq * 16);
            const half8 al = *(const half8*)((const char*)AsL + ar * 80 + lq * 16);
            #pragma unroll
            for (int ct = 0; ct < 4; ++ct) {
                acc[rt][ct] = __builtin_amdgcn_mfma_f32_16x16x32_f16(ah, bhv[ct], acc[rt][ct], 0, 0, 0);
                acc[rt][ct] = __builtin_amdgcn_mfma_f32_16x16x32_f16(ah, blv[ct], acc[rt][ct], 0, 0, 0);
                acc[rt][ct] = __builtin_amdgcn_mfma_f32_16x16x32_f16(al, bhv[ct], acc[rt][ct], 0, 0, 0);
            }
        }
        __syncthreads();
    }

    float* pout = Part + (size_t)ks * ((size_t)Mtot * EDIM);
    const float sc = 1.0f / 1024.0f;
    #pragma unroll
    for (int rt = 0; rt < 4; ++rt) {
        #pragma unroll
        for (int r = 0; r < 4; ++r) {
            const int grr = m0 + rt * 16 + lq * 4 + r;
            if (grr >= Mtot) continue;
            #pragma unroll
            for (int ct = 0; ct < 4; ++ct) {
                const int gc = wc + ct * 16 + lr;
                float vv = acc[rt][ct][r] * sc;
                if (bias) vv = fmaxf(vv + bias[gc], 0.0f);
                pout[(size_t)grr * EDIM + gc] = vv;
            }
        }
    }
}

// Reduce split-K partials + bias + relu. Deterministic fixed-order sum.
__global__ __launch_bounds__(256)
void k_reduce_bias_relu(const float* __restrict__ Part,
                        const float* __restrict__ bias,
                        float* __restrict__ C, int S, size_t MN4) {
    const size_t i = (size_t)blockIdx.x * blockDim.x + threadIdx.x;
    const size_t stride = (size_t)gridDim.x * blockDim.x;
    const size_t MN = MN4 * 4;
    for (size_t i4 = i; i4 < MN4; i4 += stride) {
        float4 s = ((const float4*)Part)[i4];
        for (int z = 1; z < S; ++z)
            { const float4 q = ((const float4*)(Part + (size_t)z * MN))[i4];
              s.x += q.x; s.y += q.y; s.z += q.z; s.w += q.w; }
        const float4 b = ((const float4*)bias)[i4 & 63];   // EDIM/4 = 64
        s.x = fmaxf(s.x + b.x, 0.f); s.y = fmaxf(s.y + b.y, 0.f);
        s.z = fmaxf(s.z + b.z, 0.f); s.w = fmaxf(s.w + b.w, 0.f);
        ((float4*)C)[i4] = s;
    }
}

// ---------------------------------------------------------------------------
// Direct fp32 GEMM (NT, fused bias+relu) — fallback only (ws too small).
// ---------------------------------------------------------------------------
__global__ __launch_bounds__(256)
void k_embed_gemm(const float* __restrict__ S0, int n0,
                  const float* __restrict__ S1, int n1,
                  const float* __restrict__ S2,
                  const float* __restrict__ W, const float* __restrict__ bias,
                  float* __restrict__ C, int Mtot, int K) {
    __shared__ alignas(16) float As[16][68];
    __shared__ alignas(16) float Bs[16][68];
    const int tid  = threadIdx.x;
    const int tx   = tid & 15, ty = tid >> 4;
    const int m0   = blockIdx.x * 64, nc0 = blockIdx.y * 64;
    const int lrow = tid >> 2;
    const int lk4  = (tid & 3) << 2;

    const int gr = m0 + lrow;
    const float* srow = nullptr;
    if (gr < n0)            srow = S0 + (size_t)gr * K;
    else if (gr < n0 + n1)  srow = S1 + (size_t)(gr - n0) * K;
    else if (gr < Mtot)     srow = S2;
    const float* wrow = W + (size_t)(nc0 + lrow) * K;

    float acc[4][4] = {};
    for (int k0 = 0; k0 < K; k0 += 16) {
        float4 va = make_float4(0.f, 0.f, 0.f, 0.f);
        if (srow) va = *(const float4*)(srow + k0 + lk4);
        const float4 vb = *(const float4*)(wrow + k0 + lk4);
        As[lk4+0][lrow] = va.x; As[lk4+1][lrow] = va.y;
        As[lk4+2][lrow] = va.z; As[lk4+3][lrow] = va.w;
        Bs[lk4+0][lrow] = vb.x; Bs[lk4+1][lrow] = vb.y;
        Bs[lk4+2][lrow] = vb.z; Bs[lk4+3][lrow] = vb.w;
        __syncthreads();
        #pragma unroll
        for (int kk = 0; kk < 16; ++kk) {
            const float4 a4 = *(const float4*)&As[kk][ty << 2];
            const float4 b4 = *(const float4*)&Bs[kk][tx << 2];
            const float av[4] = {a4.x, a4.y, a4.z, a4.w};
            const float bv[4] = {b4.x, b4.y, b4.z, b4.w};
            #pragma unroll
            for (int i2 = 0; i2 < 4; ++i2)
                #pragma unroll
                for (int j2 = 0; j2 < 4; ++j2)
                    acc[i2][j2] = fmaf(av[i2], bv[j2], acc[i2][j2]);
        }
        __syncthreads();
    }
    #pragma unroll
    for (int i2 = 0; i2 < 4; ++i2) {
        const int grr = m0 + (ty << 2) + i2;
        if (grr >= Mtot) continue;
        #pragma unroll
        for (int j2 = 0; j2 < 4; ++j2) {
            const int gc = nc0 + (tx << 2) + j2;
            const float vv = acc[i2][j2] + bias[gc];
            C[(size_t)grr * EDIM + gc] = fmaxf(vv, 0.0f);
        }
    }
}

// ---------------------------------------------------------------------------
// Per-pair scaled edit-cost matrix via MFMA Gram (fp16 3-term split).
// A = pair's padded source embeddings (rows 0..n; row n = virtual), B = target.
// Gram = A @ B^T over K=256; d_ij = sqrt(max(na_i + nb_j - 2*Gram_ij, 0)).
// 4 waves share the 3x3 grid of 16x16 output tiles (48x48 covers 33x33).
// ---------------------------------------------------------------------------
#define CSTR 36   // uints per staged k-row (64 halfs + pad): bank-phase 2-way (free)
__global__ __launch_bounds__(256)
void k_costs(const float* __restrict__ Emb, const int* __restrict__ len_s,
             const int* __restrict__ len_t, int Ns, int Nt,
             float* __restrict__ costs) {
    __shared__ alignas(16) unsigned Ah[34 * CSTR], Al[34 * CSTR];
    __shared__ alignas(16) unsigned Bh[34 * CSTR], Bl[34 * CSTR];
    __shared__ float dtile[LMAXP1 * LMAXP1];
    __shared__ float na[LMAXP1], nb[LMAXP1];
    __shared__ float red[256];
    __shared__ float s_scale;
    const int p = blockIdx.x, tid = threadIdx.x;
    const int n = len_s[p], m = len_t[p];
    int offs = 0, offt = 0;
    for (int j = 0; j < p; ++j) { offs += len_s[j]; offt += len_t[j]; }  // uniform
    const int veRow = Ns + Nt;
    const int tbase = Ns + offt;

    const int lane = tid & 63, wv = tid >> 6;
    const int lr = lane & 15, lq = lane >> 4;

    // ---- na/nb (fp32, from global) ----
    if (tid <= n) {
        const float* src = (tid < n) ? (Emb + (size_t)(offs + tid) * EDIM)
                                     : (Emb + (size_t)veRow * EDIM);
        const float4* a4 = (const float4*)src;
        float s = 0.f;
        for (int k = 0; k < 64; ++k) {
            const float4 a = a4[k];
            s = fmaf(a.x, a.x, s); s = fmaf(a.y, a.y, s);
            s = fmaf(a.z, a.z, s); s = fmaf(a.w, a.w, s);
        }
        na[tid] = s;
    } else if (tid >= 64 && tid - 64 <= m) {
        const int j = tid - 64;
        const float* src = (j < m) ? (Emb + (size_t)(tbase + j) * EDIM)
                                   : (Emb + (size_t)veRow * EDIM);
        const float4* b4 = (const float4*)src;
        float s = 0.f;
        for (int k = 0; k < 64; ++k) {
            const float4 b = b4[k];
            s = fmaf(b.x, b.x, s); s = fmaf(b.y, b.y, s);
            s = fmaf(b.z, b.z, s); s = fmaf(b.w, b.w, s);
        }
        nb[j] = s;
    }

    // ---- Gram via MFMA; wave wv owns tiles {wv, wv+4, wv+8(<9)} ----
    f32x4 g0 = {}, g1 = {}, g2 = {};
    const int t0 = wv, t1 = wv + 4, t2 = wv + 8;

    for (int k0 = 0; k0 < EDIM; k0 += 64) {
        for (int idx = tid; idx < 34 * 16; idx += 256) {
            const int r = idx >> 4, c4 = idx & 15;
            float4 va = make_float4(0.f,0.f,0.f,0.f), vb = va;
            if (r < n)       va = *(const float4*)(Emb + (size_t)(offs + r) * EDIM + k0 + c4*4);
            else if (r == n) va = *(const float4*)(Emb + (size_t)veRow * EDIM + k0 + c4*4);
            if (r < m)       vb = *(const float4*)(Emb + (size_t)(tbase + r) * EDIM + k0 + c4*4);
            else if (r == m) vb = *(const float4*)(Emb + (size_t)veRow * EDIM + k0 + c4*4);
            const float xa[4] = {va.x, va.y, va.z, va.w};
            const float xb[4] = {vb.x, vb.y, vb.z, vb.w};
            unsigned ah_[2], al_[2], bh_[2], bl_[2];
            #pragma unroll
            for (int j = 0; j < 2; ++j) {
                const _Float16 h0 = (_Float16)xa[2*j],   h1 = (_Float16)xa[2*j+1];
                const _Float16 l0 = (_Float16)(xa[2*j]   - (float)h0);
                const _Float16 l1 = (_Float16)(xa[2*j+1] - (float)h1);
                ah_[j] = pk2h(h0, h1); al_[j] = pk2h(l0, l1);
                const _Float16 g0_ = (_Float16)xb[2*j],   g1_ = (_Float16)xb[2*j+1];
                const _Float16 m0_ = (_Float16)(xb[2*j]   - (float)g0_);
                const _Float16 m1_ = (_Float16)(xb[2*j+1] - (float)g1_);
                bh_[j] = pk2h(g0_, g1_); bl_[j] = pk2h(m0_, m1_);
            }
            const int uo = r * CSTR + c4 * 2;
            *(uint2*)(Ah + uo) = make_uint2(ah_[0], ah_[1]);
            *(uint2*)(Al + uo) = make_uint2(al_[0], al_[1]);
            *(uint2*)(Bh + uo) = make_uint2(bh_[0], bh_[1]);
            *(uint2*)(Bl + uo) = make_uint2(bl_[0], bl_[1]);
        }
        __syncthreads();

        #pragma unroll
        for (int kf = 0; kf < 2; ++kf) {
#define GRAM_TILE(T, G) { \
            const int tr_ = (T) / 3, tc_ = (T) % 3;                              \
            const int ar_ = tr_ * 16 + lr, br_ = tc_ * 16 + lr;                  \
            const half8 ah = *(const half8*)((const char*)Ah + ar_*144 + kf*64 + lq*16); \
            const half8 al = *(const half8*)((const char*)Al + ar_*144 + kf*64 + lq*16); \
            const half8 bh = *(const half8*)((const char*)Bh + br_*144 + kf*64 + lq*16); \
            const half8 bl = *(const half8*)((const char*)Bl + br_*144 + kf*64 + lq*16); \
            G = __builtin_amdgcn_mfma_f32_16x16x32_f16(ah, bh, G, 0, 0, 0);      \
            G = __builtin_amdgcn_mfma_f32_16x16x32_f16(ah, bl, G, 0, 0, 0);      \
            G = __builtin_amdgcn_mfma_f32_16x16x32_f16(al, bh, G, 0, 0, 0); }
            GRAM_TILE(t0, g0)
            GRAM_TILE(t1, g1)
            if (wv == 0) GRAM_TILE(t2, g2)
#undef GRAM_TILE
        }
        __syncthreads();
    }

    // ---- dtile from Gram (C/D map: col=lane&15, row=(lane>>4)*4+reg) ----
#define DTILE_OUT(T, G) { \
    const int tr_ = (T) / 3, tc_ = (T) % 3;                                      \
    _Pragma("unroll")                                                            \
    for (int r = 0; r < 4; ++r) {                                                \
        const int i_ = tr_ * 16 + lq * 4 + r, j_ = tc_ * 16 + lr;                \
        if (i_ <= n && j_ <= m) {                                                \
            const float sq = fmaxf(na[i_] + nb[j_] - 2.0f * G[r], 0.0f);         \
            dtile[i_ * LMAXP1 + j_] = (sq > 0.0f) ? sqrtf(sq) : 0.0f;            \
        } } }
    DTILE_OUT(t0, g0)
    DTILE_OUT(t1, g1)
    if (wv == 0) DTILE_OUT(t2, g2)
#undef DTILE_OUT
    __syncthreads();

    // ---- scale and write ----
    float lsum = 0.f;
    const int m1 = m + 1;
    const int cells = (n + 1) * m1;
    for (int c = tid; c < cells; c += 256) {
        const int i = c / m1, j = c - i * m1;
        lsum += dtile[i * LMAXP1 + j];
    }
    red[tid] = lsum;
    __syncthreads();
    for (int s = 128; s > 0; s >>= 1) {
        if (tid < s) red[tid] += red[tid + s];
        __syncthreads();
    }
    if (tid == 0) s_scale = (float)(n * m) / red[0];
    __syncthreads();
    const float scale = s_scale;
    for (int idx = tid; idx < LMAXP1 * LMAXP1; idx += 256) {
        const int i = idx / LMAXP1, j = idx - i * LMAXP1;
        const float v = (i <= n && j <= m) ? dtile[i * LMAXP1 + j] * scale : 0.0f;
        costs[(size_t)p * (LMAXP1 * LMAXP1) + idx] = v;
    }
}

// ---------------------------------------------------------------------------
// LAP via exact LSAPE reduction to max(n,m)^2 square LAP + col-reduction/
// greedy init; JV Dijkstra core with packed u32 DPP argmin (R12-verified).
// ---------------------------------------------------------------------------
__device__ inline int rdlane_i(int v, int l) { return __builtin_amdgcn_readlane(v, l); }
__device__ inline float rdlane_f(float v, int l) {
    return __int_as_float(__builtin_amdgcn_readlane(__float_as_int(v), l));
}
__device__ inline unsigned wave_umin64(unsigned x) {
#define DPPMINU(ctrl) { unsigned t_ = (unsigned)__builtin_amdgcn_update_dpp(  \
        (int)x, (int)x, (ctrl), 0xf, 0xf, false);                             \
        x = (t_ < x) ? t_ : x; }
    DPPMINU(0xB1)
    DPPMINU(0x4E)
    DPPMINU(0x141)
    DPPMINU(0x140)
    DPPMINU(0x142)
    DPPMINU(0x143)
#undef DPPMINU
    return (unsigned)__builtin_amdgcn_readlane((int)x, 63);
}

__global__ __launch_bounds__(64)
void k_lap(const float* __restrict__ costs, const int* __restrict__ len_s,
           const int* __restrict__ len_t, float* __restrict__ aligns,
           float* __restrict__ geds) {
    __shared__ float ec[LMAXP1 * LMAXP1];
    __shared__ float Ms[33 * 64];
    const int p = blockIdx.x, lane = threadIdx.x;
    const int n = len_s[p], m = len_t[p];
    const float* cp = costs + (size_t)p * (LMAXP1 * LMAXP1);
    for (int idx = lane; idx < LMAXP1 * LMAXP1; idx += 64) ec[idx] = cp[idx];
    __syncthreads();

    const bool swp = (n > m);
    const int R  = swp ? n : m;
    const int S_ = swp ? m : n;
    const bool vec = (lane >= 1 && lane <= R);

    for (int r = 1; r <= R; ++r) {
        float cv = FBIG;
        const int i0b = r - 1, j0b = lane - 1;
        if (vec) {
            if (!swp) {
                const float ins = ec[n * LMAXP1 + j0b];
                cv = (i0b < S_)
                   ? fminf(ec[i0b * LMAXP1 + j0b], ec[i0b * LMAXP1 + m] + ins)
                   : ins;
            } else {
                const float ins = ec[j0b * LMAXP1 + m];
                cv = (i0b < S_)
                   ? fminf(ec[j0b * LMAXP1 + i0b], ec[n * LMAXP1 + i0b] + ins)
                   : ins;
            }
        }
        Ms[(r << 6) + lane] = cv;
    }
    __syncthreads();

    // ---- column reduction + greedy ----
    float v_l = 0.0f;
    int amin_l = 0;
    if (vec) {
        float best = FBIG;
        for (int r = 1; r <= R; ++r) {
            const float c = Ms[(r << 6) + lane];
            if (c < best) { best = c; amin_l = r; }
        }
        v_l = best;
    }
    int p_l = 0;
    unsigned long long rowfree = ((1ull << R) - 1ull) << 1;
    for (int j = 1; j <= R; ++j) {
        const int ai = rdlane_i(amin_l, j);
        if ((rowfree >> ai) & 1ull) {
            if (lane == j) p_l = ai;
            rowfree &= ~(1ull << ai);
        }
    }

    // ---- JV Dijkstra for remaining free rows ----
    float ucol = 0.0f, minv_l = FBIG;
    int way_l = 0;

    for (int i = 1; i <= R; ++i) {
        if (!((rowfree >> i) & 1ull)) continue;
        if (lane == 0) { p_l = i; ucol = 0.0f; }
        minv_l = FBIG;
        int used_l = 0;
        int j0 = 0, i0 = i;
        float u_i0 = 0.0f;
        while (true) {
            if (lane == j0) used_l = 1;
            const float cur = Ms[(i0 << 6) + lane] - u_i0 - v_l;
            const bool unused = vec && !used_l;
            if (unused && cur < minv_l) { minv_l = cur; way_l = j0; }
            const float mval = unused ? fmaxf(minv_l, 0.0f) : FBIG;
            const unsigned key = (__float_as_uint(mval) & ~63u) | (unsigned)lane;
            const unsigned kmin = wave_umin64(key);
            const int j1 = (int)(kmin & 63u);
            const float delta = rdlane_f(minv_l, j1);
            if (used_l) { ucol += delta; v_l -= delta; }
            if (unused) minv_l -= delta;
            j0 = j1;
            i0 = rdlane_i(p_l, j1);
            u_i0 = rdlane_f(ucol, j1);
            if (i0 == 0) break;
        }
        int jj = j0;
        while (jj != 0) {
            const int   j1a = rdlane_i(way_l, jj);
            const int   pn  = rdlane_i(p_l, j1a);
            const float un  = rdlane_f(ucol, j1a);
            if (lane == jj) { p_l = pn; ucol = un; }
            jj = j1a;
        }
    }

    // ---- decode ----
    float* ap = aligns + (size_t)p * (LMAXP1 * LMAXP1);
    for (int idx = lane; idx < LMAXP1 * LMAXP1; idx += 64) ap[idx] = 0.0f;
    __syncthreads();
    float gedv = 0.0f;
    if (vec) {
        const int i0b = p_l - 1;
        const int j0b = lane - 1;
        if (!swp) {
            if (i0b < S_) {
                const float sub = ec[i0b * LMAXP1 + j0b];
                const float alt = ec[i0b * LMAXP1 + m] + ec[n * LMAXP1 + j0b];
                if (sub <= alt) { ap[i0b * LMAXP1 + j0b] = 1.0f; gedv = sub; }
                else { ap[i0b * LMAXP1 + m] = 1.0f;
                       ap[n * LMAXP1 + j0b] = 1.0f;
                       gedv = alt; }
            } else {
                ap[n * LMAXP1 + j0b] = 1.0f;
                gedv = ec[n * LMAXP1 + j0b];
            }
        } else {
            if (i0b < S_) {
                const float sub = ec[j0b * LMAXP1 + i0b];
                const float alt = ec[n * LMAXP1 + i0b] + ec[j0b * LMAXP1 + m];
                if (sub <= alt) { ap[j0b * LMAXP1 + i0b] = 1.0f; gedv = sub; }
                else { ap[n * LMAXP1 + i0b] = 1.0f;
                       ap[j0b * LMAXP1 + m] = 1.0f;
                       gedv = alt; }
            } else {
                ap[j0b * LMAXP1 + m] = 1.0f;
                gedv = ec[j0b * LMAXP1 + m];
            }
        }
    }
    #pragma unroll
    for (int off = 32; off > 0; off >>= 1) gedv += __shfl_xor(gedv, off);
    if (lane == 0) geds[p] = gedv / (float)(n + m);
}

// ---------------------------------------------------------------------------
extern "C" void kernel_launch(void* const* d_in, const int* in_sizes, int n_in,
                              void* d_out, int out_size, void* d_ws, size_t ws_size,
                              hipStream_t stream) {
    const float* x_s = (const float*)d_in[0];
    const float* x_t = (const float*)d_in[1];
    const float* W1  = (const float*)d_in[2];
    const float* b1  = (const float*)d_in[3];
    const float* W2  = (const float*)d_in[4];
    const float* b2  = (const float*)d_in[5];
    const float* ve  = (const float*)d_in[6];
    const int* len_s = (const int*)d_in[7];
    const int* len_t = (const int*)d_in[8];
    const int P    = in_sizes[7];
    const int Ns   = in_sizes[0] / 2048;
    const int Nt   = in_sizes[1] / 2048;
    const int Mtot = Ns + Nt + 1;
    const size_t MN  = (size_t)Mtot * EDIM;

    float* H    = (float*)d_ws;
    float* Emb  = H + MN;
    float* Part = Emb + MN;

    int S = 1;
    if (ws_size >= (2 + 4) * MN * sizeof(float)) S = 4;
    else if (ws_size >= (2 + 2) * MN * sizeof(float)) S = 2;

    float* out_aligns = (float*)d_out;
    float* out_costs  = out_aligns + (size_t)P * LMAXP1 * LMAXP1;
    float* out_geds   = out_costs  + (size_t)P * LMAXP1 * LMAXP1;

    const dim3 b256(256);
    const int gx64 = (Mtot + 63) / 64;

    if (S > 1) {
        k_gemm_splitk<<<dim3(gx64, 1, S), b256, 0, stream>>>(
            x_s, Ns, x_t, Nt, ve, W1, Part, Mtot, 2048, 2048 / S, nullptr);
        const size_t MN4 = MN / 4;
        const int rblocks = (int)((MN4 + 255) / 256) < 2048
                          ? (int)((MN4 + 255) / 256) : 2048;
        k_reduce_bias_relu<<<dim3(rblocks), b256, 0, stream>>>(Part, b1, H, S, MN4);
        k_gemm_splitk<<<dim3(gx64, 1, 1), b256, 0, stream>>>(
            H, Mtot, nullptr, 0, nullptr, W2, Emb, Mtot, 256, 256, b2);
    } else {
        k_embed_gemm<<<dim3(gx64, 4), b256, 0, stream>>>(
            x_s, Ns, x_t, Nt, ve, W1, b1, H, Mtot, 2048);
        k_embed_gemm<<<dim3(gx64, 4), b256, 0, stream>>>(
            H, Mtot, nullptr, 0, nullptr, W2, b2, Emb, Mtot, 256);
    }
    k_costs<<<dim3(P), b256, 0, stream>>>(Emb, len_s, len_t, Ns, Nt, out_costs);
    k_lap<<<dim3(P), dim3(64), 0, stream>>>(out_costs, len_s, len_t, out_aligns, out_geds);
}

// Round 14
// 174.860 us; speedup vs baseline: 3.2924x; 1.0300x over previous
//
#include <hip/hip_runtime.h>
#include <math.h>

#define LMAXP1 33
#define EDIM   256
#define FBIG   3.0e38f

typedef _Float16 half8 __attribute__((ext_vector_type(8)));
typedef float    f32x4 __attribute__((ext_vector_type(4)));

__device__ inline unsigned pk2h(_Float16 a, _Float16 b) {
    union { _Float16 h[2]; unsigned u; } q; q.h[0] = a; q.h[1] = b; return q.u;
}

// ---------------------------------------------------------------------------
// Pre-convert a fp32 weight matrix to fp16 hi/lo planes, pre-scaled by 2^10.
// One thread = 2 elements = 1 uint per plane.
// ---------------------------------------------------------------------------
__global__ __launch_bounds__(256)
void k_convw(const float* __restrict__ W, unsigned* __restrict__ Wh,
             unsigned* __restrict__ Wl, int npairs) {
    const int stride = gridDim.x * blockDim.x;
    for (int i = blockIdx.x * blockDim.x + threadIdx.x; i < npairs; i += stride) {
        const float a0 = W[2*i] * 1024.0f, a1 = W[2*i+1] * 1024.0f;
        const _Float16 h0 = (_Float16)a0, h1 = (_Float16)a1;
        const _Float16 l0 = (_Float16)(a0 - (float)h0);
        const _Float16 l1 = (_Float16)(a1 - (float)h1);
        Wh[i] = pk2h(h0, h1); Wl[i] = pk2h(l0, l1);
    }
}

// ---------------------------------------------------------------------------
// Split-K GEMM (NT) via fp16-split MFMA. A = fp32 3-source gather (converted
// in-kernel, once per element across grid); B = PRE-CONVERTED fp16 planes
// (staging = pure uint4 copies). Writes raw partials Part[ks].
// BM=64 x BN=256, 256 thr = 4 waves; wave = 64 rows x 64 cols.
// ---------------------------------------------------------------------------
#define ASTR 20   // uints per LDS k-row (80B): bank phase -> 2-way (free)
__global__ __launch_bounds__(256)
void k_gemm_splitk(const float* __restrict__ S0, int n0,
                   const float* __restrict__ S1, int n1,
                   const float* __restrict__ S2,
                   const unsigned* __restrict__ Wh, const unsigned* __restrict__ Wl,
                   float* __restrict__ Part, int Mtot, int K, int kchunk) {
    __shared__ alignas(16) unsigned AsH[64 * ASTR],  AsL[64 * ASTR];
    __shared__ alignas(16) unsigned BsH[256 * ASTR], BsL[256 * ASTR];
    const int tid = threadIdx.x;
    const int m0  = blockIdx.x * 64;
    const int ks  = blockIdx.z;
    const int kb  = ks * kchunk;
    const int ke  = (kb + kchunk < K) ? kb + kchunk : K;

    const int sar = tid >> 2, sak = (tid & 3) << 3;   // A: row 0..63, k {0,8,16,24}
    const int gr  = m0 + sar;
    const float* srow = nullptr;
    if (gr < n0)            srow = S0 + (size_t)gr * K;
    else if (gr < n0 + n1)  srow = S1 + (size_t)(gr - n0) * K;
    else if (gr < Mtot)     srow = S2;                // single virtual row

    const int lane = tid & 63, wv = tid >> 6;
    const int wc = wv << 6;
    const int lr = lane & 15, lq = lane >> 4;

    f32x4 acc[4][4] = {};

    for (int k0 = kb; k0 < ke; k0 += 32) {
        {   // ---- stage A (64x32 fp32 -> hi/lo fp16), 8 elems/thread ----
            float x[8];
            if (srow) {
                const float4 f0 = *(const float4*)(srow + k0 + sak + 0);
                const float4 f1 = *(const float4*)(srow + k0 + sak + 4);
                x[0]=f0.x; x[1]=f0.y; x[2]=f0.z; x[3]=f0.w;
                x[4]=f1.x; x[5]=f1.y; x[6]=f1.z; x[7]=f1.w;
            } else {
                #pragma unroll
                for (int j = 0; j < 8; ++j) x[j] = 0.f;
            }
            unsigned uh[4], ul[4];
            #pragma unroll
            for (int j = 0; j < 4; ++j) {
                const _Float16 h0 = (_Float16)x[2*j],   h1 = (_Float16)x[2*j+1];
                const _Float16 l0 = (_Float16)(x[2*j]   - (float)h0);
                const _Float16 l1 = (_Float16)(x[2*j+1] - (float)h1);
                uh[j] = pk2h(h0, h1); ul[j] = pk2h(l0, l1);
            }
            *(uint4*)(AsH + sar * ASTR + (sak >> 1)) = make_uint4(uh[0],uh[1],uh[2],uh[3]);
            *(uint4*)(AsL + sar * ASTR + (sak >> 1)) = make_uint4(ul[0],ul[1],ul[2],ul[3]);
        }
        // ---- stage B: pure copies from pre-converted planes ----
        #pragma unroll
        for (int it = 0; it < 4; ++it) {
            const int idx = tid + it * 256;            // 0..1023
            const int br = idx >> 2, bk = (idx & 3) << 3;
            const size_t uoff = (size_t)br * (K >> 1) + ((k0 + bk) >> 1);
            *(uint4*)(BsH + br * ASTR + (bk >> 1)) = *(const uint4*)(Wh + uoff);
            *(uint4*)(BsL + br * ASTR + (bk >> 1)) = *(const uint4*)(Wl + uoff);
        }
        __syncthreads();

        half8 bhv[4], blv[4];
        #pragma unroll
        for (int ct = 0; ct < 4; ++ct) {
            const int br = wc + ct * 16 + lr;
            bhv[ct] = *(const half8*)((const char*)BsH + br * 80 + lq * 16);
            blv[ct] = *(const half8*)((const char*)BsL + br * 80 + lq * 16);
        }
        #pragma unroll
        for (int rt = 0; rt < 4; ++rt) {
            const int ar = rt * 16 + lr;
            const half8 ah = *(const half8*)((const char*)AsH + ar * 80 + lq * 16);
            const half8 al = *(const half8*)((const char*)AsL + ar * 80 + lq * 16);
            #pragma unroll
            for (int ct = 0; ct < 4; ++ct) {
                acc[rt][ct] = __builtin_amdgcn_mfma_f32_16x16x32_f16(ah, bhv[ct], acc[rt][ct], 0, 0, 0);
                acc[rt][ct] = __builtin_amdgcn_mfma_f32_16x16x32_f16(ah, blv[ct], acc[rt][ct], 0, 0, 0);
                acc[rt][ct] = __builtin_amdgcn_mfma_f32_16x16x32_f16(al, bhv[ct], acc[rt][ct], 0, 0, 0);
            }
        }
        __syncthreads();
    }

    float* pout = Part + (size_t)ks * ((size_t)Mtot * EDIM);
    const float sc = 1.0f / 1024.0f;
    #pragma unroll
    for (int rt = 0; rt < 4; ++rt) {
        #pragma unroll
        for (int r = 0; r < 4; ++r) {
            const int grr = m0 + rt * 16 + lq * 4 + r;
            if (grr >= Mtot) continue;
            #pragma unroll
            for (int ct = 0; ct < 4; ++ct)
                pout[(size_t)grr * EDIM + wc + ct * 16 + lr] = acc[rt][ct][r] * sc;
        }
    }
}

// ---------------------------------------------------------------------------
// Reduce split-K partials + bias + relu -> fp16 hi/lo planes directly
// (nobody consumes fp32 H). Deterministic fixed-order sum.
// ---------------------------------------------------------------------------
__global__ __launch_bounds__(256)
void k_reduce_bias_relu(const float* __restrict__ Part,
                        const float* __restrict__ bias,
                        unsigned* __restrict__ Hh, unsigned* __restrict__ Hl,
                        int S, size_t MN4) {
    const size_t i = (size_t)blockIdx.x * blockDim.x + threadIdx.x;
    const size_t stride = (size_t)gridDim.x * blockDim.x;
    const size_t MN = MN4 * 4;
    for (size_t i4 = i; i4 < MN4; i4 += stride) {
        float4 s = ((const float4*)Part)[i4];
        for (int z = 1; z < S; ++z)
            { const float4 q = ((const float4*)(Part + (size_t)z * MN))[i4];
              s.x += q.x; s.y += q.y; s.z += q.z; s.w += q.w; }
        const float4 b = ((const float4*)bias)[i4 & 63];   // EDIM/4 = 64
        s.x = fmaxf(s.x + b.x, 0.f); s.y = fmaxf(s.y + b.y, 0.f);
        s.z = fmaxf(s.z + b.z, 0.f); s.w = fmaxf(s.w + b.w, 0.f);
        const _Float16 hx = (_Float16)s.x, hy = (_Float16)s.y;
        const _Float16 hz = (_Float16)s.z, hw = (_Float16)s.w;
        Hh[i4*2+0] = pk2h(hx, hy);
        Hh[i4*2+1] = pk2h(hz, hw);
        Hl[i4*2+0] = pk2h((_Float16)(s.x - (float)hx), (_Float16)(s.y - (float)hy));
        Hl[i4*2+1] = pk2h((_Float16)(s.z - (float)hz), (_Float16)(s.w - (float)hw));
    }
}

// ---------------------------------------------------------------------------
// Pure-fp16 GEMM (both sides pre-converted planes), fused bias+relu -> C.
// A contiguous M x K halfs; B = K-major weight planes. BM=64 x BN=256.
// ---------------------------------------------------------------------------
__global__ __launch_bounds__(256)
void k_gemm_f16(const unsigned* __restrict__ Ah, const unsigned* __restrict__ Al,
                const unsigned* __restrict__ Wh, const unsigned* __restrict__ Wl,
                const float* __restrict__ bias,
                float* __restrict__ C, int Mtot, int K) {
    __shared__ alignas(16) unsigned AsH[64 * ASTR],  AsL[64 * ASTR];
    __shared__ alignas(16) unsigned BsH[256 * ASTR], BsL[256 * ASTR];
    const int tid = threadIdx.x;
    const int m0  = blockIdx.x * 64;

    const int sar = tid >> 2, sak = (tid & 3) << 3;
    const int gr  = m0 + sar;
    const bool arow = (gr < Mtot);

    const int lane = tid & 63, wv = tid >> 6;
    const int wc = wv << 6;
    const int lr = lane & 15, lq = lane >> 4;

    f32x4 acc[4][4] = {};

    for (int k0 = 0; k0 < K; k0 += 32) {
        {   // ---- stage A: copies ----
            uint4 vh = make_uint4(0,0,0,0), vl = vh;
            if (arow) {
                const size_t uoff = (size_t)gr * (K >> 1) + ((k0 + sak) >> 1);
                vh = *(const uint4*)(Ah + uoff);
                vl = *(const uint4*)(Al + uoff);
            }
            *(uint4*)(AsH + sar * ASTR + (sak >> 1)) = vh;
            *(uint4*)(AsL + sar * ASTR + (sak >> 1)) = vl;
        }
        // ---- stage B: copies ----
        #pragma unroll
        for (int it = 0; it < 4; ++it) {
            const int idx = tid + it * 256;
            const int br = idx >> 2, bk = (idx & 3) << 3;
            const size_t uoff = (size_t)br * (K >> 1) + ((k0 + bk) >> 1);
            *(uint4*)(BsH + br * ASTR + (bk >> 1)) = *(const uint4*)(Wh + uoff);
            *(uint4*)(BsL + br * ASTR + (bk >> 1)) = *(const uint4*)(Wl + uoff);
        }
        __syncthreads();

        half8 bhv[4], blv[4];
        #pragma unroll
        for (int ct = 0; ct < 4; ++ct) {
            const int br = wc + ct * 16 + lr;
            bhv[ct] = *(const half8*)((const char*)BsH + br * 80 + lq * 16);
            blv[ct] = *(const half8*)((const char*)BsL + br * 80 + lq * 16);
        }
        #pragma unroll
        for (int rt = 0; rt < 4; ++rt) {
            const int ar = rt * 16 + lr;
            const half8 ah = *(const half8*)((const char*)AsH + ar * 80 + lq * 16);
            const half8 al = *(const half8*)((const char*)AsL + ar * 80 + lq * 16);
            #pragma unroll
            for (int ct = 0; ct < 4; ++ct) {
                acc[rt][ct] = __builtin_amdgcn_mfma_f32_16x16x32_f16(ah, bhv[ct], acc[rt][ct], 0, 0, 0);
                acc[rt][ct] = __builtin_amdgcn_mfma_f32_16x16x32_f16(ah, blv[ct], acc[rt][ct], 0, 0, 0);
                acc[rt][ct] = __builtin_amdgcn_mfma_f32_16x16x32_f16(al, bhv[ct], acc[rt][ct], 0, 0, 0);
            }
        }
        __syncthreads();
    }

    const float sc = 1.0f / 1024.0f;
    #pragma unroll
    for (int rt = 0; rt < 4; ++rt) {
        #pragma unroll
        for (int r = 0; r < 4; ++r) {
            const int grr = m0 + rt * 16 + lq * 4 + r;
            if (grr >= Mtot) continue;
            #pragma unroll
            for (int ct = 0; ct < 4; ++ct) {
                const int gc = wc + ct * 16 + lr;
                C[(size_t)grr * EDIM + gc] = fmaxf(acc[rt][ct][r] * sc + bias[gc], 0.0f);
            }
        }
    }
}

// ---------------------------------------------------------------------------
// Direct fp32 GEMM (NT, fused bias+relu) — fallback only (ws too small).
// ---------------------------------------------------------------------------
__global__ __launch_bounds__(256)
void k_embed_gemm(const float* __restrict__ S0, int n0,
                  const float* __restrict__ S1, int n1,
                  const float* __restrict__ S2,
                  const float* __restrict__ W, const float* __restrict__ bias,
                  float* __restrict__ C, int Mtot, int K) {
    __shared__ alignas(16) float As[16][68];
    __shared__ alignas(16) float Bs[16][68];
    const int tid  = threadIdx.x;
    const int tx   = tid & 15, ty = tid >> 4;
    const int m0   = blockIdx.x * 64, nc0 = blockIdx.y * 64;
    const int lrow = tid >> 2;
    const int lk4  = (tid & 3) << 2;

    const int gr = m0 + lrow;
    const float* srow = nullptr;
    if (gr < n0)            srow = S0 + (size_t)gr * K;
    else if (gr < n0 + n1)  srow = S1 + (size_t)(gr - n0) * K;
    else if (gr < Mtot)     srow = S2;
    const float* wrow = W + (size_t)(nc0 + lrow) * K;

    float acc[4][4] = {};
    for (int k0 = 0; k0 < K; k0 += 16) {
        float4 va = make_float4(0.f, 0.f, 0.f, 0.f);
        if (srow) va = *(const float4*)(srow + k0 + lk4);
        const float4 vb = *(const float4*)(wrow + k0 + lk4);
        As[lk4+0][lrow] = va.x; As[lk4+1][lrow] = va.y;
        As[lk4+2][lrow] = va.z; As[lk4+3][lrow] = va.w;
        Bs[lk4+0][lrow] = vb.x; Bs[lk4+1][lrow] = vb.y;
        Bs[lk4+2][lrow] = vb.z; Bs[lk4+3][lrow] = vb.w;
        __syncthreads();
        #pragma unroll
        for (int kk = 0; kk < 16; ++kk) {
            const float4 a4 = *(const float4*)&As[kk][ty << 2];
            const float4 b4 = *(const float4*)&Bs[kk][tx << 2];
            const float av[4] = {a4.x, a4.y, a4.z, a4.w};
            const float bv[4] = {b4.x, b4.y, b4.z, b4.w};
            #pragma unroll
            for (int i2 = 0; i2 < 4; ++i2)
                #pragma unroll
                for (int j2 = 0; j2 < 4; ++j2)
                    acc[i2][j2] = fmaf(av[i2], bv[j2], acc[i2][j2]);
        }
        __syncthreads();
    }
    #pragma unroll
    for (int i2 = 0; i2 < 4; ++i2) {
        const int grr = m0 + (ty << 2) + i2;
        if (grr >= Mtot) continue;
        #pragma unroll
        for (int j2 = 0; j2 < 4; ++j2) {
            const int gc = nc0 + (tx << 2) + j2;
            const float vv = acc[i2][j2] + bias[gc];
            C[(size_t)grr * EDIM + gc] = fmaxf(vv, 0.0f);
        }
    }
}

// ---------------------------------------------------------------------------
// Per-pair scaled edit-cost matrix via MFMA Gram (fp16 3-term split).
// ---------------------------------------------------------------------------
#define CSTR 36
__global__ __launch_bounds__(256)
void k_costs(const float* __restrict__ Emb, const int* __restrict__ len_s,
             const int* __restrict__ len_t, int Ns, int Nt,
             float* __restrict__ costs) {
    __shared__ alignas(16) unsigned Ah[34 * CSTR], Al[34 * CSTR];
    __shared__ alignas(16) unsigned Bh[34 * CSTR], Bl[34 * CSTR];
    __shared__ float dtile[LMAXP1 * LMAXP1];
    __shared__ float na[LMAXP1], nb[LMAXP1];
    __shared__ float red[256];
    __shared__ float s_scale;
    const int p = blockIdx.x, tid = threadIdx.x;
    const int n = len_s[p], m = len_t[p];
    int offs = 0, offt = 0;
    for (int j = 0; j < p; ++j) { offs += len_s[j]; offt += len_t[j]; }  // uniform
    const int veRow = Ns + Nt;
    const int tbase = Ns + offt;

    const int lane = tid & 63, wv = tid >> 6;
    const int lr = lane & 15, lq = lane >> 4;

    if (tid <= n) {
        const float* src = (tid < n) ? (Emb + (size_t)(offs + tid) * EDIM)
                                     : (Emb + (size_t)veRow * EDIM);
        const float4* a4 = (const float4*)src;
        float s = 0.f;
        for (int k = 0; k < 64; ++k) {
            const float4 a = a4[k];
            s = fmaf(a.x, a.x, s); s = fmaf(a.y, a.y, s);
            s = fmaf(a.z, a.z, s); s = fmaf(a.w, a.w, s);
        }
        na[tid] = s;
    } else if (tid >= 64 && tid - 64 <= m) {
        const int j = tid - 64;
        const float* src = (j < m) ? (Emb + (size_t)(tbase + j) * EDIM)
                                   : (Emb + (size_t)veRow * EDIM);
        const float4* b4 = (const float4*)src;
        float s = 0.f;
        for (int k = 0; k < 64; ++k) {
            const float4 b = b4[k];
            s = fmaf(b.x, b.x, s); s = fmaf(b.y, b.y, s);
            s = fmaf(b.z, b.z, s); s = fmaf(b.w, b.w, s);
        }
        nb[j] = s;
    }

    f32x4 g0 = {}, g1 = {}, g2 = {};
    const int t0 = wv, t1 = wv + 4, t2 = wv + 8;

    for (int k0 = 0; k0 < EDIM; k0 += 64) {
        for (int idx = tid; idx < 34 * 16; idx += 256) {
            const int r = idx >> 4, c4 = idx & 15;
            float4 va = make_float4(0.f,0.f,0.f,0.f), vb = va;
            if (r < n)       va = *(const float4*)(Emb + (size_t)(offs + r) * EDIM + k0 + c4*4);
            else if (r == n) va = *(const float4*)(Emb + (size_t)veRow * EDIM + k0 + c4*4);
            if (r < m)       vb = *(const float4*)(Emb + (size_t)(tbase + r) * EDIM + k0 + c4*4);
            else if (r == m) vb = *(const float4*)(Emb + (size_t)veRow * EDIM + k0 + c4*4);
            const float xa[4] = {va.x, va.y, va.z, va.w};
            const float xb[4] = {vb.x, vb.y, vb.z, vb.w};
            unsigned ah_[2], al_[2], bh_[2], bl_[2];
            #pragma unroll
            for (int j = 0; j < 2; ++j) {
                const _Float16 h0 = (_Float16)xa[2*j],   h1 = (_Float16)xa[2*j+1];
                const _Float16 l0 = (_Float16)(xa[2*j]   - (float)h0);
                const _Float16 l1 = (_Float16)(xa[2*j+1] - (float)h1);
                ah_[j] = pk2h(h0, h1); al_[j] = pk2h(l0, l1);
                const _Float16 g0_ = (_Float16)xb[2*j],   g1_ = (_Float16)xb[2*j+1];
                const _Float16 m0_ = (_Float16)(xb[2*j]   - (float)g0_);
                const _Float16 m1_ = (_Float16)(xb[2*j+1] - (float)g1_);
                bh_[j] = pk2h(g0_, g1_); bl_[j] = pk2h(m0_, m1_);
            }
            const int uo = r * CSTR + c4 * 2;
            *(uint2*)(Ah + uo) = make_uint2(ah_[0], ah_[1]);
            *(uint2*)(Al + uo) = make_uint2(al_[0], al_[1]);
            *(uint2*)(Bh + uo) = make_uint2(bh_[0], bh_[1]);
            *(uint2*)(Bl + uo) = make_uint2(bl_[0], bl_[1]);
        }
        __syncthreads();

        #pragma unroll
        for (int kf = 0; kf < 2; ++kf) {
#define GRAM_TILE(T, G) { \
            const int tr_ = (T) / 3, tc_ = (T) % 3;                              \
            const int ar_ = tr_ * 16 + lr, br_ = tc_ * 16 + lr;                  \
            const half8 ah = *(const half8*)((const char*)Ah + ar_*144 + kf*64 + lq*16); \
            const half8 al = *(const half8*)((const char*)Al + ar_*144 + kf*64 + lq*16); \
            const half8 bh = *(const half8*)((const char*)Bh + br_*144 + kf*64 + lq*16); \
            const half8 bl = *(const half8*)((const char*)Bl + br_*144 + kf*64 + lq*16); \
            G = __builtin_amdgcn_mfma_f32_16x16x32_f16(ah, bh, G, 0, 0, 0);      \
            G = __builtin_amdgcn_mfma_f32_16x16x32_f16(ah, bl, G, 0, 0, 0);      \
            G = __builtin_amdgcn_mfma_f32_16x16x32_f16(al, bh, G, 0, 0, 0); }
            GRAM_TILE(t0, g0)
            GRAM_TILE(t1, g1)
            if (wv == 0) GRAM_TILE(t2, g2)
#undef GRAM_TILE
        }
        __syncthreads();
    }

#define DTILE_OUT(T, G) { \
    const int tr_ = (T) / 3, tc_ = (T) % 3;                                      \
    _Pragma("unroll")                                                            \
    for (int r = 0; r < 4; ++r) {                                                \
        const int i_ = tr_ * 16 + lq * 4 + r, j_ = tc_ * 16 + lr;                \
        if (i_ <= n && j_ <= m) {                                                \
            const float sq = fmaxf(na[i_] + nb[j_] - 2.0f * G[r], 0.0f);         \
            dtile[i_ * LMAXP1 + j_] = (sq > 0.0f) ? sqrtf(sq) : 0.0f;            \
        } } }
    DTILE_OUT(t0, g0)
    DTILE_OUT(t1, g1)
    if (wv == 0) DTILE_OUT(t2, g2)
#undef DTILE_OUT
    __syncthreads();

    float lsum = 0.f;
    const int m1 = m + 1;
    const int cells = (n + 1) * m1;
    for (int c = tid; c < cells; c += 256) {
        const int i = c / m1, j = c - i * m1;
        lsum += dtile[i * LMAXP1 + j];
    }
    red[tid] = lsum;
    __syncthreads();
    for (int s = 128; s > 0; s >>= 1) {
        if (tid < s) red[tid] += red[tid + s];
        __syncthreads();
    }
    if (tid == 0) s_scale = (float)(n * m) / red[0];
    __syncthreads();
    const float scale = s_scale;
    for (int idx = tid; idx < LMAXP1 * LMAXP1; idx += 256) {
        const int i = idx / LMAXP1, j = idx - i * LMAXP1;
        const float v = (i <= n && j <= m) ? dtile[i * LMAXP1 + j] * scale : 0.0f;
        costs[(size_t)p * (LMAXP1 * LMAXP1) + idx] = v;
    }
}

// ---------------------------------------------------------------------------
// LAP via exact LSAPE reduction to max(n,m)^2 square LAP + col-reduction/
// greedy init; JV Dijkstra core with packed u32 DPP argmin (R12-verified).
// ---------------------------------------------------------------------------
__device__ inline int rdlane_i(int v, int l) { return __builtin_amdgcn_readlane(v, l); }
__device__ inline float rdlane_f(float v, int l) {
    return __int_as_float(__builtin_amdgcn_readlane(__float_as_int(v), l));
}
__device__ inline unsigned wave_umin64(unsigned x) {
#define DPPMINU(ctrl) { unsigned t_ = (unsigned)__builtin_amdgcn_update_dpp(  \
        (int)x, (int)x, (ctrl), 0xf, 0xf, false);                             \
        x = (t_ < x) ? t_ : x; }
    DPPMINU(0xB1)
    DPPMINU(0x4E)
    DPPMINU(0x141)
    DPPMINU(0x140)
    DPPMINU(0x142)
    DPPMINU(0x143)
#undef DPPMINU
    return (unsigned)__builtin_amdgcn_readlane((int)x, 63);
}

__global__ __launch_bounds__(64)
void k_lap(const float* __restrict__ costs, const int* __restrict__ len_s,
           const int* __restrict__ len_t, float* __restrict__ aligns,
           float* __restrict__ geds) {
    __shared__ float ec[LMAXP1 * LMAXP1];
    __shared__ float Ms[33 * 64];
    const int p = blockIdx.x, lane = threadIdx.x;
    const int n = len_s[p], m = len_t[p];
    const float* cp = costs + (size_t)p * (LMAXP1 * LMAXP1);
    for (int idx = lane; idx < LMAXP1 * LMAXP1; idx += 64) ec[idx] = cp[idx];
    __syncthreads();

    const bool swp = (n > m);
    const int R  = swp ? n : m;
    const int S_ = swp ? m : n;
    const bool vec = (lane >= 1 && lane <= R);

    for (int r = 1; r <= R; ++r) {
        float cv = FBIG;
        const int i0b = r - 1, j0b = lane - 1;
        if (vec) {
            if (!swp) {
                const float ins = ec[n * LMAXP1 + j0b];
                cv = (i0b < S_)
                   ? fminf(ec[i0b * LMAXP1 + j0b], ec[i0b * LMAXP1 + m] + ins)
                   : ins;
            } else {
                const float ins = ec[j0b * LMAXP1 + m];
                cv = (i0b < S_)
                   ? fminf(ec[j0b * LMAXP1 + i0b], ec[n * LMAXP1 + i0b] + ins)
                   : ins;
            }
        }
        Ms[(r << 6) + lane] = cv;
    }
    __syncthreads();

    float v_l = 0.0f;
    int amin_l = 0;
    if (vec) {
        float best = FBIG;
        for (int r = 1; r <= R; ++r) {
            const float c = Ms[(r << 6) + lane];
            if (c < best) { best = c; amin_l = r; }
        }
        v_l = best;
    }
    int p_l = 0;
    unsigned long long rowfree = ((1ull << R) - 1ull) << 1;
    for (int j = 1; j <= R; ++j) {
        const int ai = rdlane_i(amin_l, j);
        if ((rowfree >> ai) & 1ull) {
            if (lane == j) p_l = ai;
            rowfree &= ~(1ull << ai);
        }
    }

    float ucol = 0.0f, minv_l = FBIG;
    int way_l = 0;

    for (int i = 1; i <= R; ++i) {
        if (!((rowfree >> i) & 1ull)) continue;
        if (lane == 0) { p_l = i; ucol = 0.0f; }
        minv_l = FBIG;
        int used_l = 0;
        int j0 = 0, i0 = i;
        float u_i0 = 0.0f;
        while (true) {
            if (lane == j0) used_l = 1;
            const float cur = Ms[(i0 << 6) + lane] - u_i0 - v_l;
            const bool unused = vec && !used_l;
            if (unused && cur < minv_l) { minv_l = cur; way_l = j0; }
            const float mval = unused ? fmaxf(minv_l, 0.0f) : FBIG;
            const unsigned key = (__float_as_uint(mval) & ~63u) | (unsigned)lane;
            const unsigned kmin = wave_umin64(key);
            const int j1 = (int)(kmin & 63u);
            const float delta = rdlane_f(minv_l, j1);
            if (used_l) { ucol += delta; v_l -= delta; }
            if (unused) minv_l -= delta;
            j0 = j1;
            i0 = rdlane_i(p_l, j1);
            u_i0 = rdlane_f(ucol, j1);
            if (i0 == 0) break;
        }
        int jj = j0;
        while (jj != 0) {
            const int   j1a = rdlane_i(way_l, jj);
            const int   pn  = rdlane_i(p_l, j1a);
            const float un  = rdlane_f(ucol, j1a);
            if (lane == jj) { p_l = pn; ucol = un; }
            jj = j1a;
        }
    }

    float* ap = aligns + (size_t)p * (LMAXP1 * LMAXP1);
    for (int idx = lane; idx < LMAXP1 * LMAXP1; idx += 64) ap[idx] = 0.0f;
    __syncthreads();
    float gedv = 0.0f;
    if (vec) {
        const int i0b = p_l - 1;
        const int j0b = lane - 1;
        if (!swp) {
            if (i0b < S_) {
                const float sub = ec[i0b * LMAXP1 + j0b];
                const float alt = ec[i0b * LMAXP1 + m] + ec[n * LMAXP1 + j0b];
                if (sub <= alt) { ap[i0b * LMAXP1 + j0b] = 1.0f; gedv = sub; }
                else { ap[i0b * LMAXP1 + m] = 1.0f;
                       ap[n * LMAXP1 + j0b] = 1.0f;
                       gedv = alt; }
            } else {
                ap[n * LMAXP1 + j0b] = 1.0f;
                gedv = ec[n * LMAXP1 + j0b];
            }
        } else {
            if (i0b < S_) {
                const float sub = ec[j0b * LMAXP1 + i0b];
                const float alt = ec[n * LMAXP1 + i0b] + ec[j0b * LMAXP1 + m];
                if (sub <= alt) { ap[j0b * LMAXP1 + i0b] = 1.0f; gedv = sub; }
                else { ap[n * LMAXP1 + i0b] = 1.0f;
                       ap[j0b * LMAXP1 + m] = 1.0f;
                       gedv = alt; }
            } else {
                ap[j0b * LMAXP1 + m] = 1.0f;
                gedv = ec[j0b * LMAXP1 + m];
            }
        }
    }
    #pragma unroll
    for (int off = 32; off > 0; off >>= 1) gedv += __shfl_xor(gedv, off);
    if (lane == 0) geds[p] = gedv / (float)(n + m);
}

// ---------------------------------------------------------------------------
extern "C" void kernel_launch(void* const* d_in, const int* in_sizes, int n_in,
                              void* d_out, int out_size, void* d_ws, size_t ws_size,
                              hipStream_t stream) {
    const float* x_s = (const float*)d_in[0];
    const float* x_t = (const float*)d_in[1];
    const float* W1  = (const float*)d_in[2];
    const float* b1  = (const float*)d_in[3];
    const float* W2  = (const float*)d_in[4];
    const float* b2  = (const float*)d_in[5];
    const float* ve  = (const float*)d_in[6];
    const int* len_s = (const int*)d_in[7];
    const int* len_t = (const int*)d_in[8];
    const int P    = in_sizes[7];
    const int Ns   = in_sizes[0] / 2048;
    const int Nt   = in_sizes[1] / 2048;
    const int Mtot = Ns + Nt + 1;
    const size_t MN  = (size_t)Mtot * EDIM;          // even

    float* out_aligns = (float*)d_out;
    float* out_costs  = out_aligns + (size_t)P * LMAXP1 * LMAXP1;
    float* out_geds   = out_costs  + (size_t)P * LMAXP1 * LMAXP1;

    const dim3 b256(256);
    const int gx64 = (Mtot + 63) / 64;

    // workspace plan (floats): [Part: S*MN | Emb aliases Part[0..MN)]
    //                          [Hh: MN/2][Hl: MN/2][W1h: 262144][W1l: 262144]
    //                          [W2h: 32768][W2l: 32768]
    const size_t fixed = MN /*Hh+Hl*/ + 2 * 262144 + 2 * 32768;
    int S = 0;
    if (ws_size >= (4 * MN + fixed) * sizeof(float)) S = 4;
    else if (ws_size >= (2 * MN + fixed) * sizeof(float)) S = 2;

    if (S > 0) {
        float* Part = (float*)d_ws;
        float* Emb  = Part;                           // alias, disjoint lifetime
        unsigned* Hh  = (unsigned*)(Part + (size_t)S * MN);
        unsigned* Hl  = Hh + MN / 2;
        unsigned* W1h = Hl + MN / 2;
        unsigned* W1l = W1h + 262144;
        unsigned* W2h = W1l + 262144;
        unsigned* W2l = W2h + 32768;

        k_convw<<<dim3(1024), b256, 0, stream>>>(W1, W1h, W1l, 262144);
        k_convw<<<dim3(128),  b256, 0, stream>>>(W2, W2h, W2l, 32768);

        k_gemm_splitk<<<dim3(gx64, 1, S), b256, 0, stream>>>(
            x_s, Ns, x_t, Nt, ve, W1h, W1l, Part, Mtot, 2048, 2048 / S);

        const size_t MN4 = MN / 4;
        const int rblocks = (int)((MN4 + 255) / 256) < 2048
                          ? (int)((MN4 + 255) / 256) : 2048;
        k_reduce_bias_relu<<<dim3(rblocks), b256, 0, stream>>>(Part, b1, Hh, Hl, S, MN4);

        k_gemm_f16<<<dim3(gx64), b256, 0, stream>>>(Hh, Hl, W2h, W2l, b2, Emb, Mtot, 256);

        k_costs<<<dim3(P), b256, 0, stream>>>(Emb, len_s, len_t, Ns, Nt, out_costs);
        k_lap<<<dim3(P), dim3(64), 0, stream>>>(out_costs, len_s, len_t, out_aligns, out_geds);
    } else {
        float* H   = (float*)d_ws;
        float* Emb = H + MN;
        k_embed_gemm<<<dim3(gx64, 4), b256, 0, stream>>>(
            x_s, Ns, x_t, Nt, ve, W1, b1, H, Mtot, 2048);
        k_embed_gemm<<<dim3(gx64, 4), b256, 0, stream>>>(
            H, Mtot, nullptr, 0, nullptr, W2, b2, Emb, Mtot, 256);
        k_costs<<<dim3(P), b256, 0, stream>>>(Emb, len_s, len_t, Ns, Nt, out_costs);
        k_lap<<<dim3(P), dim3(64), 0, stream>>>(out_costs, len_s, len_t, out_aligns, out_geds);
    }
}